// Round 3
// baseline (617.105 us; speedup 1.0000x reference)
//
#include <hip/hip_runtime.h>
#include <hip/hip_bf16.h>

constexpr int CN   = 256;   // channels
constexpr int NV   = 4096;  // voxels = 16^3
constexpr int KTOP = 512;

// ---------------------------------------------------------------- K1: channel mean/max
__global__ void k_reduce(const float* __restrict__ xkv, float* __restrict__ avgmx) {
  int g = blockIdx.x * 256 + threadIdx.x;   // b*NV + n
  int b = g >> 12, n = g & 4095;
  const float* p = xkv + (size_t)b * CN * NV + n;
  float s = 0.f, m = -1e30f;
  for (int c = 0; c < CN; ++c) {
    float v = p[(size_t)c * NV];
    s += v; m = fmaxf(m, v);
  }
  avgmx[(b * 2 + 0) * NV + n] = s * (1.0f / 256.0f);
  avgmx[(b * 2 + 1) * NV + n] = m;
}

// ---------------------------------------------------------------- K2: 7x7x7 conv (2ch) + sigmoid
// Whole per-batch 2-channel volume (32 KB) + weights staged in LDS.
// 64 blocks, 2 threads/voxel (split by input channel), shfl-combine.
__global__ void __launch_bounds__(256) k_spa(const float* __restrict__ avgmx,
                                             const float* __restrict__ wspa,
                                             float* __restrict__ scores) {
  __shared__ float vol[2 * 4096];
  __shared__ float ws[686];
  int b = blockIdx.x >> 5, chunk = blockIdx.x & 31;
  int tid = threadIdx.x;
  for (int t = tid; t < 8192; t += 256) vol[t] = avgmx[b * 8192 + t];
  for (int t = tid; t < 686; t += 256) ws[t] = wspa[t];
  __syncthreads();
  int ci = tid & 1;
  int n = chunk * 128 + (tid >> 1);
  int d = n >> 8, h = (n >> 4) & 15, w = n & 15;
  const float* vb = vol + ci * 4096;
  const float* wb = ws + ci * 343;
  float acc = 0.f;
  for (int kd = 0; kd < 7; ++kd) {
    int zd = d - 3 + kd; if ((unsigned)zd >= 16u) continue;
    for (int kh = 0; kh < 7; ++kh) {
      int zh = h - 3 + kh; if ((unsigned)zh >= 16u) continue;
      const float* row = vb + zd * 256 + zh * 16;
      const float* wr = wb + kd * 49 + kh * 7;
#pragma unroll
      for (int kw = 0; kw < 7; ++kw) {
        int zw = w - 3 + kw;
        if ((unsigned)zw < 16u) acc += row[zw] * wr[kw];
      }
    }
  }
  acc += __shfl_xor(acc, 1);
  if (ci == 0) scores[b * NV + n] = 1.0f / (1.0f + expf(-acc));
}

// ---------------------------------------------------------------- K3: top-512 via bitonic sort
__global__ void __launch_bounds__(1024) k_topk(const float* __restrict__ scores,
                                               int* __restrict__ idx) {
  __shared__ float sv[4096];
  __shared__ int   si[4096];
  int b = blockIdx.x, tid = threadIdx.x;
  for (int t = tid; t < 4096; t += 1024) { sv[t] = scores[b * NV + t]; si[t] = t; }
  for (unsigned k = 2; k <= 4096; k <<= 1) {
    for (unsigned j = k >> 1; j > 0; j >>= 1) {
      __syncthreads();
      for (unsigned t = tid; t < 4096; t += 1024) {
        unsigned l = t ^ j;
        if (l > t) {
          float va = sv[t], vb = sv[l];
          int   ia = si[t], ib = si[l];
          bool aAfter = (va < vb) || (va == vb && ia > ib);  // desc, tie: low idx first
          bool desc = ((t & k) == 0);
          if (desc ? aAfter : !aAfter) { sv[t] = vb; sv[l] = va; si[t] = ib; si[l] = ia; }
        }
      }
    }
  }
  __syncthreads();
  if (tid < KTOP) idx[b * KTOP + tid] = si[tid];
}

// ---------------------------------------------------------------- K4: generic projection
// Y[b, m, j] = sum_c X[b, c, map(m)] * W[c*ldw + j] + bias[j]
// headMajor: write Y as (b, h=j/8, m, d=j%8) instead of (b, m, j)
__global__ void k_proj(const float* __restrict__ X, const float* __restrict__ W, int ldw,
                       const float* __restrict__ bias, const int* __restrict__ map,
                       float* __restrict__ Y, int M, int headMajor) {
  __shared__ float Xs[32 * 33];
  __shared__ float Ws[32 * 64];
  __shared__ int nmap[32];
  int m0 = blockIdx.x * 32, j0 = blockIdx.y * 64, b = blockIdx.z;
  int tid = threadIdx.x;
  if (tid < 32) nmap[tid] = map ? map[b * KTOP + m0 + tid] : (m0 + tid);
  int mm = tid >> 3, tj = (tid & 7) * 8;
  float acc[8] = {0.f, 0.f, 0.f, 0.f, 0.f, 0.f, 0.f, 0.f};
  const float* Xb = X + (size_t)b * CN * NV;
  for (int c0 = 0; c0 < 256; c0 += 32) {
    __syncthreads();
    for (int t = tid; t < 1024; t += 256) {
      int cc = t >> 5, mmm = t & 31;
      Xs[cc * 33 + mmm] = Xb[(size_t)(c0 + cc) * NV + nmap[mmm]];
    }
    for (int t = tid; t < 2048; t += 256) {
      int cc = t >> 6, jj = t & 63;
      Ws[cc * 64 + jj] = W[(size_t)(c0 + cc) * ldw + j0 + jj];
    }
    __syncthreads();
    for (int cc = 0; cc < 32; ++cc) {
      float xv = Xs[cc * 33 + mm];
      float4 w0 = *(const float4*)&Ws[cc * 64 + tj];
      float4 w1 = *(const float4*)&Ws[cc * 64 + tj + 4];
      acc[0] += xv * w0.x; acc[1] += xv * w0.y; acc[2] += xv * w0.z; acc[3] += xv * w0.w;
      acc[4] += xv * w1.x; acc[5] += xv * w1.y; acc[6] += xv * w1.z; acc[7] += xv * w1.w;
    }
  }
  int m = m0 + mm, j = j0 + tj;
  if (headMajor) {
    float* outp = Y + ((size_t)(b * 32 + (j >> 3)) * M + m) * 8;
#pragma unroll
    for (int jj = 0; jj < 8; ++jj) outp[jj] = acc[jj] + bias[j + jj];
  } else {
    float* outp = Y + ((size_t)b * M + m) * 256 + j;
#pragma unroll
    for (int jj = 0; jj < 8; ++jj) outp[jj] = acc[jj] + bias[j + jj];
  }
}

// ---------------------------------------------------------------- K5: gathered attention
// q, k_g head-major (b,h,n,8); out head-major; scale*log2e folded into K in LDS.
__global__ void __launch_bounds__(256) k_attn(const float* __restrict__ qh,
                                              const float* __restrict__ kgh,
                                              const float* __restrict__ vfull,
                                              const int* __restrict__ idx,
                                              float* __restrict__ oh) {
  __shared__ float Ks[KTOP * 8];
  __shared__ float Vs[KTOP * 8];
  int b = blockIdx.x >> 5, h = blockIdx.x & 31;
  int tid = threadIdx.x;
  const float kscale = 0.35355339059327373f * 1.4426950408889634f;  // 1/sqrt(8) * log2(e)
  const float* kb = kgh + (size_t)(b * 32 + h) * KTOP * 8;
  for (int t = tid; t < KTOP * 8; t += 256) Ks[t] = kb[t] * kscale;
  const int* ib = idx + b * KTOP;
  for (int t = tid; t < KTOP * 8; t += 256) {
    int i = t >> 3, d = t & 7;
    Vs[t] = vfull[((size_t)b * NV + ib[i]) * 256 + h * 8 + d];
  }
  __syncthreads();
  int n0 = blockIdx.y * 1024 + tid;
  const float* qb = qh + (size_t)(b * 32 + h) * NV * 8;
  float4 qa[4], qc[4], oa[4], oc[4];
  float se[4];
#pragma unroll
  for (int qq = 0; qq < 4; ++qq) {
    const float4* qp = (const float4*)(qb + (size_t)(n0 + qq * 256) * 8);
    qa[qq] = qp[0]; qc[qq] = qp[1];
    oa[qq].x = oa[qq].y = oa[qq].z = oa[qq].w = 0.f;
    oc[qq].x = oc[qq].y = oc[qq].z = oc[qq].w = 0.f;
    se[qq] = 0.f;
  }
  for (int i = 0; i < KTOP; ++i) {
    float4 ka = *(const float4*)&Ks[i * 8];
    float4 kc = *(const float4*)&Ks[i * 8 + 4];
    float4 va = *(const float4*)&Vs[i * 8];
    float4 vc = *(const float4*)&Vs[i * 8 + 4];
#pragma unroll
    for (int qq = 0; qq < 4; ++qq) {
      float dot = qa[qq].x * ka.x + qa[qq].y * ka.y + qa[qq].z * ka.z + qa[qq].w * ka.w
                + qc[qq].x * kc.x + qc[qq].y * kc.y + qc[qq].z * kc.z + qc[qq].w * kc.w;
      float e = exp2f(dot);
      se[qq] += e;
      oa[qq].x += e * va.x; oa[qq].y += e * va.y; oa[qq].z += e * va.z; oa[qq].w += e * va.w;
      oc[qq].x += e * vc.x; oc[qq].y += e * vc.y; oc[qq].z += e * vc.z; oc[qq].w += e * vc.w;
    }
  }
#pragma unroll
  for (int qq = 0; qq < 4; ++qq) {
    float inv = 1.0f / se[qq];
    float4* op = (float4*)(oh + ((size_t)(b * 32 + h) * NV + n0 + qq * 256) * 8);
    float4 r0, r1;
    r0.x = oa[qq].x * inv; r0.y = oa[qq].y * inv; r0.z = oa[qq].z * inv; r0.w = oa[qq].w * inv;
    r1.x = oc[qq].x * inv; r1.y = oc[qq].y * inv; r1.z = oc[qq].z * inv; r1.w = oc[qq].w * inv;
    op[0] = r0; op[1] = r1;
  }
}

// ---------------------------------------------------------------- K6: depthwise 3x3x3 conv
__global__ void k_dw(const float* __restrict__ vfull, const float* __restrict__ wdw,
                     const float* __restrict__ bdw, float* __restrict__ ydw) {
  int c = threadIdx.x;
  float wr[27];
#pragma unroll
  for (int t = 0; t < 27; ++t) wr[t] = wdw[c * 27 + t];
  int b = blockIdx.y;
  float bias = bdw[c];
  int nbase = blockIdx.x * 8;
  for (int ni = 0; ni < 8; ++ni) {
    int n = nbase + ni;
    int d = n >> 8, h = (n >> 4) & 15, w = n & 15;
    float acc = bias;
    for (int kd = 0; kd < 3; ++kd) {
      int zd = d - 1 + kd; if ((unsigned)zd >= 16u) continue;
      for (int kh = 0; kh < 3; ++kh) {
        int zh = h - 1 + kh; if ((unsigned)zh >= 16u) continue;
        for (int kw = 0; kw < 3; ++kw) {
          int zw = w - 1 + kw; if ((unsigned)zw >= 16u) continue;
          int nz = zd * 256 + zh * 16 + zw;
          acc += vfull[((size_t)b * NV + nz) * 256 + c] * wr[kd * 9 + kh * 3 + kw];
        }
      }
    }
    ydw[((size_t)b * NV + n) * 256 + c] = acc;
  }
}

// ---------------------------------------------------------------- K7: fused epilogue
// out[b,j,n] = bproj[j]+bpw[j] + sum_c ao_h[b,c/8,n,c%8]*wproj[c,j] + sum_c ydw[b,n,c]*wpw[j,c]
__global__ void k_final(const float* __restrict__ ao, const float* __restrict__ ydw,
                        const float* __restrict__ wproj, const float* __restrict__ bproj,
                        const float* __restrict__ wpw, const float* __restrict__ bpw,
                        float* __restrict__ out) {
  __shared__ float As[32 * 33];
  __shared__ float Ys[32 * 33];
  __shared__ float Wp[32 * 64];
  __shared__ float Pw[32 * 65];
  int n0 = blockIdx.x * 32, j0 = blockIdx.y * 64, b = blockIdx.z;
  int tid = threadIdx.x;
  int jloc = tid >> 2, nloc = (tid & 3) * 8;
  int j = j0 + jloc;
  float bias = bproj[j] + bpw[j];
  float acc[8] = {0.f, 0.f, 0.f, 0.f, 0.f, 0.f, 0.f, 0.f};
  for (int c0 = 0; c0 < 256; c0 += 32) {
    __syncthreads();
    for (int t = tid; t < 1024; t += 256) {
      int mm = t >> 5, cc = t & 31;
      int c = c0 + cc;
      As[mm * 33 + cc] = ao[(((size_t)b * 32 + (c >> 3)) * NV + n0 + mm) * 8 + (c & 7)];
      Ys[mm * 33 + cc] = ydw[((size_t)b * NV + n0 + mm) * 256 + c];
    }
    for (int t = tid; t < 2048; t += 256) {
      int cc = t >> 6, jj = t & 63;
      Wp[cc * 64 + jj] = wproj[(size_t)(c0 + cc) * 256 + j0 + jj];
    }
    for (int t = tid; t < 2048; t += 256) {
      int cc = t & 31, jj = t >> 5;
      Pw[cc * 65 + jj] = wpw[(size_t)(j0 + jj) * 256 + c0 + cc];
    }
    __syncthreads();
    for (int cc = 0; cc < 32; ++cc) {
      float w1 = Wp[cc * 64 + jloc];
      float w2 = Pw[cc * 65 + jloc];
#pragma unroll
      for (int nn = 0; nn < 8; ++nn)
        acc[nn] += As[(nloc + nn) * 33 + cc] * w1 + Ys[(nloc + nn) * 33 + cc] * w2;
    }
  }
  float* op = out + ((size_t)b * 256 + j) * (size_t)NV + n0 + nloc;
#pragma unroll
  for (int nn = 0; nn < 8; ++nn) op[nn] = acc[nn] + bias;
}

// ---------------------------------------------------------------- launch
extern "C" void kernel_launch(void* const* d_in, const int* in_sizes, int n_in,
                              void* d_out, int out_size, void* d_ws, size_t ws_size,
                              hipStream_t stream) {
  const float* x_kv   = (const float*)d_in[0];
  const float* x_q    = (const float*)d_in[1];
  const float* w_spa  = (const float*)d_in[2];
  const float* w_kv   = (const float*)d_in[3];
  const float* b_kv   = (const float*)d_in[4];
  const float* w_q    = (const float*)d_in[5];
  const float* b_q    = (const float*)d_in[6];
  const float* w_proj = (const float*)d_in[7];
  const float* b_proj = (const float*)d_in[8];
  const float* w_dw   = (const float*)d_in[9];
  const float* b_dw   = (const float*)d_in[10];
  const float* w_pw   = (const float*)d_in[11];
  const float* b_pw   = (const float*)d_in[12];
  float* out = (float*)d_out;

  char* ws = (char*)d_ws;
  float* v_full = (float*)(ws);                               // 8 MB  (b,n,c)
  float* q      = (float*)(ws + (size_t)8  * 1024 * 1024);    // 8 MB  (b,h,n,8) — aliased by ydw later
  float* attn_o = (float*)(ws + (size_t)16 * 1024 * 1024);    // 8 MB  (b,h,n,8)
  float* k_g    = (float*)(ws + (size_t)24 * 1024 * 1024);    // 1 MB  (b,h,i,8)
  float* avgmx  = (float*)(ws + (size_t)25 * 1024 * 1024);    // 64 KB
  float* scores = (float*)(ws + (size_t)25 * 1024 * 1024 + 65536);          // 32 KB
  int*   idx    = (int*)  (ws + (size_t)25 * 1024 * 1024 + 65536 + 32768);  // 4 KB
  float* ydw    = q;  // q dead after k_attn; stream order makes this safe

  k_reduce<<<32, 256, 0, stream>>>(x_kv, avgmx);
  k_spa<<<64, 256, 0, stream>>>(avgmx, w_spa, scores);
  k_topk<<<2, 1024, 0, stream>>>(scores, idx);
  k_proj<<<dim3(128, 4, 2), 256, 0, stream>>>(x_kv, w_kv + 256, 512, b_kv + 256, nullptr, v_full, 4096, 0);
  k_proj<<<dim3(128, 4, 2), 256, 0, stream>>>(x_q,  w_q,        256, b_q,        nullptr, q,      4096, 1);
  k_proj<<<dim3(16,  4, 2), 256, 0, stream>>>(x_kv, w_kv,       512, b_kv,       idx,     k_g,     512, 1);
  k_attn<<<dim3(64, 4), 256, 0, stream>>>(q, k_g, v_full, idx, attn_o);
  k_dw<<<dim3(512, 2), 256, 0, stream>>>(v_full, w_dw, b_dw, ydw);
  k_final<<<dim3(128, 4, 2), 256, 0, stream>>>(attn_o, ydw, w_proj, b_proj, w_pw, b_pw, out);
}

// Round 4
// 474.179 us; speedup vs baseline: 1.3014x; 1.3014x over previous
//
#include <hip/hip_runtime.h>
#include <hip/hip_bf16.h>

constexpr int CN   = 256;
constexpr int NV   = 4096;
constexpr int KTOP = 512;

// ---------------------------------------------------------------- K1: channel mean/max
__global__ void k_reduce(const float* __restrict__ xkv, float* __restrict__ avgmx) {
  int g = blockIdx.x * 256 + threadIdx.x;
  int b = g >> 12, n = g & 4095;
  const float* p = xkv + (size_t)b * CN * NV + n;
  float s = 0.f, m = -1e30f;
  for (int c = 0; c < CN; ++c) {
    float v = p[(size_t)c * NV];
    s += v; m = fmaxf(m, v);
  }
  avgmx[(b * 2 + 0) * NV + n] = s * (1.0f / 256.0f);
  avgmx[(b * 2 + 1) * NV + n] = m;
}

// ---------------------------------------------------------------- K2: 7x7x7 conv + sigmoid
__global__ void __launch_bounds__(256) k_spa(const float* __restrict__ avgmx,
                                             const float* __restrict__ wspa,
                                             float* __restrict__ scores) {
  __shared__ float vol[2 * 4096];
  __shared__ float ws[686];
  int b = blockIdx.x >> 5, chunk = blockIdx.x & 31;
  int tid = threadIdx.x;
  for (int t = tid; t < 8192; t += 256) vol[t] = avgmx[b * 8192 + t];
  for (int t = tid; t < 686; t += 256) ws[t] = wspa[t];
  __syncthreads();
  int ci = tid & 1;
  int n = chunk * 128 + (tid >> 1);
  int d = n >> 8, h = (n >> 4) & 15, w = n & 15;
  const float* vb = vol + ci * 4096;
  const float* wb = ws + ci * 343;
  float acc = 0.f;
  for (int kd = 0; kd < 7; ++kd) {
    int zd = d - 3 + kd; if ((unsigned)zd >= 16u) continue;
    for (int kh = 0; kh < 7; ++kh) {
      int zh = h - 3 + kh; if ((unsigned)zh >= 16u) continue;
      const float* row = vb + zd * 256 + zh * 16;
      const float* wr = wb + kd * 49 + kh * 7;
#pragma unroll
      for (int kw = 0; kw < 7; ++kw) {
        int zw = w - 3 + kw;
        if ((unsigned)zw < 16u) acc += row[zw] * wr[kw];
      }
    }
  }
  acc += __shfl_xor(acc, 1);
  if (ci == 0) scores[b * NV + n] = 1.0f / (1.0f + expf(-acc));
}

// ---------------------------------------------------------------- K3: top-512 radix-select
// Set semantics: all values > v*, plus smallest-index values == v* to fill 512.
// Matches jax.lax.top_k's selected set (desc, ties low-index-first).
__global__ void __launch_bounds__(1024) k_topk(const float* __restrict__ scores,
                                               int* __restrict__ idx) {
  __shared__ unsigned sv[4096];
  __shared__ unsigned hist[256];
  __shared__ int sB;
  __shared__ unsigned sSub, scnt;
  int b = blockIdx.x, tid = threadIdx.x;
  for (int t = tid; t < 4096; t += 1024) sv[t] = __float_as_uint(scores[b * NV + t]);
  if (tid == 0) scnt = 0;
  unsigned prefix = 0;
  int r = 512;
  for (int shift = 24; shift >= 0; shift -= 8) {
    if (tid < 256) hist[tid] = 0;
    __syncthreads();
    unsigned maskhi = (shift == 24) ? 0u : (0xFFFFFFFFu << (shift + 8));
    for (int i = 0; i < 4; ++i) {
      unsigned v = sv[tid + i * 1024];
      if ((v & maskhi) == prefix) atomicAdd(&hist[(v >> shift) & 255], 1u);
    }
    __syncthreads();
    // suffix-inclusive scan: hist[t] = count(byte >= t)
    for (int off = 1; off < 256; off <<= 1) {
      unsigned add = 0;
      if (tid < 256 && tid + off < 256) add = hist[tid + off];
      __syncthreads();
      if (tid < 256) hist[tid] += add;
      __syncthreads();
    }
    if (tid < 256) {
      unsigned s = hist[tid];
      unsigned snext = (tid < 255) ? hist[tid + 1] : 0u;
      if (s >= (unsigned)r && snext < (unsigned)r) { sB = tid; sSub = snext; }
    }
    __syncthreads();
    prefix |= ((unsigned)sB) << shift;
    r -= (int)sSub;
    __syncthreads();
  }
  unsigned vstar = prefix;
  for (int i = 0; i < 4; ++i) {
    int t = tid + i * 1024;
    if (sv[t] > vstar) { unsigned p = atomicAdd(&scnt, 1u); idx[b * KTOP + p] = t; }
  }
  __syncthreads();
  int base = (int)scnt;
  for (int i = 0; i < 4; ++i) {
    int t = tid + i * 1024;
    if (sv[t] == vstar) {
      int rank = 0;
      for (int m = 0; m < t; ++m) rank += (sv[m] == vstar);
      if (rank < r) idx[b * KTOP + base + rank] = t;
    }
  }
}

// ---------------------------------------------------------------- K4: fused V+Q projection
// role z: 0,1 = V (b=0,1) -> v_nc (b,n,c) AND v_cn (b,c,n); 2,3 = Q -> qh (b,h,n,8)
// tile 128m x 128j, 256 threads, 8x8 per thread, BK=32
__global__ void __launch_bounds__(256) k_qv(const float* __restrict__ xkv,
                                            const float* __restrict__ xq,
                                            const float* __restrict__ wkv,
                                            const float* __restrict__ bkv,
                                            const float* __restrict__ wq,
                                            const float* __restrict__ bq,
                                            float* __restrict__ v_nc,
                                            float* __restrict__ v_cn,
                                            float* __restrict__ qh) {
  __shared__ float Xs[32 * 132];
  __shared__ float Ws[32 * 140];
  int role = blockIdx.z;
  int b = role & 1;
  bool isQ = role >= 2;
  const float* X = (isQ ? xq : xkv) + (size_t)b * CN * NV;
  const float* W = isQ ? wq : (wkv + 256);
  int ldw = isQ ? 256 : 512;
  const float* bias = isQ ? bq : (bkv + 256);
  int m0 = blockIdx.x * 128, j0 = blockIdx.y * 128;
  int tid = threadIdx.x;
  int tm = tid >> 4, tj = tid & 15;
  int jb = tj * 8 + ((tj * 8) >> 5) * 4;  // swizzled b-frag base
  float acc[8][8] = {};
  for (int c0 = 0; c0 < 256; c0 += 32) {
    __syncthreads();
#pragma unroll
    for (int i = 0; i < 4; ++i) {
      int id = i * 256 + tid;
      int cc = id >> 5, mg = id & 31;
      float4 v = *(const float4*)&X[(size_t)(c0 + cc) * NV + m0 + mg * 4];
      *(float4*)&Xs[cc * 132 + mg * 4] = v;
    }
#pragma unroll
    for (int i = 0; i < 4; ++i) {
      int id = i * 256 + tid;
      int cc = id >> 5, jg = id & 31;
      float4 v = *(const float4*)&W[(size_t)(c0 + cc) * ldw + j0 + jg * 4];
      *(float4*)&Ws[cc * 140 + jg * 4 + (jg >> 3) * 4] = v;
    }
    __syncthreads();
#pragma unroll 4
    for (int kk = 0; kk < 32; ++kk) {
      float4 a0 = *(const float4*)&Xs[kk * 132 + tm * 8];
      float4 a1 = *(const float4*)&Xs[kk * 132 + tm * 8 + 4];
      float4 b0 = *(const float4*)&Ws[kk * 140 + jb];
      float4 b1 = *(const float4*)&Ws[kk * 140 + jb + 4];
      float av[8] = {a0.x, a0.y, a0.z, a0.w, a1.x, a1.y, a1.z, a1.w};
      float bv[8] = {b0.x, b0.y, b0.z, b0.w, b1.x, b1.y, b1.z, b1.w};
#pragma unroll
      for (int mi = 0; mi < 8; ++mi)
#pragma unroll
        for (int ji = 0; ji < 8; ++ji)
          acc[mi][ji] = fmaf(av[mi], bv[ji], acc[mi][ji]);
    }
  }
  int j = j0 + tj * 8;
  float bl[8];
#pragma unroll
  for (int ji = 0; ji < 8; ++ji) bl[ji] = bias[j + ji];
#pragma unroll
  for (int mi = 0; mi < 8; ++mi)
#pragma unroll
    for (int ji = 0; ji < 8; ++ji) acc[mi][ji] += bl[ji];
  int nb = m0 + tm * 8;
  if (isQ) {
    int h = j >> 3;
    float* dst = qh + ((size_t)(b * 32 + h) * NV + nb) * 8;
#pragma unroll
    for (int mi = 0; mi < 8; ++mi) {
      *(float4*)&dst[mi * 8]     = make_float4(acc[mi][0], acc[mi][1], acc[mi][2], acc[mi][3]);
      *(float4*)&dst[mi * 8 + 4] = make_float4(acc[mi][4], acc[mi][5], acc[mi][6], acc[mi][7]);
    }
  } else {
#pragma unroll
    for (int mi = 0; mi < 8; ++mi) {
      float* d1 = v_nc + ((size_t)b * NV + nb + mi) * 256 + j;
      *(float4*)&d1[0] = make_float4(acc[mi][0], acc[mi][1], acc[mi][2], acc[mi][3]);
      *(float4*)&d1[4] = make_float4(acc[mi][4], acc[mi][5], acc[mi][6], acc[mi][7]);
    }
#pragma unroll
    for (int ji = 0; ji < 8; ++ji) {
      float* d2 = v_cn + ((size_t)(b * 256 + j + ji)) * NV + nb;
      *(float4*)&d2[0] = make_float4(acc[0][ji], acc[1][ji], acc[2][ji], acc[3][ji]);
      *(float4*)&d2[4] = make_float4(acc[4][ji], acc[5][ji], acc[6][ji], acc[7][ji]);
    }
  }
}

// ---------------------------------------------------------------- K5: gathered K projection
// Y (b,h,i,8) for the 512 gathered positions
__global__ void k_projg(const float* __restrict__ X, const float* __restrict__ W, int ldw,
                        const float* __restrict__ bias, const int* __restrict__ map,
                        float* __restrict__ Y, int M) {
  __shared__ float Xs[32 * 33];
  __shared__ float Ws[32 * 64];
  __shared__ int nmap[32];
  int m0 = blockIdx.x * 32, j0 = blockIdx.y * 64, b = blockIdx.z;
  int tid = threadIdx.x;
  if (tid < 32) nmap[tid] = map[b * KTOP + m0 + tid];
  int mm = tid >> 3, tj = (tid & 7) * 8;
  float acc[8] = {};
  const float* Xb = X + (size_t)b * CN * NV;
  for (int c0 = 0; c0 < 256; c0 += 32) {
    __syncthreads();
    for (int t = tid; t < 1024; t += 256) {
      int cc = t >> 5, mmm = t & 31;
      Xs[cc * 33 + mmm] = Xb[(size_t)(c0 + cc) * NV + nmap[mmm]];
    }
    for (int t = tid; t < 2048; t += 256) {
      int cc = t >> 6, jj = t & 63;
      Ws[cc * 64 + jj] = W[(size_t)(c0 + cc) * ldw + j0 + jj];
    }
    __syncthreads();
    for (int cc = 0; cc < 32; ++cc) {
      float xv = Xs[cc * 33 + mm];
      float4 w0 = *(const float4*)&Ws[cc * 64 + tj];
      float4 w1 = *(const float4*)&Ws[cc * 64 + tj + 4];
      acc[0] += xv * w0.x; acc[1] += xv * w0.y; acc[2] += xv * w0.z; acc[3] += xv * w0.w;
      acc[4] += xv * w1.x; acc[5] += xv * w1.y; acc[6] += xv * w1.z; acc[7] += xv * w1.w;
    }
  }
  int m = m0 + mm, j = j0 + tj;
  float* outp = Y + ((size_t)(b * 32 + (j >> 3)) * M + m) * 8;
#pragma unroll
  for (int jj = 0; jj < 8; ++jj) outp[jj] = acc[jj] + bias[j + jj];
}

// ---------------------------------------------------------------- K6: attention (key-split x2)
// writes UNNORMALIZED o and sum-of-exp; merged later
__global__ void __launch_bounds__(256) k_attn(const float* __restrict__ qh,
                                              const float* __restrict__ kgh,
                                              const float* __restrict__ v_nc,
                                              const int* __restrict__ idx,
                                              float* __restrict__ po,
                                              float* __restrict__ pse) {
  __shared__ float Ks[256 * 8];
  __shared__ float Vs[256 * 8];
  int bh = blockIdx.x;
  int b = bh >> 5, h = bh & 31;
  int z = blockIdx.z;
  po  += (size_t)z * 2097152;   // 2*32*4096*8
  pse += (size_t)z * 262144;    // 2*32*4096
  int tid = threadIdx.x;
  const float kscale = 0.35355339059327373f * 1.4426950408889634f;  // 1/sqrt(8)*log2(e)
  const float* kb = kgh + ((size_t)bh * KTOP + z * 256) * 8;
  for (int t = tid; t < 2048; t += 256) Ks[t] = kb[t] * kscale;
  const int* ib = idx + b * KTOP + z * 256;
  for (int t = tid; t < 2048; t += 256) {
    int i = t >> 3, d = t & 7;
    Vs[t] = v_nc[((size_t)b * NV + ib[i]) * 256 + h * 8 + d];
  }
  __syncthreads();
  int n0 = blockIdx.y * 1024 + tid;
  const float* qb = qh + (size_t)bh * NV * 8;
  float4 qa[4], qc[4], oa[4], oc[4];
  float se[4];
#pragma unroll
  for (int qq = 0; qq < 4; ++qq) {
    const float4* qp = (const float4*)(qb + (size_t)(n0 + qq * 256) * 8);
    qa[qq] = qp[0]; qc[qq] = qp[1];
    oa[qq] = make_float4(0.f, 0.f, 0.f, 0.f);
    oc[qq] = make_float4(0.f, 0.f, 0.f, 0.f);
    se[qq] = 0.f;
  }
#pragma unroll 2
  for (int i = 0; i < 256; ++i) {
    float4 ka = *(const float4*)&Ks[i * 8];
    float4 kc = *(const float4*)&Ks[i * 8 + 4];
    float4 va = *(const float4*)&Vs[i * 8];
    float4 vc = *(const float4*)&Vs[i * 8 + 4];
#pragma unroll
    for (int qq = 0; qq < 4; ++qq) {
      float d0 = fmaf(qa[qq].y, ka.y, qa[qq].x * ka.x);
      float d1 = fmaf(qa[qq].w, ka.w, qa[qq].z * ka.z);
      float d2 = fmaf(qc[qq].y, kc.y, qc[qq].x * kc.x);
      float d3 = fmaf(qc[qq].w, kc.w, qc[qq].z * kc.z);
      float e = exp2f((d0 + d1) + (d2 + d3));
      se[qq] += e;
      oa[qq].x = fmaf(e, va.x, oa[qq].x); oa[qq].y = fmaf(e, va.y, oa[qq].y);
      oa[qq].z = fmaf(e, va.z, oa[qq].z); oa[qq].w = fmaf(e, va.w, oa[qq].w);
      oc[qq].x = fmaf(e, vc.x, oc[qq].x); oc[qq].y = fmaf(e, vc.y, oc[qq].y);
      oc[qq].z = fmaf(e, vc.z, oc[qq].z); oc[qq].w = fmaf(e, vc.w, oc[qq].w);
    }
  }
#pragma unroll
  for (int qq = 0; qq < 4; ++qq) {
    int n = n0 + qq * 256;
    float4* op = (float4*)(po + ((size_t)bh * NV + n) * 8);
    op[0] = oa[qq]; op[1] = oc[qq];
    pse[(size_t)bh * NV + n] = se[qq];
  }
}

// ---------------------------------------------------------------- K7: merge partial softmax -> aoydw rows c<256 (b,c,n)
__global__ void __launch_bounds__(256) k_merge(const float* __restrict__ po,
                                               const float* __restrict__ pse,
                                               float* __restrict__ aoydw) {
  int bh = blockIdx.x;
  int b = bh >> 5, h = bh & 31;
  int n0 = blockIdx.y * 256;
  int tid = threadIdx.x;
  int d = tid >> 5, ng = tid & 31;
  const float* p0 = po;
  const float* p1 = po + 2097152;
  const float* s0 = pse + (size_t)bh * NV;
  const float* s1 = s0 + 262144;
  float* dst = aoydw + ((size_t)(b * 512 + h * 8 + d)) * NV + n0 + ng * 8;
  float r[8];
#pragma unroll
  for (int i = 0; i < 8; ++i) {
    int n = n0 + ng * 8 + i;
    size_t o = ((size_t)bh * NV + n) * 8 + d;
    float inv = 1.0f / (s0[n] + s1[n]);
    r[i] = (p0[o] + p1[o]) * inv;
  }
  *(float4*)&dst[0] = make_float4(r[0], r[1], r[2], r[3]);
  *(float4*)&dst[4] = make_float4(r[4], r[5], r[6], r[7]);
}

// ---------------------------------------------------------------- K8: depthwise conv -> aoydw rows c>=256
__global__ void __launch_bounds__(256) k_dw(const float* __restrict__ vt,
                                            const float* __restrict__ wdw,
                                            const float* __restrict__ bdw,
                                            float* __restrict__ aoydw) {
  int c = blockIdx.x, b = blockIdx.y;
  const float* plane = vt + ((size_t)(b * 256 + c)) * NV;
  float wr[27];
#pragma unroll
  for (int i = 0; i < 27; ++i) wr[i] = wdw[c * 27 + i];
  float bias = bdw[c];
  float* dst = aoydw + ((size_t)(b * 512 + 256 + c)) * NV;
  int tid = threadIdx.x;
  for (int i = 0; i < 16; ++i) {
    int n = i * 256 + tid;
    int d = n >> 8, h = (n >> 4) & 15, w = n & 15;
    float acc = bias;
    for (int kd = 0; kd < 3; ++kd) {
      int zd = d - 1 + kd; if ((unsigned)zd >= 16u) continue;
      for (int kh = 0; kh < 3; ++kh) {
        int zh = h - 1 + kh; if ((unsigned)zh >= 16u) continue;
        int rowb = zd * 256 + zh * 16;
        for (int kw = 0; kw < 3; ++kw) {
          int zw = w - 1 + kw; if ((unsigned)zw >= 16u) continue;
          acc += plane[rowb + zw] * wr[kd * 9 + kh * 3 + kw];
        }
      }
    }
    dst[n] = acc;
  }
}

// ---------------------------------------------------------------- K9: final GEMM, K=512
// out[b,j,n] = sum_{c<512} aoydw[b,c,n] * W'[c,j] + bproj[j] + bpw[j]
// W'[c<256] = wproj[c,j]; W'[c>=256] = wpw[j, c-256]
// tile 64n x 128j, 256 threads, 4x8 per thread
__global__ void __launch_bounds__(256) k_final(const float* __restrict__ aoydw,
                                               const float* __restrict__ wproj,
                                               const float* __restrict__ bproj,
                                               const float* __restrict__ wpw,
                                               const float* __restrict__ bpw,
                                               float* __restrict__ out) {
  __shared__ float Xs[32 * 68];
  __shared__ float Ws[32 * 140];
  int n0 = blockIdx.x * 64, j0 = blockIdx.y * 128, b = blockIdx.z;
  int tid = threadIdx.x;
  int tm = tid >> 4, tj = tid & 15;
  int jb = tj * 8 + ((tj * 8) >> 5) * 4;
  float acc[4][8] = {};
  for (int c0 = 0; c0 < 512; c0 += 32) {
    __syncthreads();
#pragma unroll
    for (int i = 0; i < 2; ++i) {
      int id = i * 256 + tid;
      int cc = id >> 4, ng = id & 15;
      float4 v = *(const float4*)&aoydw[((size_t)(b * 512 + c0 + cc)) * NV + n0 + ng * 4];
      *(float4*)&Xs[cc * 68 + ng * 4] = v;
    }
    if (c0 < 256) {
#pragma unroll
      for (int i = 0; i < 4; ++i) {
        int id = i * 256 + tid;
        int cc = id >> 5, jg = id & 31;
        float4 v = *(const float4*)&wproj[(size_t)(c0 + cc) * 256 + j0 + jg * 4];
        *(float4*)&Ws[cc * 140 + jg * 4 + (jg >> 3) * 4] = v;
      }
    } else {
#pragma unroll
      for (int i = 0; i < 4; ++i) {
        int id = i * 256 + tid;
        int jj = id >> 3, cg = id & 7;
        float4 v = *(const float4*)&wpw[(size_t)(j0 + jj) * 256 + (c0 - 256) + cg * 4];
        int jjs = jj + (jj >> 5) * 4;
        Ws[(cg * 4 + 0) * 140 + jjs] = v.x;
        Ws[(cg * 4 + 1) * 140 + jjs] = v.y;
        Ws[(cg * 4 + 2) * 140 + jjs] = v.z;
        Ws[(cg * 4 + 3) * 140 + jjs] = v.w;
      }
    }
    __syncthreads();
#pragma unroll 4
    for (int kk = 0; kk < 32; ++kk) {
      float4 a0 = *(const float4*)&Xs[kk * 68 + tm * 4];
      float4 b0 = *(const float4*)&Ws[kk * 140 + jb];
      float4 b1 = *(const float4*)&Ws[kk * 140 + jb + 4];
      float av[4] = {a0.x, a0.y, a0.z, a0.w};
      float bv[8] = {b0.x, b0.y, b0.z, b0.w, b1.x, b1.y, b1.z, b1.w};
#pragma unroll
      for (int mi = 0; mi < 4; ++mi)
#pragma unroll
        for (int ji = 0; ji < 8; ++ji)
          acc[mi][ji] = fmaf(av[mi], bv[ji], acc[mi][ji]);
    }
  }
  int j = j0 + tj * 8;
#pragma unroll
  for (int ji = 0; ji < 8; ++ji) {
    float bl = bproj[j + ji] + bpw[j + ji];
    float* op = out + ((size_t)(b * 256 + j + ji)) * NV + n0 + tm * 4;
    *(float4*)op = make_float4(acc[0][ji] + bl, acc[1][ji] + bl, acc[2][ji] + bl, acc[3][ji] + bl);
  }
}

// ---------------------------------------------------------------- launch
extern "C" void kernel_launch(void* const* d_in, const int* in_sizes, int n_in,
                              void* d_out, int out_size, void* d_ws, size_t ws_size,
                              hipStream_t stream) {
  const float* x_kv   = (const float*)d_in[0];
  const float* x_q    = (const float*)d_in[1];
  const float* w_spa  = (const float*)d_in[2];
  const float* w_kv   = (const float*)d_in[3];
  const float* b_kv   = (const float*)d_in[4];
  const float* w_q    = (const float*)d_in[5];
  const float* b_q    = (const float*)d_in[6];
  const float* w_proj = (const float*)d_in[7];
  const float* b_proj = (const float*)d_in[8];
  const float* w_dw   = (const float*)d_in[9];
  const float* b_dw   = (const float*)d_in[10];
  const float* w_pw   = (const float*)d_in[11];
  const float* b_pw   = (const float*)d_in[12];
  float* out = (float*)d_out;

  const size_t MB = 1024 * 1024;
  char* ws = (char*)d_ws;
  // layout: [0,16M) = v_nc(8M)+qh(8M), later reused as aoydw(16M)
  float* v_nc  = (float*)(ws);                 // (b,n,c)   dead after k_attn
  float* qh    = (float*)(ws + 8 * MB);        // (b,h,n,8) dead after k_attn
  float* aoydw = (float*)(ws);                 // (b,c512,n) written by k_merge/k_dw
  float* v_t   = (float*)(ws + 16 * MB);       // (b,c,n)   live through k_dw
  float* po    = (float*)(ws + 24 * MB);       // 2 x (bh,n,8) partial attn
  float* pse   = (float*)(ws + 40 * MB);       // 2 x (bh,n)
  float* k_g   = (float*)(ws + 42 * MB);       // (b,h,i,8)
  float* avgmx = (float*)(ws + 43 * MB);
  float* scores= (float*)(ws + 43 * MB + 65536);
  int*   idx   = (int*)  (ws + 43 * MB + 98304);

  k_reduce<<<32, 256, 0, stream>>>(x_kv, avgmx);
  k_spa<<<64, 256, 0, stream>>>(avgmx, w_spa, scores);
  k_topk<<<2, 1024, 0, stream>>>(scores, idx);
  k_qv<<<dim3(32, 2, 4), 256, 0, stream>>>(x_kv, x_q, w_kv, b_kv, w_q, b_q, v_nc, v_t, qh);
  k_projg<<<dim3(16, 4, 2), 256, 0, stream>>>(x_kv, w_kv, 512, b_kv, idx, k_g, KTOP);
  k_attn<<<dim3(64, 4, 2), 256, 0, stream>>>(qh, k_g, v_nc, idx, po, pse);
  k_merge<<<dim3(64, 16), 256, 0, stream>>>(po, pse, aoydw);
  k_dw<<<dim3(256, 2), 256, 0, stream>>>(v_t, w_dw, b_dw, aoydw);
  k_final<<<dim3(64, 2, 2), 256, 0, stream>>>(aoydw, w_proj, b_proj, w_pw, b_pw, out);
}

// Round 5
// 442.913 us; speedup vs baseline: 1.3933x; 1.0706x over previous
//
#include <hip/hip_runtime.h>
#include <hip/hip_bf16.h>

constexpr int CN   = 256;
constexpr int NV   = 4096;
constexpr int KTOP = 512;

// ---------------------------------------------------------------- K1: channel mean/max
__global__ void k_reduce(const float* __restrict__ xkv, float* __restrict__ avgmx) {
  int g = blockIdx.x * 256 + threadIdx.x;
  int b = g >> 12, n = g & 4095;
  const float* p = xkv + (size_t)b * CN * NV + n;
  float s = 0.f, m = -1e30f;
  for (int c = 0; c < CN; ++c) {
    float v = p[(size_t)c * NV];
    s += v; m = fmaxf(m, v);
  }
  avgmx[(b * 2 + 0) * NV + n] = s * (1.0f / 256.0f);
  avgmx[(b * 2 + 1) * NV + n] = m;
}

// ---------------------------------------------------------------- K2: 7x7x7 conv + sigmoid
__global__ void __launch_bounds__(256) k_spa(const float* __restrict__ avgmx,
                                             const float* __restrict__ wspa,
                                             float* __restrict__ scores) {
  __shared__ float vol[2 * 4096];
  __shared__ float ws[686];
  int b = blockIdx.x >> 5, chunk = blockIdx.x & 31;
  int tid = threadIdx.x;
  for (int t = tid; t < 8192; t += 256) vol[t] = avgmx[b * 8192 + t];
  for (int t = tid; t < 686; t += 256) ws[t] = wspa[t];
  __syncthreads();
  int ci = tid & 1;
  int n = chunk * 128 + (tid >> 1);
  int d = n >> 8, h = (n >> 4) & 15, w = n & 15;
  const float* vb = vol + ci * 4096;
  const float* wb = ws + ci * 343;
  float acc = 0.f;
  for (int kd = 0; kd < 7; ++kd) {
    int zd = d - 3 + kd; if ((unsigned)zd >= 16u) continue;
    for (int kh = 0; kh < 7; ++kh) {
      int zh = h - 3 + kh; if ((unsigned)zh >= 16u) continue;
      const float* row = vb + zd * 256 + zh * 16;
      const float* wr = wb + kd * 49 + kh * 7;
#pragma unroll
      for (int kw = 0; kw < 7; ++kw) {
        int zw = w - 3 + kw;
        if ((unsigned)zw < 16u) acc += row[zw] * wr[kw];
      }
    }
  }
  acc += __shfl_xor(acc, 1);
  if (ci == 0) scores[b * NV + n] = 1.0f / (1.0f + expf(-acc));
}

// ---------------------------------------------------------------- K3: top-512 radix-select
__global__ void __launch_bounds__(1024) k_topk(const float* __restrict__ scores,
                                               int* __restrict__ idx) {
  __shared__ unsigned sv[4096];
  __shared__ unsigned hist[256];
  __shared__ int sB;
  __shared__ unsigned sSub, scnt;
  int b = blockIdx.x, tid = threadIdx.x;
  for (int t = tid; t < 4096; t += 1024) sv[t] = __float_as_uint(scores[b * NV + t]);
  if (tid == 0) scnt = 0;
  unsigned prefix = 0;
  int r = 512;
  for (int shift = 24; shift >= 0; shift -= 8) {
    if (tid < 256) hist[tid] = 0;
    __syncthreads();
    unsigned maskhi = (shift == 24) ? 0u : (0xFFFFFFFFu << (shift + 8));
    for (int i = 0; i < 4; ++i) {
      unsigned v = sv[tid + i * 1024];
      if ((v & maskhi) == prefix) atomicAdd(&hist[(v >> shift) & 255], 1u);
    }
    __syncthreads();
    for (int off = 1; off < 256; off <<= 1) {
      unsigned add = 0;
      if (tid < 256 && tid + off < 256) add = hist[tid + off];
      __syncthreads();
      if (tid < 256) hist[tid] += add;
      __syncthreads();
    }
    if (tid < 256) {
      unsigned s = hist[tid];
      unsigned snext = (tid < 255) ? hist[tid + 1] : 0u;
      if (s >= (unsigned)r && snext < (unsigned)r) { sB = tid; sSub = snext; }
    }
    __syncthreads();
    prefix |= ((unsigned)sB) << shift;
    r -= (int)sSub;
    __syncthreads();
  }
  unsigned vstar = prefix;
  for (int i = 0; i < 4; ++i) {
    int t = tid + i * 1024;
    if (sv[t] > vstar) { unsigned p = atomicAdd(&scnt, 1u); idx[b * KTOP + p] = t; }
  }
  __syncthreads();
  int base = (int)scnt;
  for (int i = 0; i < 4; ++i) {
    int t = tid + i * 1024;
    if (sv[t] == vstar) {
      int rank = 0;
      for (int m = 0; m < t; ++m) rank += (sv[m] == vstar);
      if (rank < r) idx[b * KTOP + base + rank] = t;
    }
  }
}

// ---------------------------------------------------------------- K4: fused V+Q projection
__global__ void __launch_bounds__(256) k_qv(const float* __restrict__ xkv,
                                            const float* __restrict__ xq,
                                            const float* __restrict__ wkv,
                                            const float* __restrict__ bkv,
                                            const float* __restrict__ wq,
                                            const float* __restrict__ bq,
                                            float* __restrict__ v_nc,
                                            float* __restrict__ v_cn,
                                            float* __restrict__ qh) {
  __shared__ float Xs[32 * 132];
  __shared__ float Ws[32 * 140];
  int role = blockIdx.z;
  int b = role & 1;
  bool isQ = role >= 2;
  const float* X = (isQ ? xq : xkv) + (size_t)b * CN * NV;
  const float* W = isQ ? wq : (wkv + 256);
  int ldw = isQ ? 256 : 512;
  const float* bias = isQ ? bq : (bkv + 256);
  int m0 = blockIdx.x * 128, j0 = blockIdx.y * 128;
  int tid = threadIdx.x;
  int tm = tid >> 4, tj = tid & 15;
  int jb = tj * 8 + ((tj * 8) >> 5) * 4;
  float acc[8][8] = {};
  for (int c0 = 0; c0 < 256; c0 += 32) {
    __syncthreads();
#pragma unroll
    for (int i = 0; i < 4; ++i) {
      int id = i * 256 + tid;
      int cc = id >> 5, mg = id & 31;
      float4 v = *(const float4*)&X[(size_t)(c0 + cc) * NV + m0 + mg * 4];
      *(float4*)&Xs[cc * 132 + mg * 4] = v;
    }
#pragma unroll
    for (int i = 0; i < 4; ++i) {
      int id = i * 256 + tid;
      int cc = id >> 5, jg = id & 31;
      float4 v = *(const float4*)&W[(size_t)(c0 + cc) * ldw + j0 + jg * 4];
      *(float4*)&Ws[cc * 140 + jg * 4 + (jg >> 3) * 4] = v;
    }
    __syncthreads();
#pragma unroll 4
    for (int kk = 0; kk < 32; ++kk) {
      float4 a0 = *(const float4*)&Xs[kk * 132 + tm * 8];
      float4 a1 = *(const float4*)&Xs[kk * 132 + tm * 8 + 4];
      float4 b0 = *(const float4*)&Ws[kk * 140 + jb];
      float4 b1 = *(const float4*)&Ws[kk * 140 + jb + 4];
      float av[8] = {a0.x, a0.y, a0.z, a0.w, a1.x, a1.y, a1.z, a1.w};
      float bv[8] = {b0.x, b0.y, b0.z, b0.w, b1.x, b1.y, b1.z, b1.w};
#pragma unroll
      for (int mi = 0; mi < 8; ++mi)
#pragma unroll
        for (int ji = 0; ji < 8; ++ji)
          acc[mi][ji] = fmaf(av[mi], bv[ji], acc[mi][ji]);
    }
  }
  int j = j0 + tj * 8;
  float bl[8];
#pragma unroll
  for (int ji = 0; ji < 8; ++ji) bl[ji] = bias[j + ji];
#pragma unroll
  for (int mi = 0; mi < 8; ++mi)
#pragma unroll
    for (int ji = 0; ji < 8; ++ji) acc[mi][ji] += bl[ji];
  int nb = m0 + tm * 8;
  if (isQ) {
    int h = j >> 3;
    float* dst = qh + ((size_t)(b * 32 + h) * NV + nb) * 8;
#pragma unroll
    for (int mi = 0; mi < 8; ++mi) {
      *(float4*)&dst[mi * 8]     = make_float4(acc[mi][0], acc[mi][1], acc[mi][2], acc[mi][3]);
      *(float4*)&dst[mi * 8 + 4] = make_float4(acc[mi][4], acc[mi][5], acc[mi][6], acc[mi][7]);
    }
  } else {
#pragma unroll
    for (int mi = 0; mi < 8; ++mi) {
      float* d1 = v_nc + ((size_t)b * NV + nb + mi) * 256 + j;
      *(float4*)&d1[0] = make_float4(acc[mi][0], acc[mi][1], acc[mi][2], acc[mi][3]);
      *(float4*)&d1[4] = make_float4(acc[mi][4], acc[mi][5], acc[mi][6], acc[mi][7]);
    }
#pragma unroll
    for (int ji = 0; ji < 8; ++ji) {
      float* d2 = v_cn + ((size_t)(b * 256 + j + ji)) * NV + nb;
      *(float4*)&d2[0] = make_float4(acc[0][ji], acc[1][ji], acc[2][ji], acc[3][ji]);
      *(float4*)&d2[4] = make_float4(acc[4][ji], acc[5][ji], acc[6][ji], acc[7][ji]);
    }
  }
}

// ---------------------------------------------------------------- K5: gathered K projection
__global__ void k_projg(const float* __restrict__ X, const float* __restrict__ W, int ldw,
                        const float* __restrict__ bias, const int* __restrict__ map,
                        float* __restrict__ Y, int M) {
  __shared__ float Xs[32 * 33];
  __shared__ float Ws[32 * 64];
  __shared__ int nmap[32];
  int m0 = blockIdx.x * 32, j0 = blockIdx.y * 64, b = blockIdx.z;
  int tid = threadIdx.x;
  if (tid < 32) nmap[tid] = map[b * KTOP + m0 + tid];
  int mm = tid >> 3, tj = (tid & 7) * 8;
  float acc[8] = {};
  const float* Xb = X + (size_t)b * CN * NV;
  for (int c0 = 0; c0 < 256; c0 += 32) {
    __syncthreads();
    for (int t = tid; t < 1024; t += 256) {
      int cc = t >> 5, mmm = t & 31;
      Xs[cc * 33 + mmm] = Xb[(size_t)(c0 + cc) * NV + nmap[mmm]];
    }
    for (int t = tid; t < 2048; t += 256) {
      int cc = t >> 6, jj = t & 63;
      Ws[cc * 64 + jj] = W[(size_t)(c0 + cc) * ldw + j0 + jj];
    }
    __syncthreads();
    for (int cc = 0; cc < 32; ++cc) {
      float xv = Xs[cc * 33 + mm];
      float4 w0 = *(const float4*)&Ws[cc * 64 + tj];
      float4 w1 = *(const float4*)&Ws[cc * 64 + tj + 4];
      acc[0] += xv * w0.x; acc[1] += xv * w0.y; acc[2] += xv * w0.z; acc[3] += xv * w0.w;
      acc[4] += xv * w1.x; acc[5] += xv * w1.y; acc[6] += xv * w1.z; acc[7] += xv * w1.w;
    }
  }
  int m = m0 + mm, j = j0 + tj;
  float* outp = Y + ((size_t)(b * 32 + (j >> 3)) * M + m) * 8;
#pragma unroll
  for (int jj = 0; jj < 8; ++jj) outp[jj] = acc[jj] + bias[j + jj];
}

// ---------------------------------------------------------------- K6: attention
// All 512 keys in LDS; wave-pairs split keys (tid<128 -> keys 0..255, tid>=128 -> 256..511).
// Partials combined through LDS (Ks reused), normalized, written directly to aoydw (b,c,n).
__global__ void __launch_bounds__(256) k_attn(const float* __restrict__ qh,
                                              const float* __restrict__ kgh,
                                              const float* __restrict__ v_nc,
                                              const int* __restrict__ idx,
                                              float* __restrict__ aoydw) {
  __shared__ float Ks[512 * 8];
  __shared__ float Vs[512 * 8];
  int bh = blockIdx.x;
  int b = bh >> 5, h = bh & 31;
  int tid = threadIdx.x;
  const float kscale = 0.35355339059327373f * 1.4426950408889634f;  // 1/sqrt(8)*log2(e)
  const float* kb = kgh + (size_t)bh * KTOP * 8;
  for (int t = tid; t < 4096; t += 256) Ks[t] = kb[t] * kscale;
  const int* ib = idx + b * KTOP;
  for (int t = tid; t < 4096; t += 256) {
    int i = t >> 3, d = t & 7;
    Vs[t] = v_nc[((size_t)b * NV + ib[i]) * 256 + h * 8 + d];
  }
  __syncthreads();
  int ksplit = tid >> 7;       // 0: keys 0-255, 1: keys 256-511 (wave-uniform)
  int nl = tid & 127;
  int n0 = blockIdx.y * 512 + nl;
  const float* qb = qh + (size_t)bh * NV * 8;
  float4 qa[4], qc[4], oa[4], oc[4];
  float se[4];
#pragma unroll
  for (int qq = 0; qq < 4; ++qq) {
    const float4* qp = (const float4*)(qb + (size_t)(n0 + qq * 128) * 8);
    qa[qq] = qp[0]; qc[qq] = qp[1];
    oa[qq] = make_float4(0.f, 0.f, 0.f, 0.f);
    oc[qq] = make_float4(0.f, 0.f, 0.f, 0.f);
    se[qq] = 0.f;
  }
  int kbase = ksplit * 256;
#pragma unroll 2
  for (int i = 0; i < 256; ++i) {
    int kk = kbase + i;
    float4 ka = *(const float4*)&Ks[kk * 8];
    float4 kc = *(const float4*)&Ks[kk * 8 + 4];
    float4 va = *(const float4*)&Vs[kk * 8];
    float4 vc = *(const float4*)&Vs[kk * 8 + 4];
#pragma unroll
    for (int qq = 0; qq < 4; ++qq) {
      float d0 = fmaf(qa[qq].y, ka.y, qa[qq].x * ka.x);
      float d1 = fmaf(qa[qq].w, ka.w, qa[qq].z * ka.z);
      float d2 = fmaf(qc[qq].y, kc.y, qc[qq].x * kc.x);
      float d3 = fmaf(qc[qq].w, kc.w, qc[qq].z * kc.z);
      float e = exp2f((d0 + d1) + (d2 + d3));
      se[qq] += e;
      oa[qq].x = fmaf(e, va.x, oa[qq].x); oa[qq].y = fmaf(e, va.y, oa[qq].y);
      oa[qq].z = fmaf(e, va.z, oa[qq].z); oa[qq].w = fmaf(e, va.w, oa[qq].w);
      oc[qq].x = fmaf(e, vc.x, oc[qq].x); oc[qq].y = fmaf(e, vc.y, oc[qq].y);
      oc[qq].z = fmaf(e, vc.z, oc[qq].z); oc[qq].w = fmaf(e, vc.w, oc[qq].w);
    }
  }
  __syncthreads();            // everyone done reading Ks/Vs
  if (ksplit) {               // upper half dumps partials into Ks (o) and Vs (se)
#pragma unroll
    for (int qq = 0; qq < 4; ++qq) {
      *(float4*)&Ks[(qq * 128 + nl) * 8]     = oa[qq];
      *(float4*)&Ks[(qq * 128 + nl) * 8 + 4] = oc[qq];
      Vs[qq * 128 + nl] = se[qq];
    }
  }
  __syncthreads();
  if (!ksplit) {
#pragma unroll
    for (int qq = 0; qq < 4; ++qq) {
      float4 pa = *(const float4*)&Ks[(qq * 128 + nl) * 8];
      float4 pc = *(const float4*)&Ks[(qq * 128 + nl) * 8 + 4];
      float inv = 1.0f / (se[qq] + Vs[qq * 128 + nl]);
      float r[8];
      r[0] = (oa[qq].x + pa.x) * inv; r[1] = (oa[qq].y + pa.y) * inv;
      r[2] = (oa[qq].z + pa.z) * inv; r[3] = (oa[qq].w + pa.w) * inv;
      r[4] = (oc[qq].x + pc.x) * inv; r[5] = (oc[qq].y + pc.y) * inv;
      r[6] = (oc[qq].z + pc.z) * inv; r[7] = (oc[qq].w + pc.w) * inv;
      int n = n0 + qq * 128;
#pragma unroll
      for (int d = 0; d < 8; ++d)
        aoydw[((size_t)(b * 512 + h * 8 + d)) * NV + n] = r[d];
    }
  }
}

// ---------------------------------------------------------------- K7: depthwise conv -> aoydw rows c>=256
// plane staged in LDS; taps fully unrolled so wr[] stays in registers (round-4 bug: scratch spill)
__global__ void __launch_bounds__(256) k_dw(const float* __restrict__ vt,
                                            const float* __restrict__ wdw,
                                            const float* __restrict__ bdw,
                                            float* __restrict__ aoydw) {
  __shared__ float pl[4096];
  int c = blockIdx.x, b = blockIdx.y;
  const float* plane = vt + ((size_t)(b * 256 + c)) * NV;
  int tid = threadIdx.x;
  for (int i = tid; i < 4096; i += 256) pl[i] = plane[i];
  float wr[27];
#pragma unroll
  for (int i = 0; i < 27; ++i) wr[i] = wdw[c * 27 + i];
  float bias = bdw[c];
  __syncthreads();
  float* dst = aoydw + ((size_t)(b * 512 + 256 + c)) * NV;
  for (int i = 0; i < 16; ++i) {
    int n = i * 256 + tid;
    int d = n >> 8, h = (n >> 4) & 15, w = n & 15;
    float acc = bias;
#pragma unroll
    for (int kd = 0; kd < 3; ++kd) {
      int zd = d - 1 + kd;
      bool okd = (unsigned)zd < 16u;
#pragma unroll
      for (int kh = 0; kh < 3; ++kh) {
        int zh = h - 1 + kh;
        bool okh = okd && ((unsigned)zh < 16u);
#pragma unroll
        for (int kw = 0; kw < 3; ++kw) {
          int zw = w - 1 + kw;
          bool ok = okh && ((unsigned)zw < 16u);
          int nz = ok ? (zd * 256 + zh * 16 + zw) : 0;
          float v = pl[nz];
          acc = fmaf(ok ? v : 0.f, wr[kd * 9 + kh * 3 + kw], acc);
        }
      }
    }
    dst[n] = acc;
  }
}

// ---------------------------------------------------------------- K8: final GEMM, K=512
__global__ void __launch_bounds__(256) k_final(const float* __restrict__ aoydw,
                                               const float* __restrict__ wproj,
                                               const float* __restrict__ bproj,
                                               const float* __restrict__ wpw,
                                               const float* __restrict__ bpw,
                                               float* __restrict__ out) {
  __shared__ float Xs[32 * 68];
  __shared__ float Ws[32 * 140];
  int n0 = blockIdx.x * 64, j0 = blockIdx.y * 128, b = blockIdx.z;
  int tid = threadIdx.x;
  int tm = tid >> 4, tj = tid & 15;
  int jb = tj * 8 + ((tj * 8) >> 5) * 4;
  float acc[4][8] = {};
  for (int c0 = 0; c0 < 512; c0 += 32) {
    __syncthreads();
#pragma unroll
    for (int i = 0; i < 2; ++i) {
      int id = i * 256 + tid;
      int cc = id >> 4, ng = id & 15;
      float4 v = *(const float4*)&aoydw[((size_t)(b * 512 + c0 + cc)) * NV + n0 + ng * 4];
      *(float4*)&Xs[cc * 68 + ng * 4] = v;
    }
    if (c0 < 256) {
#pragma unroll
      for (int i = 0; i < 4; ++i) {
        int id = i * 256 + tid;
        int cc = id >> 5, jg = id & 31;
        float4 v = *(const float4*)&wproj[(size_t)(c0 + cc) * 256 + j0 + jg * 4];
        *(float4*)&Ws[cc * 140 + jg * 4 + (jg >> 3) * 4] = v;
      }
    } else {
#pragma unroll
      for (int i = 0; i < 4; ++i) {
        int id = i * 256 + tid;
        int jj = id >> 3, cg = id & 7;
        float4 v = *(const float4*)&wpw[(size_t)(j0 + jj) * 256 + (c0 - 256) + cg * 4];
        int jjs = jj + (jj >> 5) * 4;
        Ws[(cg * 4 + 0) * 140 + jjs] = v.x;
        Ws[(cg * 4 + 1) * 140 + jjs] = v.y;
        Ws[(cg * 4 + 2) * 140 + jjs] = v.z;
        Ws[(cg * 4 + 3) * 140 + jjs] = v.w;
      }
    }
    __syncthreads();
#pragma unroll 4
    for (int kk = 0; kk < 32; ++kk) {
      float4 a0 = *(const float4*)&Xs[kk * 68 + tm * 4];
      float4 b0 = *(const float4*)&Ws[kk * 140 + jb];
      float4 b1 = *(const float4*)&Ws[kk * 140 + jb + 4];
      float av[4] = {a0.x, a0.y, a0.z, a0.w};
      float bv[8] = {b0.x, b0.y, b0.z, b0.w, b1.x, b1.y, b1.z, b1.w};
#pragma unroll
      for (int mi = 0; mi < 4; ++mi)
#pragma unroll
        for (int ji = 0; ji < 8; ++ji)
          acc[mi][ji] = fmaf(av[mi], bv[ji], acc[mi][ji]);
    }
  }
  int j = j0 + tj * 8;
#pragma unroll
  for (int ji = 0; ji < 8; ++ji) {
    float bl = bproj[j + ji] + bpw[j + ji];
    float* op = out + ((size_t)(b * 256 + j + ji)) * NV + n0 + tm * 4;
    *(float4*)op = make_float4(acc[0][ji] + bl, acc[1][ji] + bl, acc[2][ji] + bl, acc[3][ji] + bl);
  }
}

// ---------------------------------------------------------------- launch
extern "C" void kernel_launch(void* const* d_in, const int* in_sizes, int n_in,
                              void* d_out, int out_size, void* d_ws, size_t ws_size,
                              hipStream_t stream) {
  const float* x_kv   = (const float*)d_in[0];
  const float* x_q    = (const float*)d_in[1];
  const float* w_spa  = (const float*)d_in[2];
  const float* w_kv   = (const float*)d_in[3];
  const float* b_kv   = (const float*)d_in[4];
  const float* w_q    = (const float*)d_in[5];
  const float* b_q    = (const float*)d_in[6];
  const float* w_proj = (const float*)d_in[7];
  const float* b_proj = (const float*)d_in[8];
  const float* w_dw   = (const float*)d_in[9];
  const float* b_dw   = (const float*)d_in[10];
  const float* w_pw   = (const float*)d_in[11];
  const float* b_pw   = (const float*)d_in[12];
  float* out = (float*)d_out;

  const size_t MB = 1024 * 1024;
  char* ws = (char*)d_ws;
  float* v_nc  = (float*)(ws);                 // (b,n,c)     8 MB
  float* qh    = (float*)(ws + 8 * MB);        // (b,h,n,8)   8 MB
  float* v_t   = (float*)(ws + 16 * MB);       // (b,c,n)     8 MB
  float* aoydw = (float*)(ws + 24 * MB);       // (b,c512,n) 16 MB
  float* k_g   = (float*)(ws + 40 * MB);       // (b,h,i,8)   1 MB
  float* avgmx = (float*)(ws + 41 * MB);
  float* scores= (float*)(ws + 41 * MB + 65536);
  int*   idx   = (int*)  (ws + 41 * MB + 98304);

  k_reduce<<<32, 256, 0, stream>>>(x_kv, avgmx);
  k_spa<<<64, 256, 0, stream>>>(avgmx, w_spa, scores);
  k_topk<<<2, 1024, 0, stream>>>(scores, idx);
  k_qv<<<dim3(32, 2, 4), 256, 0, stream>>>(x_kv, x_q, w_kv, b_kv, w_q, b_q, v_nc, v_t, qh);
  k_projg<<<dim3(16, 4, 2), 256, 0, stream>>>(x_kv, w_kv, 512, b_kv, idx, k_g, KTOP);
  k_attn<<<dim3(64, 8), 256, 0, stream>>>(qh, k_g, v_nc, idx, aoydw);
  k_dw<<<dim3(256, 2), 256, 0, stream>>>(v_t, w_dw, b_dw, aoydw);
  k_final<<<dim3(64, 2, 2), 256, 0, stream>>>(aoydw, w_proj, b_proj, w_pw, b_pw, out);
}

// Round 6
// 416.676 us; speedup vs baseline: 1.4810x; 1.0630x over previous
//
#include <hip/hip_runtime.h>
#include <hip/hip_bf16.h>

constexpr int CN   = 256;
constexpr int NV   = 4096;
constexpr int KTOP = 512;

// ---------------------------------------------------------------- K1: channel mean/max
__global__ void k_reduce(const float* __restrict__ xkv, float* __restrict__ avgmx) {
  int g = blockIdx.x * 256 + threadIdx.x;
  int b = g >> 12, n = g & 4095;
  const float* p = xkv + (size_t)b * CN * NV + n;
  float s = 0.f, m = -1e30f;
  for (int c = 0; c < CN; ++c) {
    float v = p[(size_t)c * NV];
    s += v; m = fmaxf(m, v);
  }
  avgmx[(b * 2 + 0) * NV + n] = s * (1.0f / 256.0f);
  avgmx[(b * 2 + 1) * NV + n] = m;
}

// ---------------------------------------------------------------- K2: 7x7x7 conv + sigmoid
__global__ void __launch_bounds__(256) k_spa(const float* __restrict__ avgmx,
                                             const float* __restrict__ wspa,
                                             float* __restrict__ scores) {
  __shared__ float vol[2 * 4096];
  __shared__ float ws[686];
  int b = blockIdx.x >> 5, chunk = blockIdx.x & 31;
  int tid = threadIdx.x;
  for (int t = tid; t < 8192; t += 256) vol[t] = avgmx[b * 8192 + t];
  for (int t = tid; t < 686; t += 256) ws[t] = wspa[t];
  __syncthreads();
  int ci = tid & 1;
  int n = chunk * 128 + (tid >> 1);
  int d = n >> 8, h = (n >> 4) & 15, w = n & 15;
  const float* vb = vol + ci * 4096;
  const float* wb = ws + ci * 343;
  float acc = 0.f;
  for (int kd = 0; kd < 7; ++kd) {
    int zd = d - 3 + kd; if ((unsigned)zd >= 16u) continue;
    for (int kh = 0; kh < 7; ++kh) {
      int zh = h - 3 + kh; if ((unsigned)zh >= 16u) continue;
      const float* row = vb + zd * 256 + zh * 16;
      const float* wr = wb + kd * 49 + kh * 7;
#pragma unroll
      for (int kw = 0; kw < 7; ++kw) {
        int zw = w - 3 + kw;
        if ((unsigned)zw < 16u) acc += row[zw] * wr[kw];
      }
    }
  }
  acc += __shfl_xor(acc, 1);
  if (ci == 0) scores[b * NV + n] = 1.0f / (1.0f + expf(-acc));
}

// ---------------------------------------------------------------- K3: top-512 radix-select
__global__ void __launch_bounds__(1024) k_topk(const float* __restrict__ scores,
                                               int* __restrict__ idx) {
  __shared__ unsigned sv[4096];
  __shared__ unsigned hist[256];
  __shared__ int sB;
  __shared__ unsigned sSub, scnt;
  int b = blockIdx.x, tid = threadIdx.x;
  for (int t = tid; t < 4096; t += 1024) sv[t] = __float_as_uint(scores[b * NV + t]);
  if (tid == 0) scnt = 0;
  unsigned prefix = 0;
  int r = 512;
  for (int shift = 24; shift >= 0; shift -= 8) {
    if (tid < 256) hist[tid] = 0;
    __syncthreads();
    unsigned maskhi = (shift == 24) ? 0u : (0xFFFFFFFFu << (shift + 8));
    for (int i = 0; i < 4; ++i) {
      unsigned v = sv[tid + i * 1024];
      if ((v & maskhi) == prefix) atomicAdd(&hist[(v >> shift) & 255], 1u);
    }
    __syncthreads();
    for (int off = 1; off < 256; off <<= 1) {
      unsigned add = 0;
      if (tid < 256 && tid + off < 256) add = hist[tid + off];
      __syncthreads();
      if (tid < 256) hist[tid] += add;
      __syncthreads();
    }
    if (tid < 256) {
      unsigned s = hist[tid];
      unsigned snext = (tid < 255) ? hist[tid + 1] : 0u;
      if (s >= (unsigned)r && snext < (unsigned)r) { sB = tid; sSub = snext; }
    }
    __syncthreads();
    prefix |= ((unsigned)sB) << shift;
    r -= (int)sSub;
    __syncthreads();
  }
  unsigned vstar = prefix;
  for (int i = 0; i < 4; ++i) {
    int t = tid + i * 1024;
    if (sv[t] > vstar) { unsigned p = atomicAdd(&scnt, 1u); idx[b * KTOP + p] = t; }
  }
  __syncthreads();
  int base = (int)scnt;
  for (int i = 0; i < 4; ++i) {
    int t = tid + i * 1024;
    if (sv[t] == vstar) {
      int rank = 0;
      for (int m = 0; m < t; ++m) rank += (sv[m] == vstar);
      if (rank < r) idx[b * KTOP + base + rank] = t;
    }
  }
}

// ---------------------------------------------------------------- K4: fused V+Q projection
__global__ void __launch_bounds__(256) k_qv(const float* __restrict__ xkv,
                                            const float* __restrict__ xq,
                                            const float* __restrict__ wkv,
                                            const float* __restrict__ bkv,
                                            const float* __restrict__ wq,
                                            const float* __restrict__ bq,
                                            float* __restrict__ v_nc,
                                            float* __restrict__ v_cn,
                                            float* __restrict__ qh) {
  __shared__ float Xs[32 * 132];
  __shared__ float Ws[32 * 140];
  int role = blockIdx.z;
  int b = role & 1;
  bool isQ = role >= 2;
  const float* X = (isQ ? xq : xkv) + (size_t)b * CN * NV;
  const float* W = isQ ? wq : (wkv + 256);
  int ldw = isQ ? 256 : 512;
  const float* bias = isQ ? bq : (bkv + 256);
  int m0 = blockIdx.x * 128, j0 = blockIdx.y * 128;
  int tid = threadIdx.x;
  int tm = tid >> 4, tj = tid & 15;
  int jb = tj * 8 + ((tj * 8) >> 5) * 4;
  float acc[8][8] = {};
  for (int c0 = 0; c0 < 256; c0 += 32) {
    __syncthreads();
#pragma unroll
    for (int i = 0; i < 4; ++i) {
      int id = i * 256 + tid;
      int cc = id >> 5, mg = id & 31;
      float4 v = *(const float4*)&X[(size_t)(c0 + cc) * NV + m0 + mg * 4];
      *(float4*)&Xs[cc * 132 + mg * 4] = v;
    }
#pragma unroll
    for (int i = 0; i < 4; ++i) {
      int id = i * 256 + tid;
      int cc = id >> 5, jg = id & 31;
      float4 v = *(const float4*)&W[(size_t)(c0 + cc) * ldw + j0 + jg * 4];
      *(float4*)&Ws[cc * 140 + jg * 4 + (jg >> 3) * 4] = v;
    }
    __syncthreads();
#pragma unroll 4
    for (int kk = 0; kk < 32; ++kk) {
      float4 a0 = *(const float4*)&Xs[kk * 132 + tm * 8];
      float4 a1 = *(const float4*)&Xs[kk * 132 + tm * 8 + 4];
      float4 b0 = *(const float4*)&Ws[kk * 140 + jb];
      float4 b1 = *(const float4*)&Ws[kk * 140 + jb + 4];
      float av[8] = {a0.x, a0.y, a0.z, a0.w, a1.x, a1.y, a1.z, a1.w};
      float bv[8] = {b0.x, b0.y, b0.z, b0.w, b1.x, b1.y, b1.z, b1.w};
#pragma unroll
      for (int mi = 0; mi < 8; ++mi)
#pragma unroll
        for (int ji = 0; ji < 8; ++ji)
          acc[mi][ji] = fmaf(av[mi], bv[ji], acc[mi][ji]);
    }
  }
  int j = j0 + tj * 8;
  float bl[8];
#pragma unroll
  for (int ji = 0; ji < 8; ++ji) bl[ji] = bias[j + ji];
#pragma unroll
  for (int mi = 0; mi < 8; ++mi)
#pragma unroll
    for (int ji = 0; ji < 8; ++ji) acc[mi][ji] += bl[ji];
  int nb = m0 + tm * 8;
  if (isQ) {
    int h = j >> 3;
    float* dst = qh + ((size_t)(b * 32 + h) * NV + nb) * 8;
#pragma unroll
    for (int mi = 0; mi < 8; ++mi) {
      *(float4*)&dst[mi * 8]     = make_float4(acc[mi][0], acc[mi][1], acc[mi][2], acc[mi][3]);
      *(float4*)&dst[mi * 8 + 4] = make_float4(acc[mi][4], acc[mi][5], acc[mi][6], acc[mi][7]);
    }
  } else {
#pragma unroll
    for (int mi = 0; mi < 8; ++mi) {
      float* d1 = v_nc + ((size_t)b * NV + nb + mi) * 256 + j;
      *(float4*)&d1[0] = make_float4(acc[mi][0], acc[mi][1], acc[mi][2], acc[mi][3]);
      *(float4*)&d1[4] = make_float4(acc[mi][4], acc[mi][5], acc[mi][6], acc[mi][7]);
    }
#pragma unroll
    for (int ji = 0; ji < 8; ++ji) {
      float* d2 = v_cn + ((size_t)(b * 256 + j + ji)) * NV + nb;
      *(float4*)&d2[0] = make_float4(acc[0][ji], acc[1][ji], acc[2][ji], acc[3][ji]);
      *(float4*)&d2[4] = make_float4(acc[4][ji], acc[5][ji], acc[6][ji], acc[7][ji]);
    }
  }
}

// ---------------------------------------------------------------- K5: gathered K projection
__global__ void k_projg(const float* __restrict__ X, const float* __restrict__ W, int ldw,
                        const float* __restrict__ bias, const int* __restrict__ map,
                        float* __restrict__ Y, int M) {
  __shared__ float Xs[32 * 33];
  __shared__ float Ws[32 * 64];
  __shared__ int nmap[32];
  int m0 = blockIdx.x * 32, j0 = blockIdx.y * 64, b = blockIdx.z;
  int tid = threadIdx.x;
  if (tid < 32) nmap[tid] = map[b * KTOP + m0 + tid];
  int mm = tid >> 3, tj = (tid & 7) * 8;
  float acc[8] = {};
  const float* Xb = X + (size_t)b * CN * NV;
  for (int c0 = 0; c0 < 256; c0 += 32) {
    __syncthreads();
    for (int t = tid; t < 1024; t += 256) {
      int cc = t >> 5, mmm = t & 31;
      Xs[cc * 33 + mmm] = Xb[(size_t)(c0 + cc) * NV + nmap[mmm]];
    }
    for (int t = tid; t < 2048; t += 256) {
      int cc = t >> 6, jj = t & 63;
      Ws[cc * 64 + jj] = W[(size_t)(c0 + cc) * ldw + j0 + jj];
    }
    __syncthreads();
    for (int cc = 0; cc < 32; ++cc) {
      float xv = Xs[cc * 33 + mm];
      float4 w0 = *(const float4*)&Ws[cc * 64 + tj];
      float4 w1 = *(const float4*)&Ws[cc * 64 + tj + 4];
      acc[0] += xv * w0.x; acc[1] += xv * w0.y; acc[2] += xv * w0.z; acc[3] += xv * w0.w;
      acc[4] += xv * w1.x; acc[5] += xv * w1.y; acc[6] += xv * w1.z; acc[7] += xv * w1.w;
    }
  }
  int m = m0 + mm, j = j0 + tj;
  float* outp = Y + ((size_t)(b * 32 + (j >> 3)) * M + m) * 8;
#pragma unroll
  for (int jj = 0; jj < 8; ++jj) outp[jj] = acc[jj] + bias[j + jj];
}

// ---------------------------------------------------------------- K6: attention
// 2 queries/thread (low VGPR state), all 512 keys per thread, no combine.
// Writes normalized output directly to aoydw (b,c,n).
__global__ void __launch_bounds__(256) k_attn(const float* __restrict__ qh,
                                              const float* __restrict__ kgh,
                                              const float* __restrict__ v_nc,
                                              const int* __restrict__ idx,
                                              float* __restrict__ aoydw) {
  __shared__ float Ks[512 * 8];
  __shared__ float Vs[512 * 8];
  int bh = blockIdx.x;
  int b = bh >> 5, h = bh & 31;
  int tid = threadIdx.x;
  const float kscale = 0.35355339059327373f * 1.4426950408889634f;  // 1/sqrt(8)*log2(e)
  const float* kb = kgh + (size_t)bh * KTOP * 8;
  for (int t = tid; t < 4096; t += 256) Ks[t] = kb[t] * kscale;
  const int* ib = idx + b * KTOP;
  for (int t = tid; t < 4096; t += 256) {
    int i = t >> 3, d = t & 7;
    Vs[t] = v_nc[((size_t)b * NV + ib[i]) * 256 + h * 8 + d];
  }
  __syncthreads();
  int n0 = blockIdx.y * 512 + tid;
  const float* qb = qh + (size_t)bh * NV * 8;
  float4 qa[2], qc[2], oa[2], oc[2];
  float se[2];
#pragma unroll
  for (int qq = 0; qq < 2; ++qq) {
    const float4* qp = (const float4*)(qb + (size_t)(n0 + qq * 256) * 8);
    qa[qq] = qp[0]; qc[qq] = qp[1];
    oa[qq] = make_float4(0.f, 0.f, 0.f, 0.f);
    oc[qq] = make_float4(0.f, 0.f, 0.f, 0.f);
    se[qq] = 0.f;
  }
#pragma unroll 2
  for (int i = 0; i < 512; ++i) {
    float4 ka = *(const float4*)&Ks[i * 8];
    float4 kc = *(const float4*)&Ks[i * 8 + 4];
    float4 va = *(const float4*)&Vs[i * 8];
    float4 vc = *(const float4*)&Vs[i * 8 + 4];
#pragma unroll
    for (int qq = 0; qq < 2; ++qq) {
      float d0 = qa[qq].x * ka.x;
      d0 = fmaf(qa[qq].y, ka.y, d0);
      d0 = fmaf(qa[qq].z, ka.z, d0);
      d0 = fmaf(qa[qq].w, ka.w, d0);
      d0 = fmaf(qc[qq].x, kc.x, d0);
      d0 = fmaf(qc[qq].y, kc.y, d0);
      d0 = fmaf(qc[qq].z, kc.z, d0);
      d0 = fmaf(qc[qq].w, kc.w, d0);
      float e = exp2f(d0);
      se[qq] += e;
      oa[qq].x = fmaf(e, va.x, oa[qq].x); oa[qq].y = fmaf(e, va.y, oa[qq].y);
      oa[qq].z = fmaf(e, va.z, oa[qq].z); oa[qq].w = fmaf(e, va.w, oa[qq].w);
      oc[qq].x = fmaf(e, vc.x, oc[qq].x); oc[qq].y = fmaf(e, vc.y, oc[qq].y);
      oc[qq].z = fmaf(e, vc.z, oc[qq].z); oc[qq].w = fmaf(e, vc.w, oc[qq].w);
    }
  }
#pragma unroll
  for (int qq = 0; qq < 2; ++qq) {
    float inv = 1.0f / se[qq];
    float r[8];
    r[0] = oa[qq].x * inv; r[1] = oa[qq].y * inv; r[2] = oa[qq].z * inv; r[3] = oa[qq].w * inv;
    r[4] = oc[qq].x * inv; r[5] = oc[qq].y * inv; r[6] = oc[qq].z * inv; r[7] = oc[qq].w * inv;
    int n = n0 + qq * 256;
#pragma unroll
    for (int d = 0; d < 8; ++d)
      aoydw[((size_t)(b * 512 + h * 8 + d)) * NV + n] = r[d];
  }
}

// ---------------------------------------------------------------- K7: depthwise conv -> aoydw rows c>=256
__global__ void __launch_bounds__(256) k_dw(const float* __restrict__ vt,
                                            const float* __restrict__ wdw,
                                            const float* __restrict__ bdw,
                                            float* __restrict__ aoydw) {
  __shared__ float pl[4096];
  int c = blockIdx.x, b = blockIdx.y;
  const float* plane = vt + ((size_t)(b * 256 + c)) * NV;
  int tid = threadIdx.x;
  for (int i = tid; i < 4096; i += 256) pl[i] = plane[i];
  float wr[27];
#pragma unroll
  for (int i = 0; i < 27; ++i) wr[i] = wdw[c * 27 + i];
  float bias = bdw[c];
  __syncthreads();
  float* dst = aoydw + ((size_t)(b * 512 + 256 + c)) * NV;
  for (int i = 0; i < 16; ++i) {
    int n = i * 256 + tid;
    int d = n >> 8, h = (n >> 4) & 15, w = n & 15;
    float acc = bias;
#pragma unroll
    for (int kd = 0; kd < 3; ++kd) {
      int zd = d - 1 + kd;
      bool okd = (unsigned)zd < 16u;
#pragma unroll
      for (int kh = 0; kh < 3; ++kh) {
        int zh = h - 1 + kh;
        bool okh = okd && ((unsigned)zh < 16u);
#pragma unroll
        for (int kw = 0; kw < 3; ++kw) {
          int zw = w - 1 + kw;
          bool ok = okh && ((unsigned)zw < 16u);
          int nz = ok ? (zd * 256 + zh * 16 + zw) : 0;
          float v = pl[nz];
          acc = fmaf(ok ? v : 0.f, wr[kd * 9 + kh * 3 + kw], acc);
        }
      }
    }
    dst[n] = acc;
  }
}

// ---------------------------------------------------------------- K8: final GEMM, K=512
__global__ void __launch_bounds__(256) k_final(const float* __restrict__ aoydw,
                                               const float* __restrict__ wproj,
                                               const float* __restrict__ bproj,
                                               const float* __restrict__ wpw,
                                               const float* __restrict__ bpw,
                                               float* __restrict__ out) {
  __shared__ float Xs[32 * 68];
  __shared__ float Ws[32 * 140];
  int n0 = blockIdx.x * 64, j0 = blockIdx.y * 128, b = blockIdx.z;
  int tid = threadIdx.x;
  int tm = tid >> 4, tj = tid & 15;
  int jb = tj * 8 + ((tj * 8) >> 5) * 4;
  float acc[4][8] = {};
  for (int c0 = 0; c0 < 512; c0 += 32) {
    __syncthreads();
#pragma unroll
    for (int i = 0; i < 2; ++i) {
      int id = i * 256 + tid;
      int cc = id >> 4, ng = id & 15;
      float4 v = *(const float4*)&aoydw[((size_t)(b * 512 + c0 + cc)) * NV + n0 + ng * 4];
      *(float4*)&Xs[cc * 68 + ng * 4] = v;
    }
    if (c0 < 256) {
#pragma unroll
      for (int i = 0; i < 4; ++i) {
        int id = i * 256 + tid;
        int cc = id >> 5, jg = id & 31;
        float4 v = *(const float4*)&wproj[(size_t)(c0 + cc) * 256 + j0 + jg * 4];
        *(float4*)&Ws[cc * 140 + jg * 4 + (jg >> 3) * 4] = v;
      }
    } else {
#pragma unroll
      for (int i = 0; i < 4; ++i) {
        int id = i * 256 + tid;
        int jj = id >> 3, cg = id & 7;
        float4 v = *(const float4*)&wpw[(size_t)(j0 + jj) * 256 + (c0 - 256) + cg * 4];
        int jjs = jj + (jj >> 5) * 4;
        Ws[(cg * 4 + 0) * 140 + jjs] = v.x;
        Ws[(cg * 4 + 1) * 140 + jjs] = v.y;
        Ws[(cg * 4 + 2) * 140 + jjs] = v.z;
        Ws[(cg * 4 + 3) * 140 + jjs] = v.w;
      }
    }
    __syncthreads();
#pragma unroll 4
    for (int kk = 0; kk < 32; ++kk) {
      float4 a0 = *(const float4*)&Xs[kk * 68 + tm * 4];
      float4 b0 = *(const float4*)&Ws[kk * 140 + jb];
      float4 b1 = *(const float4*)&Ws[kk * 140 + jb + 4];
      float av[4] = {a0.x, a0.y, a0.z, a0.w};
      float bv[8] = {b0.x, b0.y, b0.z, b0.w, b1.x, b1.y, b1.z, b1.w};
#pragma unroll
      for (int mi = 0; mi < 4; ++mi)
#pragma unroll
        for (int ji = 0; ji < 8; ++ji)
          acc[mi][ji] = fmaf(av[mi], bv[ji], acc[mi][ji]);
    }
  }
  int j = j0 + tj * 8;
#pragma unroll
  for (int ji = 0; ji < 8; ++ji) {
    float bl = bproj[j + ji] + bpw[j + ji];
    float* op = out + ((size_t)(b * 256 + j + ji)) * NV + n0 + tm * 4;
    *(float4*)op = make_float4(acc[0][ji] + bl, acc[1][ji] + bl, acc[2][ji] + bl, acc[3][ji] + bl);
  }
}

// ---------------------------------------------------------------- launch
extern "C" void kernel_launch(void* const* d_in, const int* in_sizes, int n_in,
                              void* d_out, int out_size, void* d_ws, size_t ws_size,
                              hipStream_t stream) {
  const float* x_kv   = (const float*)d_in[0];
  const float* x_q    = (const float*)d_in[1];
  const float* w_spa  = (const float*)d_in[2];
  const float* w_kv   = (const float*)d_in[3];
  const float* b_kv   = (const float*)d_in[4];
  const float* w_q    = (const float*)d_in[5];
  const float* b_q    = (const float*)d_in[6];
  const float* w_proj = (const float*)d_in[7];
  const float* b_proj = (const float*)d_in[8];
  const float* w_dw   = (const float*)d_in[9];
  const float* b_dw   = (const float*)d_in[10];
  const float* w_pw   = (const float*)d_in[11];
  const float* b_pw   = (const float*)d_in[12];
  float* out = (float*)d_out;

  const size_t MB = 1024 * 1024;
  char* ws = (char*)d_ws;
  float* v_nc  = (float*)(ws);                 // (b,n,c)     8 MB
  float* qh    = (float*)(ws + 8 * MB);        // (b,h,n,8)   8 MB
  float* v_t   = (float*)(ws + 16 * MB);       // (b,c,n)     8 MB
  float* aoydw = (float*)(ws + 24 * MB);       // (b,c512,n) 16 MB
  float* k_g   = (float*)(ws + 40 * MB);       // (b,h,i,8)   1 MB
  float* avgmx = (float*)(ws + 41 * MB);
  float* scores= (float*)(ws + 41 * MB + 65536);
  int*   idx   = (int*)  (ws + 41 * MB + 98304);

  k_reduce<<<32, 256, 0, stream>>>(x_kv, avgmx);
  k_spa<<<64, 256, 0, stream>>>(avgmx, w_spa, scores);
  k_topk<<<2, 1024, 0, stream>>>(scores, idx);
  k_qv<<<dim3(32, 2, 4), 256, 0, stream>>>(x_kv, x_q, w_kv, b_kv, w_q, b_q, v_nc, v_t, qh);
  k_projg<<<dim3(16, 4, 2), 256, 0, stream>>>(x_kv, w_kv, 512, b_kv, idx, k_g, KTOP);
  k_attn<<<dim3(64, 8), 256, 0, stream>>>(qh, k_g, v_nc, idx, aoydw);
  k_dw<<<dim3(256, 2), 256, 0, stream>>>(v_t, w_dw, b_dw, aoydw);
  k_final<<<dim3(64, 2, 2), 256, 0, stream>>>(aoydw, w_proj, b_proj, w_pw, b_pw, out);
}

// Round 9
// 369.286 us; speedup vs baseline: 1.6711x; 1.1283x over previous
//
#include <hip/hip_runtime.h>
#include <hip/hip_bf16.h>

typedef short bf16x8 __attribute__((ext_vector_type(8)));
typedef float f32x4 __attribute__((ext_vector_type(4)));

constexpr int CN = 256, NV = 4096, KTOP = 512;

static __device__ __forceinline__ unsigned short f2bf(float f) {
  __hip_bfloat16 h = __float2bfloat16(f);
  return *(unsigned short*)&h;
}
static __device__ __forceinline__ unsigned pack2(float a, float b) {
  return (unsigned)f2bf(a) | ((unsigned)f2bf(b) << 16);
}

// ---------------------------------------------------------------- K0: transpose-cast f32 (c,n) -> bf16 (n,c)
__global__ void __launch_bounds__(256) k_tcast(const float* __restrict__ src, size_t srcBS,
                                               unsigned short* __restrict__ dst, int dstLD,
                                               int colOff, size_t dstBS) {
  __shared__ float tile[64 * 65];
  int b = blockIdx.z, c0 = blockIdx.y * 64, n0 = blockIdx.x * 64;
  const float* s = src + (size_t)b * srcBS;
  unsigned short* d = dst + (size_t)b * dstBS;
  int t = threadIdx.x;
  for (int i = 0; i < 16; ++i) {
    int id = i * 256 + t, c = id >> 6, n = id & 63;
    tile[c * 65 + n] = s[(size_t)(c0 + c) * NV + n0 + n];
  }
  __syncthreads();
  int n = t & 63, part = t >> 6;
  unsigned w[8];
#pragma unroll
  for (int k = 0; k < 8; ++k)
    w[k] = pack2(tile[(part * 16 + 2 * k) * 65 + n], tile[(part * 16 + 2 * k + 1) * 65 + n]);
  // round-8 bug: write address was missing "+ c0" -> 3/4 of dst stayed poisoned
  uint4* p = (uint4*)&d[(size_t)(n0 + n) * dstLD + colOff + c0 + part * 16];
  p[0] = make_uint4(w[0], w[1], w[2], w[3]);
  p[1] = make_uint4(w[4], w[5], w[6], w[7]);
}

// ---------------------------------------------------------------- K0b: weight prep -> bf16 (j, c) layouts
__global__ void __launch_bounds__(256) k_wprep(const float* __restrict__ wkv,
                                               const float* __restrict__ wq,
                                               const float* __restrict__ wproj,
                                               const float* __restrict__ wpw,
                                               unsigned short* __restrict__ wv_t,
                                               unsigned short* __restrict__ wq_t,
                                               unsigned short* __restrict__ wcat) {
  __shared__ float tile[64 * 65];
  int role = blockIdx.z;
  int j0 = blockIdx.x * 64, c0 = blockIdx.y * 64;
  int t = threadIdx.x;
  if (role == 3) {  // wpw (j,c) straight cast into wcat cols 256..512
    int j = t >> 2, part = t & 3;
    const float* s = &wpw[(size_t)(j0 + j) * 256 + c0 + part * 16];
    unsigned w[8];
#pragma unroll
    for (int k = 0; k < 8; ++k) w[k] = pack2(s[2 * k], s[2 * k + 1]);
    uint4* p = (uint4*)&wcat[(size_t)(j0 + j) * 512 + 256 + c0 + part * 16];
    p[0] = make_uint4(w[0], w[1], w[2], w[3]);
    p[1] = make_uint4(w[4], w[5], w[6], w[7]);
    return;
  }
  const float* src; int srcLD, srcOff; unsigned short* dst; int dstLD;
  if (role == 0)      { src = wkv;   srcLD = 512; srcOff = 256; dst = wv_t; dstLD = 256; }
  else if (role == 1) { src = wq;    srcLD = 256; srcOff = 0;   dst = wq_t; dstLD = 256; }
  else                { src = wproj; srcLD = 256; srcOff = 0;   dst = wcat; dstLD = 512; }
  for (int i = 0; i < 16; ++i) {
    int id = i * 256 + t, c = id >> 6, j = id & 63;
    tile[c * 65 + j] = src[(size_t)(c0 + c) * srcLD + srcOff + j0 + j];
  }
  __syncthreads();
  int j = t & 63, part = t >> 6;
  unsigned w[8];
#pragma unroll
  for (int k = 0; k < 8; ++k)
    w[k] = pack2(tile[(part * 16 + 2 * k) * 65 + j], tile[(part * 16 + 2 * k + 1) * 65 + j]);
  uint4* p = (uint4*)&dst[(size_t)(j0 + j) * dstLD + c0 + part * 16];
  p[0] = make_uint4(w[0], w[1], w[2], w[3]);
  p[1] = make_uint4(w[4], w[5], w[6], w[7]);
}

// ---------------------------------------------------------------- K1: channel mean/max (8-way c-split)
__global__ void __launch_bounds__(256) k_reduce(const float* __restrict__ xkv,
                                                float* __restrict__ avgmx) {
  __shared__ float ssum[256], smax[256];
  int blk = blockIdx.x;
  int b = blk >> 7, n0 = (blk & 127) * 32;
  int t = threadIdx.x, cg = t >> 5, nl = t & 31;
  int n = n0 + nl;
  const float* p = xkv + (size_t)b * CN * NV + (size_t)cg * 32 * NV + n;
  float s = 0.f, m = -1e30f;
  for (int i = 0; i < 32; ++i) {
    float v = p[(size_t)i * NV];
    s += v; m = fmaxf(m, v);
  }
  ssum[t] = s; smax[t] = m;
  __syncthreads();
  if (cg == 0) {
    for (int g = 1; g < 8; ++g) { s += ssum[g * 32 + nl]; m = fmaxf(m, smax[g * 32 + nl]); }
    avgmx[(b * 2 + 0) * NV + n] = s * (1.0f / 256.0f);
    avgmx[(b * 2 + 1) * NV + n] = m;
  }
}

// ---------------------------------------------------------------- K2: 7x7x7 conv + sigmoid
__global__ void __launch_bounds__(256) k_spa(const float* __restrict__ avgmx,
                                             const float* __restrict__ wspa,
                                             float* __restrict__ scores) {
  __shared__ float vol[2 * 4096];
  __shared__ float ws[686];
  int b = blockIdx.x >> 5, chunk = blockIdx.x & 31;
  int tid = threadIdx.x;
  for (int t = tid; t < 8192; t += 256) vol[t] = avgmx[b * 8192 + t];
  for (int t = tid; t < 686; t += 256) ws[t] = wspa[t];
  __syncthreads();
  int ci = tid & 1;
  int n = chunk * 128 + (tid >> 1);
  int d = n >> 8, h = (n >> 4) & 15, w = n & 15;
  const float* vb = vol + ci * 4096;
  const float* wb = ws + ci * 343;
  float acc = 0.f;
  for (int kd = 0; kd < 7; ++kd) {
    int zd = d - 3 + kd; if ((unsigned)zd >= 16u) continue;
    for (int kh = 0; kh < 7; ++kh) {
      int zh = h - 3 + kh; if ((unsigned)zh >= 16u) continue;
      const float* row = vb + zd * 256 + zh * 16;
      const float* wr = wb + kd * 49 + kh * 7;
#pragma unroll
      for (int kw = 0; kw < 7; ++kw) {
        int zw = w - 3 + kw;
        if ((unsigned)zw < 16u) acc += row[zw] * wr[kw];
      }
    }
  }
  acc += __shfl_xor(acc, 1);
  if (ci == 0) scores[b * NV + n] = 1.0f / (1.0f + expf(-acc));
}

// ---------------------------------------------------------------- K3: top-512 radix-select
__global__ void __launch_bounds__(1024) k_topk(const float* __restrict__ scores,
                                               int* __restrict__ idx) {
  __shared__ unsigned sv[4096];
  __shared__ unsigned hist[256];
  __shared__ int sB;
  __shared__ unsigned sSub, scnt;
  int b = blockIdx.x, tid = threadIdx.x;
  for (int t = tid; t < 4096; t += 1024) sv[t] = __float_as_uint(scores[b * NV + t]);
  if (tid == 0) scnt = 0;
  unsigned prefix = 0;
  int r = 512;
  for (int shift = 24; shift >= 0; shift -= 8) {
    if (tid < 256) hist[tid] = 0;
    __syncthreads();
    unsigned maskhi = (shift == 24) ? 0u : (0xFFFFFFFFu << (shift + 8));
    for (int i = 0; i < 4; ++i) {
      unsigned v = sv[tid + i * 1024];
      if ((v & maskhi) == prefix) atomicAdd(&hist[(v >> shift) & 255], 1u);
    }
    __syncthreads();
    for (int off = 1; off < 256; off <<= 1) {
      unsigned add = 0;
      if (tid < 256 && tid + off < 256) add = hist[tid + off];
      __syncthreads();
      if (tid < 256) hist[tid] += add;
      __syncthreads();
    }
    if (tid < 256) {
      unsigned s = hist[tid];
      unsigned snext = (tid < 255) ? hist[tid + 1] : 0u;
      if (s >= (unsigned)r && snext < (unsigned)r) { sB = tid; sSub = snext; }
    }
    __syncthreads();
    prefix |= ((unsigned)sB) << shift;
    r -= (int)sSub;
    __syncthreads();
  }
  unsigned vstar = prefix;
  for (int i = 0; i < 4; ++i) {
    int t = tid + i * 1024;
    if (sv[t] > vstar) { unsigned p = atomicAdd(&scnt, 1u); idx[b * KTOP + p] = t; }
  }
  __syncthreads();
  int base = (int)scnt;
  for (int i = 0; i < 4; ++i) {
    int t = tid + i * 1024;
    if (sv[t] == vstar) {
      int rank = 0;
      for (int m = 0; m < t; ++m) rank += (sv[m] == vstar);
      if (rank < r) idx[b * KTOP + base + rank] = t;
    }
  }
}

// ---------------------------------------------------------------- K4: fused V+Q projection, MFMA bf16
// D[j][n] = sum_c Wt[j][c] * Xt[n][c];  f32 outputs (v_nc, v_cn, qh)
__global__ void __launch_bounds__(256) k_qv(const unsigned short* __restrict__ xkv_t,
                                            const unsigned short* __restrict__ xq_t,
                                            const unsigned short* __restrict__ wv_t,
                                            const unsigned short* __restrict__ wq_t,
                                            const float* __restrict__ bkv,
                                            const float* __restrict__ bq,
                                            float* __restrict__ v_nc,
                                            float* __restrict__ v_cn,
                                            float* __restrict__ qh) {
  __shared__ unsigned short Als[128 * 40];
  __shared__ unsigned short Bls[128 * 40];
  int role = blockIdx.z;
  int b = role & 1;
  bool isQ = role >= 2;
  const unsigned short* A = isQ ? wq_t : wv_t;                              // (j=256, c=256)
  const unsigned short* B = (isQ ? xq_t : xkv_t) + (size_t)b * NV * 256;    // (n, c)
  const float* bias = isQ ? bq : (bkv + 256);
  int n0 = blockIdx.x * 128, j0 = blockIdx.y * 128;
  int t = threadIdx.x;
  int wave = t >> 6, lane = t & 63;
  int l15 = lane & 15, q = lane >> 4, q8 = q * 8;
  int wj = (wave >> 1) * 64, wn = (wave & 1) * 64;
  f32x4 acc[4][4] = {};
  int ar = t >> 1, ah = t & 1;
  for (int c0 = 0; c0 < 256; c0 += 32) {
    __syncthreads();
    {
      const unsigned short* sa = &A[(size_t)(j0 + ar) * 256 + c0 + ah * 16];
      *(uint4*)&Als[ar * 40 + ah * 16]     = *(const uint4*)&sa[0];
      *(uint4*)&Als[ar * 40 + ah * 16 + 8] = *(const uint4*)&sa[8];
      const unsigned short* sb = &B[(size_t)(n0 + ar) * 256 + c0 + ah * 16];
      *(uint4*)&Bls[ar * 40 + ah * 16]     = *(const uint4*)&sb[0];
      *(uint4*)&Bls[ar * 40 + ah * 16 + 8] = *(const uint4*)&sb[8];
    }
    __syncthreads();
    bf16x8 af[4], bf[4];
#pragma unroll
    for (int mt = 0; mt < 4; ++mt)
      af[mt] = *(const bf16x8*)&Als[(wj + mt * 16 + l15) * 40 + q8];
#pragma unroll
    for (int nt = 0; nt < 4; ++nt)
      bf[nt] = *(const bf16x8*)&Bls[(wn + nt * 16 + l15) * 40 + q8];
#pragma unroll
    for (int mt = 0; mt < 4; ++mt)
#pragma unroll
      for (int nt = 0; nt < 4; ++nt)
        acc[mt][nt] = __builtin_amdgcn_mfma_f32_16x16x32_bf16(af[mt], bf[nt], acc[mt][nt], 0, 0, 0);
  }
#pragma unroll
  for (int mt = 0; mt < 4; ++mt) {
    int jb = j0 + wj + mt * 16 + q * 4;          // 4 consecutive j held in regs
    float4 b4 = *(const float4*)&bias[jb];
#pragma unroll
    for (int nt = 0; nt < 4; ++nt) {
      int n = n0 + wn + nt * 16 + l15;
      float v0 = acc[mt][nt][0] + b4.x;
      float v1 = acc[mt][nt][1] + b4.y;
      float v2 = acc[mt][nt][2] + b4.z;
      float v3 = acc[mt][nt][3] + b4.w;
      if (isQ) {
        int h = jb >> 3, d0 = jb & 7;            // jb multiple of 4 -> within one head
        *(float4*)&qh[((size_t)(b * 32 + h) * NV + n) * 8 + d0] = make_float4(v0, v1, v2, v3);
      } else {
        *(float4*)&v_nc[((size_t)b * NV + n) * 256 + jb] = make_float4(v0, v1, v2, v3);
        size_t base = (size_t)(b * 256 + jb) * NV + n;   // plain scalar stores (no LDS transpose)
        v_cn[base]          = v0;
        v_cn[base + NV]     = v1;
        v_cn[base + 2 * NV] = v2;
        v_cn[base + 3 * NV] = v3;
      }
    }
  }
}

// ---------------------------------------------------------------- K5: gathered K projection (f32)
__global__ void k_projg(const float* __restrict__ X, const float* __restrict__ W, int ldw,
                        const float* __restrict__ bias, const int* __restrict__ map,
                        float* __restrict__ Y, int M) {
  __shared__ float Xs[32 * 33];
  __shared__ float Ws[32 * 64];
  __shared__ int nmap[32];
  int m0 = blockIdx.x * 32, j0 = blockIdx.y * 64, b = blockIdx.z;
  int tid = threadIdx.x;
  if (tid < 32) nmap[tid] = map[b * KTOP + m0 + tid];
  int mm = tid >> 3, tj = (tid & 7) * 8;
  float acc[8] = {};
  const float* Xb = X + (size_t)b * CN * NV;
  for (int c0 = 0; c0 < 256; c0 += 32) {
    __syncthreads();
    for (int t = tid; t < 1024; t += 256) {
      int cc = t >> 5, mmm = t & 31;
      Xs[cc * 33 + mmm] = Xb[(size_t)(c0 + cc) * NV + nmap[mmm]];
    }
    for (int t = tid; t < 2048; t += 256) {
      int cc = t >> 6, jj = t & 63;
      Ws[cc * 64 + jj] = W[(size_t)(c0 + cc) * ldw + j0 + jj];
    }
    __syncthreads();
    for (int cc = 0; cc < 32; ++cc) {
      float xv = Xs[cc * 33 + mm];
      float4 w0 = *(const float4*)&Ws[cc * 64 + tj];
      float4 w1 = *(const float4*)&Ws[cc * 64 + tj + 4];
      acc[0] += xv * w0.x; acc[1] += xv * w0.y; acc[2] += xv * w0.z; acc[3] += xv * w0.w;
      acc[4] += xv * w1.x; acc[5] += xv * w1.y; acc[6] += xv * w1.z; acc[7] += xv * w1.w;
    }
  }
  int m = m0 + mm, j = j0 + tj;
  float* outp = Y + ((size_t)(b * 32 + (j >> 3)) * M + m) * 8;
#pragma unroll
  for (int jj = 0; jj < 8; ++jj) outp[jj] = acc[jj] + bias[j + jj];
}

// ---------------------------------------------------------------- K6: attention (f32 in, bf16 packed out)
__global__ void __launch_bounds__(256) k_attn(const float* __restrict__ qh,
                                              const float* __restrict__ kgh,
                                              const float* __restrict__ v_nc,
                                              const int* __restrict__ idx,
                                              unsigned short* __restrict__ aoydw) {
  __shared__ float Ks[512 * 8];
  __shared__ float Vs[512 * 8];
  int bh = blockIdx.x;
  int b = bh >> 5, h = bh & 31;
  int tid = threadIdx.x;
  const float kscale = 0.35355339059327373f * 1.4426950408889634f;  // 1/sqrt(8)*log2(e)
  const float* kb = kgh + (size_t)bh * KTOP * 8;
  for (int t = tid; t < 4096; t += 256) Ks[t] = kb[t] * kscale;
  const int* ib = idx + b * KTOP;
  for (int t = tid; t < 4096; t += 256) {
    int i = t >> 3, d = t & 7;
    Vs[t] = v_nc[((size_t)b * NV + ib[i]) * 256 + h * 8 + d];
  }
  __syncthreads();
  int n0 = blockIdx.y * 512 + tid;
  const float* qb = qh + (size_t)bh * NV * 8;
  float4 qa[2], qc[2], oa[2], oc[2];
  float se[2];
#pragma unroll
  for (int qq = 0; qq < 2; ++qq) {
    const float4* qp = (const float4*)(qb + (size_t)(n0 + qq * 256) * 8);
    qa[qq] = qp[0]; qc[qq] = qp[1];
    oa[qq] = make_float4(0.f, 0.f, 0.f, 0.f);
    oc[qq] = make_float4(0.f, 0.f, 0.f, 0.f);
    se[qq] = 0.f;
  }
#pragma unroll 2
  for (int i = 0; i < 512; ++i) {
    float4 ka = *(const float4*)&Ks[i * 8];
    float4 kc = *(const float4*)&Ks[i * 8 + 4];
    float4 va = *(const float4*)&Vs[i * 8];
    float4 vc = *(const float4*)&Vs[i * 8 + 4];
#pragma unroll
    for (int qq = 0; qq < 2; ++qq) {
      float d0 = qa[qq].x * ka.x;
      d0 = fmaf(qa[qq].y, ka.y, d0);
      d0 = fmaf(qa[qq].z, ka.z, d0);
      d0 = fmaf(qa[qq].w, ka.w, d0);
      d0 = fmaf(qc[qq].x, kc.x, d0);
      d0 = fmaf(qc[qq].y, kc.y, d0);
      d0 = fmaf(qc[qq].z, kc.z, d0);
      d0 = fmaf(qc[qq].w, kc.w, d0);
      float e = exp2f(d0);
      se[qq] += e;
      oa[qq].x = fmaf(e, va.x, oa[qq].x); oa[qq].y = fmaf(e, va.y, oa[qq].y);
      oa[qq].z = fmaf(e, va.z, oa[qq].z); oa[qq].w = fmaf(e, va.w, oa[qq].w);
      oc[qq].x = fmaf(e, vc.x, oc[qq].x); oc[qq].y = fmaf(e, vc.y, oc[qq].y);
      oc[qq].z = fmaf(e, vc.z, oc[qq].z); oc[qq].w = fmaf(e, vc.w, oc[qq].w);
    }
  }
#pragma unroll
  for (int qq = 0; qq < 2; ++qq) {
    float inv = 1.0f / se[qq];
    int n = n0 + qq * 256;
    uint4 o = make_uint4(pack2(oa[qq].x * inv, oa[qq].y * inv),
                         pack2(oa[qq].z * inv, oa[qq].w * inv),
                         pack2(oc[qq].x * inv, oc[qq].y * inv),
                         pack2(oc[qq].z * inv, oc[qq].w * inv));
    *(uint4*)&aoydw[((size_t)b * NV + n) * 512 + h * 8] = o;
  }
}

// ---------------------------------------------------------------- K7: depthwise conv -> ydw_cn (c,n) f32
__global__ void __launch_bounds__(256) k_dw(const float* __restrict__ vt,
                                            const float* __restrict__ wdw,
                                            const float* __restrict__ bdw,
                                            float* __restrict__ ydw_cn) {
  __shared__ float pl[4096];
  int c = blockIdx.x, b = blockIdx.y;
  const float* plane = vt + ((size_t)(b * 256 + c)) * NV;
  int tid = threadIdx.x;
  for (int i = tid; i < 4096; i += 256) pl[i] = plane[i];
  float wr[27];
#pragma unroll
  for (int i = 0; i < 27; ++i) wr[i] = wdw[c * 27 + i];
  float bias = bdw[c];
  __syncthreads();
  float* dst = ydw_cn + ((size_t)(b * 256 + c)) * NV;
  for (int i = 0; i < 16; ++i) {
    int n = i * 256 + tid;
    int d = n >> 8, h = (n >> 4) & 15, w = n & 15;
    float acc = bias;
#pragma unroll
    for (int kd = 0; kd < 3; ++kd) {
      int zd = d - 1 + kd;
      bool okd = (unsigned)zd < 16u;
#pragma unroll
      for (int kh = 0; kh < 3; ++kh) {
        int zh = h - 1 + kh;
        bool okh = okd && ((unsigned)zh < 16u);
#pragma unroll
        for (int kw = 0; kw < 3; ++kw) {
          int zw = w - 1 + kw;
          bool ok = okh && ((unsigned)zw < 16u);
          int nz = ok ? (zd * 256 + zh * 16 + zw) : 0;
          float v = pl[nz];
          acc = fmaf(ok ? v : 0.f, wr[kd * 9 + kh * 3 + kw], acc);
        }
      }
    }
    dst[n] = acc;
  }
}

// ---------------------------------------------------------------- K8: final GEMM K=512, MFMA bf16
__global__ void __launch_bounds__(256) k_final(const unsigned short* __restrict__ aoydw,
                                               const unsigned short* __restrict__ wcat,
                                               const float* __restrict__ bproj,
                                               const float* __restrict__ bpw,
                                               float* __restrict__ out) {
  __shared__ unsigned short Als[64 * 40];
  __shared__ unsigned short Bls[128 * 40];
  int n0 = blockIdx.x * 64, j0 = blockIdx.y * 128, b = blockIdx.z;
  int t = threadIdx.x;
  int wave = t >> 6, lane = t & 63;
  int l15 = lane & 15, q = lane >> 4, q8 = q * 8;
  int wn = (wave >> 1) * 32, wjj = (wave & 1) * 64;
  f32x4 acc[2][4] = {};
  const unsigned short* Abase = aoydw + (size_t)b * NV * 512;
  int ar = t >> 2, aq = t & 3;
  int br = t >> 1, bhh = t & 1;
  for (int c0 = 0; c0 < 512; c0 += 32) {
    __syncthreads();
    *(uint4*)&Als[ar * 40 + aq * 8] =
        *(const uint4*)&Abase[(size_t)(n0 + ar) * 512 + c0 + aq * 8];
    const unsigned short* sb = &wcat[(size_t)(j0 + br) * 512 + c0 + bhh * 16];
    *(uint4*)&Bls[br * 40 + bhh * 16]     = *(const uint4*)&sb[0];
    *(uint4*)&Bls[br * 40 + bhh * 16 + 8] = *(const uint4*)&sb[8];
    __syncthreads();
    bf16x8 af[2], bf[4];
#pragma unroll
    for (int mt = 0; mt < 2; ++mt)
      af[mt] = *(const bf16x8*)&Als[(wn + mt * 16 + l15) * 40 + q8];
#pragma unroll
    for (int nt = 0; nt < 4; ++nt)
      bf[nt] = *(const bf16x8*)&Bls[(wjj + nt * 16 + l15) * 40 + q8];
#pragma unroll
    for (int mt = 0; mt < 2; ++mt)
#pragma unroll
      for (int nt = 0; nt < 4; ++nt)
        acc[mt][nt] = __builtin_amdgcn_mfma_f32_16x16x32_bf16(af[mt], bf[nt], acc[mt][nt], 0, 0, 0);
  }
#pragma unroll
  for (int nt = 0; nt < 4; ++nt) {
    int j = j0 + wjj + nt * 16 + l15;
    float bl = bproj[j] + bpw[j];
#pragma unroll
    for (int mt = 0; mt < 2; ++mt) {
      int n = n0 + wn + mt * 16 + q * 4;
      float4 r = make_float4(acc[mt][nt][0] + bl, acc[mt][nt][1] + bl,
                             acc[mt][nt][2] + bl, acc[mt][nt][3] + bl);
      *(float4*)&out[(size_t)(b * 256 + j) * NV + n] = r;
    }
  }
}

// ---------------------------------------------------------------- launch
extern "C" void kernel_launch(void* const* d_in, const int* in_sizes, int n_in,
                              void* d_out, int out_size, void* d_ws, size_t ws_size,
                              hipStream_t stream) {
  const float* x_kv   = (const float*)d_in[0];
  const float* x_q    = (const float*)d_in[1];
  const float* w_spa  = (const float*)d_in[2];
  const float* w_kv   = (const float*)d_in[3];
  const float* b_kv   = (const float*)d_in[4];
  const float* w_q    = (const float*)d_in[5];
  const float* b_q    = (const float*)d_in[6];
  const float* w_proj = (const float*)d_in[7];
  const float* b_proj = (const float*)d_in[8];
  const float* w_dw   = (const float*)d_in[9];
  const float* b_dw   = (const float*)d_in[10];
  const float* w_pw   = (const float*)d_in[11];
  const float* b_pw   = (const float*)d_in[12];
  float* out = (float*)d_out;

  const size_t MB = 1024 * 1024;
  char* ws = (char*)d_ws;
  unsigned short* xkv_t = (unsigned short*)(ws);            // 4 MB (b,n,c) bf16   [dead after k_qv]
  unsigned short* xq_t  = (unsigned short*)(ws + 4 * MB);   // 4 MB                [dead after k_qv]
  float*          ydwcn = (float*)(ws);                     // 8 MB (b,c,n) f32 — reuses xkv_t/xq_t
  float*          v_nc  = (float*)(ws + 8 * MB);            // 8 MB (b,n,c) f32
  float*          qh    = (float*)(ws + 16 * MB);           // 8 MB (b,h,n,8) f32
  float*          v_cn  = (float*)(ws + 24 * MB);           // 8 MB (b,c,n) f32
  unsigned short* aoydw = (unsigned short*)(ws + 32 * MB);  // 8 MB (b,n,512) bf16
  float*          k_g   = (float*)(ws + 40 * MB);           // 1 MB (b,h,i,8) f32
  unsigned short* wv_t  = (unsigned short*)(ws + 41 * MB);          // 128 KB
  unsigned short* wq_t  = (unsigned short*)(ws + 41 * MB + 131072); // 128 KB
  unsigned short* wcat  = (unsigned short*)(ws + 41 * MB + 262144); // 256 KB
  float*          avgmx = (float*)(ws + 41 * MB + 524288);          //  64 KB
  float*          scores= (float*)(ws + 41 * MB + 589824);          //  32 KB
  int*            idx   = (int*)  (ws + 41 * MB + 622592);          //   4 KB

  k_tcast<<<dim3(64, 4, 2), 256, 0, stream>>>(x_kv, (size_t)CN * NV, xkv_t, 256, 0, (size_t)NV * 256);
  k_tcast<<<dim3(64, 4, 2), 256, 0, stream>>>(x_q,  (size_t)CN * NV, xq_t,  256, 0, (size_t)NV * 256);
  k_wprep<<<dim3(4, 4, 4), 256, 0, stream>>>(w_kv, w_q, w_proj, w_pw, wv_t, wq_t, wcat);
  k_reduce<<<256, 256, 0, stream>>>(x_kv, avgmx);
  k_spa<<<64, 256, 0, stream>>>(avgmx, w_spa, scores);
  k_topk<<<2, 1024, 0, stream>>>(scores, idx);
  k_qv<<<dim3(32, 2, 4), 256, 0, stream>>>(xkv_t, xq_t, wv_t, wq_t, b_kv, b_q, v_nc, v_cn, qh);
  k_projg<<<dim3(16, 4, 2), 256, 0, stream>>>(x_kv, w_kv, 512, b_kv, idx, k_g, KTOP);
  k_attn<<<dim3(64, 8), 256, 0, stream>>>(qh, k_g, v_nc, idx, aoydw);
  k_dw<<<dim3(256, 2), 256, 0, stream>>>(v_cn, w_dw, b_dw, ydwcn);
  k_tcast<<<dim3(64, 4, 2), 256, 0, stream>>>(ydwcn, (size_t)CN * NV, aoydw, 512, 256, (size_t)NV * 512);
  k_final<<<dim3(64, 2, 2), 256, 0, stream>>>(aoydw, wcat, b_proj, b_pw, out);
}

// Round 10
// 301.160 us; speedup vs baseline: 2.0491x; 1.2262x over previous
//
#include <hip/hip_runtime.h>
#include <hip/hip_bf16.h>

typedef short bf16x8 __attribute__((ext_vector_type(8)));
typedef float f32x4 __attribute__((ext_vector_type(4)));

constexpr int CN = 256, NV = 4096, KTOP = 512;

static __device__ __forceinline__ unsigned short f2bf(float f) {
  __hip_bfloat16 h = __float2bfloat16(f);
  return *(unsigned short*)&h;
}
static __device__ __forceinline__ unsigned pack2(float a, float b) {
  return (unsigned)f2bf(a) | ((unsigned)f2bf(b) << 16);
}
static __device__ __forceinline__ float bf2f(unsigned short u) {
  return __uint_as_float(((unsigned)u) << 16);
}

// ---------------------------------------------------------------- K0: transpose-cast f32 (c,n) -> bf16 (n,c)
__global__ void __launch_bounds__(256) k_tcast(const float* __restrict__ src, size_t srcBS,
                                               unsigned short* __restrict__ dst, int dstLD,
                                               size_t dstBS) {
  __shared__ float tile[64 * 65];
  int b = blockIdx.z, c0 = blockIdx.y * 64, n0 = blockIdx.x * 64;
  const float* s = src + (size_t)b * srcBS;
  unsigned short* d = dst + (size_t)b * dstBS;
  int t = threadIdx.x;
  for (int i = 0; i < 16; ++i) {
    int id = i * 256 + t, c = id >> 6, n = id & 63;
    tile[c * 65 + n] = s[(size_t)(c0 + c) * NV + n0 + n];
  }
  __syncthreads();
  int n = t & 63, part = t >> 6;
  unsigned w[8];
#pragma unroll
  for (int k = 0; k < 8; ++k)
    w[k] = pack2(tile[(part * 16 + 2 * k) * 65 + n], tile[(part * 16 + 2 * k + 1) * 65 + n]);
  uint4* p = (uint4*)&d[(size_t)(n0 + n) * dstLD + c0 + part * 16];
  p[0] = make_uint4(w[0], w[1], w[2], w[3]);
  p[1] = make_uint4(w[4], w[5], w[6], w[7]);
}

// ---------------------------------------------------------------- K0b: weight prep -> bf16 (j, c) layouts
__global__ void __launch_bounds__(256) k_wprep(const float* __restrict__ wkv,
                                               const float* __restrict__ wq,
                                               const float* __restrict__ wproj,
                                               const float* __restrict__ wpw,
                                               unsigned short* __restrict__ wv_t,
                                               unsigned short* __restrict__ wq_t,
                                               unsigned short* __restrict__ wcat) {
  __shared__ float tile[64 * 65];
  int role = blockIdx.z;
  int j0 = blockIdx.x * 64, c0 = blockIdx.y * 64;
  int t = threadIdx.x;
  if (role == 3) {  // wpw (j,c) straight cast into wcat cols 256..512
    int j = t >> 2, part = t & 3;
    const float* s = &wpw[(size_t)(j0 + j) * 256 + c0 + part * 16];
    unsigned w[8];
#pragma unroll
    for (int k = 0; k < 8; ++k) w[k] = pack2(s[2 * k], s[2 * k + 1]);
    uint4* p = (uint4*)&wcat[(size_t)(j0 + j) * 512 + 256 + c0 + part * 16];
    p[0] = make_uint4(w[0], w[1], w[2], w[3]);
    p[1] = make_uint4(w[4], w[5], w[6], w[7]);
    return;
  }
  const float* src; int srcLD, srcOff; unsigned short* dst; int dstLD;
  if (role == 0)      { src = wkv;   srcLD = 512; srcOff = 256; dst = wv_t; dstLD = 256; }
  else if (role == 1) { src = wq;    srcLD = 256; srcOff = 0;   dst = wq_t; dstLD = 256; }
  else                { src = wproj; srcLD = 256; srcOff = 0;   dst = wcat; dstLD = 512; }
  for (int i = 0; i < 16; ++i) {
    int id = i * 256 + t, c = id >> 6, j = id & 63;
    tile[c * 65 + j] = src[(size_t)(c0 + c) * srcLD + srcOff + j0 + j];
  }
  __syncthreads();
  int j = t & 63, part = t >> 6;
  unsigned w[8];
#pragma unroll
  for (int k = 0; k < 8; ++k)
    w[k] = pack2(tile[(part * 16 + 2 * k) * 65 + j], tile[(part * 16 + 2 * k + 1) * 65 + j]);
  uint4* p = (uint4*)&dst[(size_t)(j0 + j) * dstLD + c0 + part * 16];
  p[0] = make_uint4(w[0], w[1], w[2], w[3]);
  p[1] = make_uint4(w[4], w[5], w[6], w[7]);
}

// ---------------------------------------------------------------- K1: channel mean/max
__global__ void __launch_bounds__(256) k_reduce(const float* __restrict__ xkv,
                                                float* __restrict__ avgmx) {
  __shared__ float ssum[256], smax[256];
  int blk = blockIdx.x;
  int b = blk >> 7, n0 = (blk & 127) * 32;
  int t = threadIdx.x, cg = t >> 5, nl = t & 31;
  int n = n0 + nl;
  const float* p = xkv + (size_t)b * CN * NV + (size_t)cg * 32 * NV + n;
  float s = 0.f, m = -1e30f;
  for (int i = 0; i < 32; ++i) {
    float v = p[(size_t)i * NV];
    s += v; m = fmaxf(m, v);
  }
  ssum[t] = s; smax[t] = m;
  __syncthreads();
  if (cg == 0) {
    for (int g = 1; g < 8; ++g) { s += ssum[g * 32 + nl]; m = fmaxf(m, smax[g * 32 + nl]); }
    avgmx[(b * 2 + 0) * NV + n] = s * (1.0f / 256.0f);
    avgmx[(b * 2 + 1) * NV + n] = m;
  }
}

// ---------------------------------------------------------------- K2: 7x7x7 conv + sigmoid
__global__ void __launch_bounds__(256) k_spa(const float* __restrict__ avgmx,
                                             const float* __restrict__ wspa,
                                             float* __restrict__ scores) {
  __shared__ float vol[2 * 4096];
  __shared__ float ws[686];
  int b = blockIdx.x >> 5, chunk = blockIdx.x & 31;
  int tid = threadIdx.x;
  for (int t = tid; t < 8192; t += 256) vol[t] = avgmx[b * 8192 + t];
  for (int t = tid; t < 686; t += 256) ws[t] = wspa[t];
  __syncthreads();
  int ci = tid & 1;
  int n = chunk * 128 + (tid >> 1);
  int d = n >> 8, h = (n >> 4) & 15, w = n & 15;
  const float* vb = vol + ci * 4096;
  const float* wb = ws + ci * 343;
  float acc = 0.f;
  for (int kd = 0; kd < 7; ++kd) {
    int zd = d - 3 + kd; if ((unsigned)zd >= 16u) continue;
    for (int kh = 0; kh < 7; ++kh) {
      int zh = h - 3 + kh; if ((unsigned)zh >= 16u) continue;
      const float* row = vb + zd * 256 + zh * 16;
      const float* wr = wb + kd * 49 + kh * 7;
#pragma unroll
      for (int kw = 0; kw < 7; ++kw) {
        int zw = w - 3 + kw;
        if ((unsigned)zw < 16u) acc += row[zw] * wr[kw];
      }
    }
  }
  acc += __shfl_xor(acc, 1);
  if (ci == 0) scores[b * NV + n] = 1.0f / (1.0f + expf(-acc));
}

// ---------------------------------------------------------------- K3: top-512 radix-select (parallel tie-rank)
__global__ void __launch_bounds__(1024) k_topk(const float* __restrict__ scores,
                                               int* __restrict__ idx) {
  __shared__ unsigned sv[4096];
  __shared__ unsigned hist[256];
  __shared__ int sB;
  __shared__ unsigned sSub, scnt;
  __shared__ int wsum[16];
  int b = blockIdx.x, tid = threadIdx.x;
  for (int t = tid; t < 4096; t += 1024) sv[t] = __float_as_uint(scores[b * NV + t]);
  if (tid == 0) scnt = 0;
  unsigned prefix = 0;
  int r = 512;
  for (int shift = 24; shift >= 0; shift -= 8) {
    if (tid < 256) hist[tid] = 0;
    __syncthreads();
    unsigned maskhi = (shift == 24) ? 0u : (0xFFFFFFFFu << (shift + 8));
    for (int i = 0; i < 4; ++i) {
      unsigned v = sv[tid + i * 1024];
      if ((v & maskhi) == prefix) atomicAdd(&hist[(v >> shift) & 255], 1u);
    }
    __syncthreads();
    for (int off = 1; off < 256; off <<= 1) {
      unsigned add = 0;
      if (tid < 256 && tid + off < 256) add = hist[tid + off];
      __syncthreads();
      if (tid < 256) hist[tid] += add;
      __syncthreads();
    }
    if (tid < 256) {
      unsigned s = hist[tid];
      unsigned snext = (tid < 255) ? hist[tid + 1] : 0u;
      if (s >= (unsigned)r && snext < (unsigned)r) { sB = tid; sSub = snext; }
    }
    __syncthreads();
    prefix |= ((unsigned)sB) << shift;
    r -= (int)sSub;
    __syncthreads();
  }
  unsigned vstar = prefix;
  for (int i = 0; i < 4; ++i) {
    int t = tid * 4 + i;
    if (sv[t] > vstar) { unsigned p = atomicAdd(&scnt, 1u); idx[b * KTOP + p] = t; }
  }
  __syncthreads();
  int base = (int)scnt;
  // tie-rank via block-wide exclusive scan (index order, contiguous segments)
  int loc = 0;
  for (int i = 0; i < 4; ++i) loc += (sv[tid * 4 + i] == vstar);
  int lane = tid & 63, w = tid >> 6;
  int x = loc;
  for (int off = 1; off < 64; off <<= 1) {
    int y = __shfl_up(x, off);
    if (lane >= off) x += y;
  }
  if (lane == 63) wsum[w] = x;
  __syncthreads();
  int wbase = 0;
  for (int i = 0; i < w; ++i) wbase += wsum[i];
  int excl = wbase + x - loc;
  for (int i = 0; i < 4; ++i) {
    int t = tid * 4 + i;
    if (sv[t] == vstar) {
      if (excl < r) idx[b * KTOP + base + excl] = t;
      ++excl;
    }
  }
}

// ---------------------------------------------------------------- K4: fused V+Q projection, MFMA bf16 -> bf16 outs
__global__ void __launch_bounds__(256) k_qv(const unsigned short* __restrict__ xkv_t,
                                            const unsigned short* __restrict__ xq_t,
                                            const unsigned short* __restrict__ wv_t,
                                            const unsigned short* __restrict__ wq_t,
                                            const float* __restrict__ bkv,
                                            const float* __restrict__ bq,
                                            unsigned short* __restrict__ v_nc,
                                            unsigned short* __restrict__ qh) {
  __shared__ unsigned short Als[128 * 40];
  __shared__ unsigned short Bls[128 * 40];
  int role = blockIdx.z;
  int b = role & 1;
  bool isQ = role >= 2;
  const unsigned short* A = isQ ? wq_t : wv_t;                              // (j=256, c=256)
  const unsigned short* B = (isQ ? xq_t : xkv_t) + (size_t)b * NV * 256;    // (n, c)
  const float* bias = isQ ? bq : (bkv + 256);
  int n0 = blockIdx.x * 128, j0 = blockIdx.y * 128;
  int t = threadIdx.x;
  int wave = t >> 6, lane = t & 63;
  int l15 = lane & 15, q = lane >> 4, q8 = q * 8;
  int wj = (wave >> 1) * 64, wn = (wave & 1) * 64;
  f32x4 acc[4][4] = {};
  int ar = t >> 1, ah = t & 1;
  for (int c0 = 0; c0 < 256; c0 += 32) {
    __syncthreads();
    {
      const unsigned short* sa = &A[(size_t)(j0 + ar) * 256 + c0 + ah * 16];
      *(uint4*)&Als[ar * 40 + ah * 16]     = *(const uint4*)&sa[0];
      *(uint4*)&Als[ar * 40 + ah * 16 + 8] = *(const uint4*)&sa[8];
      const unsigned short* sb = &B[(size_t)(n0 + ar) * 256 + c0 + ah * 16];
      *(uint4*)&Bls[ar * 40 + ah * 16]     = *(const uint4*)&sb[0];
      *(uint4*)&Bls[ar * 40 + ah * 16 + 8] = *(const uint4*)&sb[8];
    }
    __syncthreads();
    bf16x8 af[4], bf[4];
#pragma unroll
    for (int mt = 0; mt < 4; ++mt)
      af[mt] = *(const bf16x8*)&Als[(wj + mt * 16 + l15) * 40 + q8];
#pragma unroll
    for (int nt = 0; nt < 4; ++nt)
      bf[nt] = *(const bf16x8*)&Bls[(wn + nt * 16 + l15) * 40 + q8];
#pragma unroll
    for (int mt = 0; mt < 4; ++mt)
#pragma unroll
      for (int nt = 0; nt < 4; ++nt)
        acc[mt][nt] = __builtin_amdgcn_mfma_f32_16x16x32_bf16(af[mt], bf[nt], acc[mt][nt], 0, 0, 0);
  }
#pragma unroll
  for (int mt = 0; mt < 4; ++mt) {
    int jb = j0 + wj + mt * 16 + q * 4;          // 4 consecutive j
    float4 b4 = *(const float4*)&bias[jb];
#pragma unroll
    for (int nt = 0; nt < 4; ++nt) {
      int n = n0 + wn + nt * 16 + l15;
      float v0 = acc[mt][nt][0] + b4.x;
      float v1 = acc[mt][nt][1] + b4.y;
      float v2 = acc[mt][nt][2] + b4.z;
      float v3 = acc[mt][nt][3] + b4.w;
      uint2 pk = make_uint2(pack2(v0, v1), pack2(v2, v3));
      if (isQ) {
        int h = jb >> 3, d0 = jb & 7;            // jb%4==0 -> within one head
        *(uint2*)&qh[((size_t)(b * 32 + h) * NV + n) * 8 + d0] = pk;
      } else {
        *(uint2*)&v_nc[((size_t)b * NV + n) * 256 + jb] = pk;
      }
    }
  }
}

// ---------------------------------------------------------------- K5: gathered K projection (f32 compute, bf16 scaled out)
__global__ void k_projg(const float* __restrict__ X, const float* __restrict__ W, int ldw,
                        const float* __restrict__ bias, const int* __restrict__ map,
                        unsigned short* __restrict__ kg) {
  __shared__ float Xs[32 * 33];
  __shared__ float Ws[32 * 64];
  __shared__ int nmap[32];
  const float kscale = 0.35355339059327373f * 1.4426950408889634f;  // 1/sqrt(8)*log2(e)
  int m0 = blockIdx.x * 32, j0 = blockIdx.y * 64, b = blockIdx.z;
  int tid = threadIdx.x;
  if (tid < 32) nmap[tid] = map[b * KTOP + m0 + tid];
  int mm = tid >> 3, tj = (tid & 7) * 8;
  float acc[8] = {};
  const float* Xb = X + (size_t)b * CN * NV;
  for (int c0 = 0; c0 < 256; c0 += 32) {
    __syncthreads();
    for (int t = tid; t < 1024; t += 256) {
      int cc = t >> 5, mmm = t & 31;
      Xs[cc * 33 + mmm] = Xb[(size_t)(c0 + cc) * NV + nmap[mmm]];
    }
    for (int t = tid; t < 2048; t += 256) {
      int cc = t >> 6, jj = t & 63;
      Ws[cc * 64 + jj] = W[(size_t)(c0 + cc) * ldw + j0 + jj];
    }
    __syncthreads();
    for (int cc = 0; cc < 32; ++cc) {
      float xv = Xs[cc * 33 + mm];
      float4 w0 = *(const float4*)&Ws[cc * 64 + tj];
      float4 w1 = *(const float4*)&Ws[cc * 64 + tj + 4];
      acc[0] += xv * w0.x; acc[1] += xv * w0.y; acc[2] += xv * w0.z; acc[3] += xv * w0.w;
      acc[4] += xv * w1.x; acc[5] += xv * w1.y; acc[6] += xv * w1.z; acc[7] += xv * w1.w;
    }
  }
  int m = m0 + mm, j = j0 + tj;
  float s[8];
#pragma unroll
  for (int jj = 0; jj < 8; ++jj) s[jj] = (acc[jj] + bias[j + jj]) * kscale;
  unsigned short* outp = kg + ((size_t)(b * 32 + (j >> 3)) * KTOP + m) * 8;
  *(uint4*)outp = make_uint4(pack2(s[0], s[1]), pack2(s[2], s[3]),
                             pack2(s[4], s[5]), pack2(s[6], s[7]));
}

// ---------------------------------------------------------------- K5b: build V^T (+ones row) per bh
// vt (bh, 16, 512): rows 0-7 = v dims, row 8 = 1.0, rows 9-15 = 0
__global__ void __launch_bounds__(256) k_vt(const unsigned short* __restrict__ v_nc,
                                            const int* __restrict__ idx,
                                            unsigned short* __restrict__ vt) {
  int bh = blockIdx.x;
  int b = bh >> 5, h = bh & 31;
  int t = threadIdx.x;
  unsigned short* dst = vt + (size_t)bh * 16 * 512;
  for (int i = t; i < 512; i += 256) dst[8 * 512 + i] = 0x3F80;       // 1.0 bf16
  for (int i = t; i < 512 * 7; i += 256) dst[9 * 512 + i] = 0;
  const int* ib = idx + b * KTOP;
  for (int kk = t; kk < 512; kk += 256) {
    uint4 v = *(const uint4*)&v_nc[((size_t)b * NV + ib[kk]) * 256 + h * 8];
    unsigned short tmp[8];
    *(uint4*)tmp = v;
#pragma unroll
    for (int d = 0; d < 8; ++d) dst[d * 512 + kk] = tmp[d];
  }
}

// ---------------------------------------------------------------- K6: MFMA flash attention
// per wave: 16 queries x 512 keys. QK^T 16x16x32 (d=8 zero-padded), exp2 in C-regs,
// P->LDS bf16 (wave-private, no barrier), PV 16x16x32 over keys; V^T ones-row gives sum(e).
__global__ void __launch_bounds__(256) k_fattn(const unsigned short* __restrict__ qh,
                                               const unsigned short* __restrict__ kg,
                                               const unsigned short* __restrict__ vt,
                                               unsigned short* __restrict__ aoydw) {
  __shared__ unsigned short P[4][16 * 40];
  int bh = blockIdx.x;
  int b = bh >> 5, h = bh & 31;
  int t = threadIdx.x, wave = t >> 6, lane = t & 63;
  int l15 = lane & 15, quad = lane >> 4;
  int n0 = blockIdx.y * 64 + wave * 16;
  bf16x8 aQ = {};
  if (quad == 0)
    aQ = *(const bf16x8*)&qh[((size_t)bh * NV + n0 + l15) * 8];
  unsigned short* Pw = P[wave];
  f32x4 accO = {0.f, 0.f, 0.f, 0.f};
  const unsigned short* kbase = kg + (size_t)bh * KTOP * 8;
  const unsigned short* vbase = vt + (size_t)bh * 16 * 512;
  for (int kc = 0; kc < 16; ++kc) {          // 32 keys per iteration
#pragma unroll
    for (int half = 0; half < 2; ++half) {   // 16 keys per QK mfma
      int key0 = kc * 32 + half * 16;
      bf16x8 bK = {};
      if (quad == 0)
        bK = *(const bf16x8*)&kbase[(size_t)(key0 + l15) * 8];
      f32x4 s = {0.f, 0.f, 0.f, 0.f};
      s = __builtin_amdgcn_mfma_f32_16x16x32_bf16(aQ, bK, s, 0, 0, 0);
      // s[r]: q_local = quad*4+r, key_local = l15
#pragma unroll
      for (int r = 0; r < 4; ++r)
        Pw[(quad * 4 + r) * 40 + half * 16 + l15] = f2bf(exp2f(s[r]));
    }
    bf16x8 aP = *(const bf16x8*)&Pw[l15 * 40 + quad * 8];                     // A: m=q, k=key
    bf16x8 bV = *(const bf16x8*)&vbase[(size_t)l15 * 512 + kc * 32 + quad * 8]; // B: n=vcol, k=key
    accO = __builtin_amdgcn_mfma_f32_16x16x32_bf16(aP, bV, accO, 0, 0, 0);
  }
  // accO[r]: vcol=l15, q_local=quad*4+r; sum(e) sits at vcol==8
#pragma unroll
  for (int r = 0; r < 4; ++r) {
    float se = __shfl(accO[r], quad * 16 + 8);
    float o = accO[r] * (1.0f / se);
    if (l15 < 8) {
      int n = n0 + quad * 4 + r;
      aoydw[((size_t)b * NV + n) * 512 + h * 8 + l15] = f2bf(o);
    }
  }
}

// ---------------------------------------------------------------- K7: depthwise conv, v_nc (n,c) bf16 -> aoydw cols 256+
__global__ void __launch_bounds__(256) k_dw(const unsigned short* __restrict__ v_nc,
                                            const float* __restrict__ wdw,
                                            const float* __restrict__ bdw,
                                            unsigned short* __restrict__ aoydw) {
  __shared__ float wls[256 * 27];
  int c = threadIdx.x;
  int b = blockIdx.y;
  for (int i = c; i < 256 * 27; i += 256) wls[i] = wdw[i];
  __syncthreads();
  float wr[27];
#pragma unroll
  for (int i = 0; i < 27; ++i) wr[i] = wls[c * 27 + i];
  float bias = bdw[c];
  const unsigned short* src = v_nc + (size_t)b * NV * 256 + c;
  unsigned short* dst = aoydw + (size_t)b * NV * 512 + 256 + c;
  for (int g = 0; g < 8; ++g) {              // 4 consecutive n (same h-row) share taps
    int n = blockIdx.x * 32 + g * 4;
    int d = n >> 8, h = (n >> 4) & 15, w = n & 15;
    float a0 = bias, a1 = bias, a2 = bias, a3 = bias;
#pragma unroll
    for (int kd = 0; kd < 3; ++kd) {
      int zd = d - 1 + kd; bool okd = (unsigned)zd < 16u;
#pragma unroll
      for (int kh = 0; kh < 3; ++kh) {
        int zh = h - 1 + kh; bool okh = okd && ((unsigned)zh < 16u);
        int rowb = zd * 256 + zh * 16;
        float v[6];
#pragma unroll
        for (int i = 0; i < 6; ++i) {
          int zw = w - 1 + i;
          bool ok = okh && ((unsigned)zw < 16u);   // wave-uniform mask
          v[i] = ok ? bf2f(src[(size_t)(rowb + zw) * 256]) : 0.f;
        }
        const float* wp = &wr[kd * 9 + kh * 3];
        a0 = fmaf(v[0], wp[0], fmaf(v[1], wp[1], fmaf(v[2], wp[2], a0)));
        a1 = fmaf(v[1], wp[0], fmaf(v[2], wp[1], fmaf(v[3], wp[2], a1)));
        a2 = fmaf(v[2], wp[0], fmaf(v[3], wp[1], fmaf(v[4], wp[2], a2)));
        a3 = fmaf(v[3], wp[0], fmaf(v[4], wp[1], fmaf(v[5], wp[2], a3)));
      }
    }
    dst[(size_t)(n + 0) * 512] = f2bf(a0);
    dst[(size_t)(n + 1) * 512] = f2bf(a1);
    dst[(size_t)(n + 2) * 512] = f2bf(a2);
    dst[(size_t)(n + 3) * 512] = f2bf(a3);
  }
}

// ---------------------------------------------------------------- K8: final GEMM K=512, MFMA bf16
__global__ void __launch_bounds__(256) k_final(const unsigned short* __restrict__ aoydw,
                                               const unsigned short* __restrict__ wcat,
                                               const float* __restrict__ bproj,
                                               const float* __restrict__ bpw,
                                               float* __restrict__ out) {
  __shared__ unsigned short Als[64 * 40];
  __shared__ unsigned short Bls[128 * 40];
  int n0 = blockIdx.x * 64, j0 = blockIdx.y * 128, b = blockIdx.z;
  int t = threadIdx.x;
  int wave = t >> 6, lane = t & 63;
  int l15 = lane & 15, q = lane >> 4, q8 = q * 8;
  int wn = (wave >> 1) * 32, wjj = (wave & 1) * 64;
  f32x4 acc[2][4] = {};
  const unsigned short* Abase = aoydw + (size_t)b * NV * 512;
  int ar = t >> 2, aq = t & 3;
  int br = t >> 1, bhh = t & 1;
  for (int c0 = 0; c0 < 512; c0 += 32) {
    __syncthreads();
    *(uint4*)&Als[ar * 40 + aq * 8] =
        *(const uint4*)&Abase[(size_t)(n0 + ar) * 512 + c0 + aq * 8];
    const unsigned short* sb = &wcat[(size_t)(j0 + br) * 512 + c0 + bhh * 16];
    *(uint4*)&Bls[br * 40 + bhh * 16]     = *(const uint4*)&sb[0];
    *(uint4*)&Bls[br * 40 + bhh * 16 + 8] = *(const uint4*)&sb[8];
    __syncthreads();
    bf16x8 af[2], bf[4];
#pragma unroll
    for (int mt = 0; mt < 2; ++mt)
      af[mt] = *(const bf16x8*)&Als[(wn + mt * 16 + l15) * 40 + q8];
#pragma unroll
    for (int nt = 0; nt < 4; ++nt)
      bf[nt] = *(const bf16x8*)&Bls[(wjj + nt * 16 + l15) * 40 + q8];
#pragma unroll
    for (int mt = 0; mt < 2; ++mt)
#pragma unroll
      for (int nt = 0; nt < 4; ++nt)
        acc[mt][nt] = __builtin_amdgcn_mfma_f32_16x16x32_bf16(af[mt], bf[nt], acc[mt][nt], 0, 0, 0);
  }
#pragma unroll
  for (int nt = 0; nt < 4; ++nt) {
    int j = j0 + wjj + nt * 16 + l15;
    float bl = bproj[j] + bpw[j];
#pragma unroll
    for (int mt = 0; mt < 2; ++mt) {
      int n = n0 + wn + mt * 16 + q * 4;
      float4 r = make_float4(acc[mt][nt][0] + bl, acc[mt][nt][1] + bl,
                             acc[mt][nt][2] + bl, acc[mt][nt][3] + bl);
      *(float4*)&out[(size_t)(b * 256 + j) * NV + n] = r;
    }
  }
}

// ---------------------------------------------------------------- launch
extern "C" void kernel_launch(void* const* d_in, const int* in_sizes, int n_in,
                              void* d_out, int out_size, void* d_ws, size_t ws_size,
                              hipStream_t stream) {
  const float* x_kv   = (const float*)d_in[0];
  const float* x_q    = (const float*)d_in[1];
  const float* w_spa  = (const float*)d_in[2];
  const float* w_kv   = (const float*)d_in[3];
  const float* b_kv   = (const float*)d_in[4];
  const float* w_q    = (const float*)d_in[5];
  const float* b_q    = (const float*)d_in[6];
  const float* w_proj = (const float*)d_in[7];
  const float* b_proj = (const float*)d_in[8];
  const float* w_dw   = (const float*)d_in[9];
  const float* b_dw   = (const float*)d_in[10];
  const float* w_pw   = (const float*)d_in[11];
  const float* b_pw   = (const float*)d_in[12];
  float* out = (float*)d_out;

  const size_t MB = 1024 * 1024;
  char* ws = (char*)d_ws;
  unsigned short* xkv_t = (unsigned short*)(ws);                 // 4 MB (b,n,c) bf16
  unsigned short* xq_t  = (unsigned short*)(ws + 4 * MB);        // 4 MB
  unsigned short* v_nc  = (unsigned short*)(ws + 8 * MB);        // 4 MB (b,n,c) bf16
  unsigned short* qh    = (unsigned short*)(ws + 12 * MB);       // 4 MB (b,h,n,8) bf16
  unsigned short* aoydw = (unsigned short*)(ws + 16 * MB);       // 8 MB (b,n,512) bf16
  unsigned short* kg    = (unsigned short*)(ws + 24 * MB);       // 512 KB (bh,512,8) bf16 pre-scaled
  unsigned short* vt    = (unsigned short*)(ws + 24 * MB + 512 * 1024);  // 1 MB (bh,16,512) bf16
  unsigned short* wv_t  = (unsigned short*)(ws + 26 * MB);               // 128 KB
  unsigned short* wq_t  = (unsigned short*)(ws + 26 * MB + 131072);      // 128 KB
  unsigned short* wcat  = (unsigned short*)(ws + 26 * MB + 262144);      // 256 KB
  float*          avgmx = (float*)(ws + 27 * MB);                        //  64 KB
  float*          scores= (float*)(ws + 27 * MB + 65536);               //  32 KB
  int*            idx   = (int*)  (ws + 27 * MB + 98304);               //   4 KB

  k_tcast<<<dim3(64, 4, 2), 256, 0, stream>>>(x_kv, (size_t)CN * NV, xkv_t, 256, (size_t)NV * 256);
  k_tcast<<<dim3(64, 4, 2), 256, 0, stream>>>(x_q,  (size_t)CN * NV, xq_t,  256, (size_t)NV * 256);
  k_wprep<<<dim3(4, 4, 4), 256, 0, stream>>>(w_kv, w_q, w_proj, w_pw, wv_t, wq_t, wcat);
  k_reduce<<<256, 256, 0, stream>>>(x_kv, avgmx);
  k_spa<<<64, 256, 0, stream>>>(avgmx, w_spa, scores);
  k_topk<<<2, 1024, 0, stream>>>(scores, idx);
  k_qv<<<dim3(32, 2, 4), 256, 0, stream>>>(xkv_t, xq_t, wv_t, wq_t, b_kv, b_q, v_nc, qh);
  k_projg<<<dim3(16, 4, 2), 256, 0, stream>>>(x_kv, w_kv, 512, b_kv, idx, kg);
  k_vt<<<64, 256, 0, stream>>>(v_nc, idx, vt);
  k_fattn<<<dim3(64, 64), 256, 0, stream>>>(qh, kg, vt, aoydw);
  k_dw<<<dim3(128, 2), 256, 0, stream>>>(v_nc, w_dw, b_dw, aoydw);
  k_final<<<dim3(64, 2, 2), 256, 0, stream>>>(aoydw, wcat, b_proj, b_pw, out);
}

// Round 11
// 265.532 us; speedup vs baseline: 2.3240x; 1.1342x over previous
//
#include <hip/hip_runtime.h>
#include <hip/hip_bf16.h>

typedef short bf16x8 __attribute__((ext_vector_type(8)));
typedef float f32x4 __attribute__((ext_vector_type(4)));

constexpr int CN = 256, NV = 4096, KTOP = 512;

static __device__ __forceinline__ unsigned short f2bf(float f) {
  __hip_bfloat16 h = __float2bfloat16(f);
  return *(unsigned short*)&h;
}
static __device__ __forceinline__ unsigned pack2(float a, float b) {
  return (unsigned)f2bf(a) | ((unsigned)f2bf(b) << 16);
}
static __device__ __forceinline__ float bf2f(unsigned short u) {
  return __uint_as_float(((unsigned)u) << 16);
}

// ---------------------------------------------------------------- K0: transpose-cast f32 (c,n) -> bf16 (n,c)
__global__ void __launch_bounds__(256) k_tcast(const float* __restrict__ src, size_t srcBS,
                                               unsigned short* __restrict__ dst, int dstLD,
                                               size_t dstBS) {
  __shared__ float tile[64 * 65];
  int b = blockIdx.z, c0 = blockIdx.y * 64, n0 = blockIdx.x * 64;
  const float* s = src + (size_t)b * srcBS;
  unsigned short* d = dst + (size_t)b * dstBS;
  int t = threadIdx.x;
  for (int i = 0; i < 16; ++i) {
    int id = i * 256 + t, c = id >> 6, n = id & 63;
    tile[c * 65 + n] = s[(size_t)(c0 + c) * NV + n0 + n];
  }
  __syncthreads();
  int n = t & 63, part = t >> 6;
  unsigned w[8];
#pragma unroll
  for (int k = 0; k < 8; ++k)
    w[k] = pack2(tile[(part * 16 + 2 * k) * 65 + n], tile[(part * 16 + 2 * k + 1) * 65 + n]);
  uint4* p = (uint4*)&d[(size_t)(n0 + n) * dstLD + c0 + part * 16];
  p[0] = make_uint4(w[0], w[1], w[2], w[3]);
  p[1] = make_uint4(w[4], w[5], w[6], w[7]);
}

// ---------------------------------------------------------------- K0b: weight prep -> bf16 (j, c) layouts
__global__ void __launch_bounds__(256) k_wprep(const float* __restrict__ wkv,
                                               const float* __restrict__ wq,
                                               const float* __restrict__ wproj,
                                               const float* __restrict__ wpw,
                                               unsigned short* __restrict__ wv_t,
                                               unsigned short* __restrict__ wq_t,
                                               unsigned short* __restrict__ wcat) {
  __shared__ float tile[64 * 65];
  int role = blockIdx.z;
  int j0 = blockIdx.x * 64, c0 = blockIdx.y * 64;
  int t = threadIdx.x;
  if (role == 3) {  // wpw (j,c) straight cast into wcat cols 256..512
    int j = t >> 2, part = t & 3;
    const float* s = &wpw[(size_t)(j0 + j) * 256 + c0 + part * 16];
    unsigned w[8];
#pragma unroll
    for (int k = 0; k < 8; ++k) w[k] = pack2(s[2 * k], s[2 * k + 1]);
    uint4* p = (uint4*)&wcat[(size_t)(j0 + j) * 512 + 256 + c0 + part * 16];
    p[0] = make_uint4(w[0], w[1], w[2], w[3]);
    p[1] = make_uint4(w[4], w[5], w[6], w[7]);
    return;
  }
  const float* src; int srcLD, srcOff; unsigned short* dst; int dstLD;
  if (role == 0)      { src = wkv;   srcLD = 512; srcOff = 256; dst = wv_t; dstLD = 256; }
  else if (role == 1) { src = wq;    srcLD = 256; srcOff = 0;   dst = wq_t; dstLD = 256; }
  else                { src = wproj; srcLD = 256; srcOff = 0;   dst = wcat; dstLD = 512; }
  for (int i = 0; i < 16; ++i) {
    int id = i * 256 + t, c = id >> 6, j = id & 63;
    tile[c * 65 + j] = src[(size_t)(c0 + c) * srcLD + srcOff + j0 + j];
  }
  __syncthreads();
  int j = t & 63, part = t >> 6;
  unsigned w[8];
#pragma unroll
  for (int k = 0; k < 8; ++k)
    w[k] = pack2(tile[(part * 16 + 2 * k) * 65 + j], tile[(part * 16 + 2 * k + 1) * 65 + j]);
  uint4* p = (uint4*)&dst[(size_t)(j0 + j) * dstLD + c0 + part * 16];
  p[0] = make_uint4(w[0], w[1], w[2], w[3]);
  p[1] = make_uint4(w[4], w[5], w[6], w[7]);
}

// ---------------------------------------------------------------- K1: channel mean/max
__global__ void __launch_bounds__(256) k_reduce(const float* __restrict__ xkv,
                                                float* __restrict__ avgmx) {
  __shared__ float ssum[256], smax[256];
  int blk = blockIdx.x;
  int b = blk >> 7, n0 = (blk & 127) * 32;
  int t = threadIdx.x, cg = t >> 5, nl = t & 31;
  int n = n0 + nl;
  const float* p = xkv + (size_t)b * CN * NV + (size_t)cg * 32 * NV + n;
  float s = 0.f, m = -1e30f;
  for (int i = 0; i < 32; ++i) {
    float v = p[(size_t)i * NV];
    s += v; m = fmaxf(m, v);
  }
  ssum[t] = s; smax[t] = m;
  __syncthreads();
  if (cg == 0) {
    for (int g = 1; g < 8; ++g) { s += ssum[g * 32 + nl]; m = fmaxf(m, smax[g * 32 + nl]); }
    avgmx[(b * 2 + 0) * NV + n] = s * (1.0f / 256.0f);
    avgmx[(b * 2 + 1) * NV + n] = m;
  }
}

// ---------------------------------------------------------------- K2: 7x7x7 conv + sigmoid
__global__ void __launch_bounds__(256) k_spa(const float* __restrict__ avgmx,
                                             const float* __restrict__ wspa,
                                             float* __restrict__ scores) {
  __shared__ float vol[2 * 4096];
  __shared__ float ws[686];
  int b = blockIdx.x >> 5, chunk = blockIdx.x & 31;
  int tid = threadIdx.x;
  for (int t = tid; t < 8192; t += 256) vol[t] = avgmx[b * 8192 + t];
  for (int t = tid; t < 686; t += 256) ws[t] = wspa[t];
  __syncthreads();
  int ci = tid & 1;
  int n = chunk * 128 + (tid >> 1);
  int d = n >> 8, h = (n >> 4) & 15, w = n & 15;
  const float* vb = vol + ci * 4096;
  const float* wb = ws + ci * 343;
  float acc = 0.f;
  for (int kd = 0; kd < 7; ++kd) {
    int zd = d - 3 + kd; if ((unsigned)zd >= 16u) continue;
    for (int kh = 0; kh < 7; ++kh) {
      int zh = h - 3 + kh; if ((unsigned)zh >= 16u) continue;
      const float* row = vb + zd * 256 + zh * 16;
      const float* wr = wb + kd * 49 + kh * 7;
#pragma unroll
      for (int kw = 0; kw < 7; ++kw) {
        int zw = w - 3 + kw;
        if ((unsigned)zw < 16u) acc += row[zw] * wr[kw];
      }
    }
  }
  acc += __shfl_xor(acc, 1);
  if (ci == 0) scores[b * NV + n] = 1.0f / (1.0f + expf(-acc));
}

// ---------------------------------------------------------------- K3: top-512 radix-select (parallel tie-rank)
__global__ void __launch_bounds__(1024) k_topk(const float* __restrict__ scores,
                                               int* __restrict__ idx) {
  __shared__ unsigned sv[4096];
  __shared__ unsigned hist[256];
  __shared__ int sB;
  __shared__ unsigned sSub, scnt;
  __shared__ int wsum[16];
  int b = blockIdx.x, tid = threadIdx.x;
  for (int t = tid; t < 4096; t += 1024) sv[t] = __float_as_uint(scores[b * NV + t]);
  if (tid == 0) scnt = 0;
  unsigned prefix = 0;
  int r = 512;
  for (int shift = 24; shift >= 0; shift -= 8) {
    if (tid < 256) hist[tid] = 0;
    __syncthreads();
    unsigned maskhi = (shift == 24) ? 0u : (0xFFFFFFFFu << (shift + 8));
    for (int i = 0; i < 4; ++i) {
      unsigned v = sv[tid + i * 1024];
      if ((v & maskhi) == prefix) atomicAdd(&hist[(v >> shift) & 255], 1u);
    }
    __syncthreads();
    for (int off = 1; off < 256; off <<= 1) {
      unsigned add = 0;
      if (tid < 256 && tid + off < 256) add = hist[tid + off];
      __syncthreads();
      if (tid < 256) hist[tid] += add;
      __syncthreads();
    }
    if (tid < 256) {
      unsigned s = hist[tid];
      unsigned snext = (tid < 255) ? hist[tid + 1] : 0u;
      if (s >= (unsigned)r && snext < (unsigned)r) { sB = tid; sSub = snext; }
    }
    __syncthreads();
    prefix |= ((unsigned)sB) << shift;
    r -= (int)sSub;
    __syncthreads();
  }
  unsigned vstar = prefix;
  for (int i = 0; i < 4; ++i) {
    int t = tid * 4 + i;
    if (sv[t] > vstar) { unsigned p = atomicAdd(&scnt, 1u); idx[b * KTOP + p] = t; }
  }
  __syncthreads();
  int base = (int)scnt;
  int loc = 0;
  for (int i = 0; i < 4; ++i) loc += (sv[tid * 4 + i] == vstar);
  int lane = tid & 63, w = tid >> 6;
  int x = loc;
  for (int off = 1; off < 64; off <<= 1) {
    int y = __shfl_up(x, off);
    if (lane >= off) x += y;
  }
  if (lane == 63) wsum[w] = x;
  __syncthreads();
  int wbase = 0;
  for (int i = 0; i < w; ++i) wbase += wsum[i];
  int excl = wbase + x - loc;
  for (int i = 0; i < 4; ++i) {
    int t = tid * 4 + i;
    if (sv[t] == vstar) {
      if (excl < r) idx[b * KTOP + base + excl] = t;
      ++excl;
    }
  }
}

// ---------------------------------------------------------------- K4: fused V+Q projection, MFMA bf16 -> bf16 outs
__global__ void __launch_bounds__(256) k_qv(const unsigned short* __restrict__ xkv_t,
                                            const unsigned short* __restrict__ xq_t,
                                            const unsigned short* __restrict__ wv_t,
                                            const unsigned short* __restrict__ wq_t,
                                            const float* __restrict__ bkv,
                                            const float* __restrict__ bq,
                                            unsigned short* __restrict__ v_nc,
                                            unsigned short* __restrict__ qh) {
  __shared__ unsigned short Als[128 * 40];
  __shared__ unsigned short Bls[128 * 40];
  int role = blockIdx.z;
  int b = role & 1;
  bool isQ = role >= 2;
  const unsigned short* A = isQ ? wq_t : wv_t;                              // (j=256, c=256)
  const unsigned short* B = (isQ ? xq_t : xkv_t) + (size_t)b * NV * 256;    // (n, c)
  const float* bias = isQ ? bq : (bkv + 256);
  int n0 = blockIdx.x * 128, j0 = blockIdx.y * 128;
  int t = threadIdx.x;
  int wave = t >> 6, lane = t & 63;
  int l15 = lane & 15, q = lane >> 4, q8 = q * 8;
  int wj = (wave >> 1) * 64, wn = (wave & 1) * 64;
  f32x4 acc[4][4] = {};
  int ar = t >> 1, ah = t & 1;
  for (int c0 = 0; c0 < 256; c0 += 32) {
    __syncthreads();
    {
      const unsigned short* sa = &A[(size_t)(j0 + ar) * 256 + c0 + ah * 16];
      *(uint4*)&Als[ar * 40 + ah * 16]     = *(const uint4*)&sa[0];
      *(uint4*)&Als[ar * 40 + ah * 16 + 8] = *(const uint4*)&sa[8];
      const unsigned short* sb = &B[(size_t)(n0 + ar) * 256 + c0 + ah * 16];
      *(uint4*)&Bls[ar * 40 + ah * 16]     = *(const uint4*)&sb[0];
      *(uint4*)&Bls[ar * 40 + ah * 16 + 8] = *(const uint4*)&sb[8];
    }
    __syncthreads();
    bf16x8 af[4], bf[4];
#pragma unroll
    for (int mt = 0; mt < 4; ++mt)
      af[mt] = *(const bf16x8*)&Als[(wj + mt * 16 + l15) * 40 + q8];
#pragma unroll
    for (int nt = 0; nt < 4; ++nt)
      bf[nt] = *(const bf16x8*)&Bls[(wn + nt * 16 + l15) * 40 + q8];
#pragma unroll
    for (int mt = 0; mt < 4; ++mt)
#pragma unroll
      for (int nt = 0; nt < 4; ++nt)
        acc[mt][nt] = __builtin_amdgcn_mfma_f32_16x16x32_bf16(af[mt], bf[nt], acc[mt][nt], 0, 0, 0);
  }
#pragma unroll
  for (int mt = 0; mt < 4; ++mt) {
    int jb = j0 + wj + mt * 16 + q * 4;          // 4 consecutive j
    float4 b4 = *(const float4*)&bias[jb];
#pragma unroll
    for (int nt = 0; nt < 4; ++nt) {
      int n = n0 + wn + nt * 16 + l15;
      float v0 = acc[mt][nt][0] + b4.x;
      float v1 = acc[mt][nt][1] + b4.y;
      float v2 = acc[mt][nt][2] + b4.z;
      float v3 = acc[mt][nt][3] + b4.w;
      uint2 pk = make_uint2(pack2(v0, v1), pack2(v2, v3));
      if (isQ) {
        int h = jb >> 3, d0 = jb & 7;            // jb%4==0 -> within one head
        *(uint2*)&qh[((size_t)(b * 32 + h) * NV + n) * 8 + d0] = pk;
      } else {
        *(uint2*)&v_nc[((size_t)b * NV + n) * 256 + jb] = pk;
      }
    }
  }
}

// ---------------------------------------------------------------- K5: gathered K projection (f32 compute, bf16 scaled out)
__global__ void k_projg(const float* __restrict__ X, const float* __restrict__ W, int ldw,
                        const float* __restrict__ bias, const int* __restrict__ map,
                        unsigned short* __restrict__ kg) {
  __shared__ float Xs[32 * 33];
  __shared__ float Ws[32 * 64];
  __shared__ int nmap[32];
  const float kscale = 0.35355339059327373f * 1.4426950408889634f;  // 1/sqrt(8)*log2(e)
  int m0 = blockIdx.x * 32, j0 = blockIdx.y * 64, b = blockIdx.z;
  int tid = threadIdx.x;
  if (tid < 32) nmap[tid] = map[b * KTOP + m0 + tid];
  int mm = tid >> 3, tj = (tid & 7) * 8;
  float acc[8] = {};
  const float* Xb = X + (size_t)b * CN * NV;
  for (int c0 = 0; c0 < 256; c0 += 32) {
    __syncthreads();
    for (int t = tid; t < 1024; t += 256) {
      int cc = t >> 5, mmm = t & 31;
      Xs[cc * 33 + mmm] = Xb[(size_t)(c0 + cc) * NV + nmap[mmm]];
    }
    for (int t = tid; t < 2048; t += 256) {
      int cc = t >> 6, jj = t & 63;
      Ws[cc * 64 + jj] = W[(size_t)(c0 + cc) * ldw + j0 + jj];
    }
    __syncthreads();
    for (int cc = 0; cc < 32; ++cc) {
      float xv = Xs[cc * 33 + mm];
      float4 w0 = *(const float4*)&Ws[cc * 64 + tj];
      float4 w1 = *(const float4*)&Ws[cc * 64 + tj + 4];
      acc[0] += xv * w0.x; acc[1] += xv * w0.y; acc[2] += xv * w0.z; acc[3] += xv * w0.w;
      acc[4] += xv * w1.x; acc[5] += xv * w1.y; acc[6] += xv * w1.z; acc[7] += xv * w1.w;
    }
  }
  int m = m0 + mm, j = j0 + tj;
  float s[8];
#pragma unroll
  for (int jj = 0; jj < 8; ++jj) s[jj] = (acc[jj] + bias[j + jj]) * kscale;
  unsigned short* outp = kg + ((size_t)(b * 32 + (j >> 3)) * KTOP + m) * 8;
  *(uint4*)outp = make_uint4(pack2(s[0], s[1]), pack2(s[2], s[3]),
                             pack2(s[4], s[5]), pack2(s[6], s[7]));
}

// ---------------------------------------------------------------- K5b: build V^T (+ones row) per bh
__global__ void __launch_bounds__(256) k_vt(const unsigned short* __restrict__ v_nc,
                                            const int* __restrict__ idx,
                                            unsigned short* __restrict__ vt) {
  int bh = blockIdx.x;
  int b = bh >> 5, h = bh & 31;
  int t = threadIdx.x;
  unsigned short* dst = vt + (size_t)bh * 16 * 512;
  for (int i = t; i < 512; i += 256) dst[8 * 512 + i] = 0x3F80;       // 1.0 bf16
  for (int i = t; i < 512 * 7; i += 256) dst[9 * 512 + i] = 0;
  const int* ib = idx + b * KTOP;
  for (int kk = t; kk < 512; kk += 256) {
    uint4 v = *(const uint4*)&v_nc[((size_t)b * NV + ib[kk]) * 256 + h * 8];
    unsigned short tmp[8];
    *(uint4*)tmp = v;
#pragma unroll
    for (int d = 0; d < 8; ++d) dst[d * 512 + kk] = tmp[d];
  }
}

// ---------------------------------------------------------------- K6: MFMA flash attention
__global__ void __launch_bounds__(256) k_fattn(const unsigned short* __restrict__ qh,
                                               const unsigned short* __restrict__ kg,
                                               const unsigned short* __restrict__ vt,
                                               unsigned short* __restrict__ aoydw) {
  __shared__ unsigned short P[4][16 * 40];
  int bh = blockIdx.x;
  int b = bh >> 5, h = bh & 31;
  int t = threadIdx.x, wave = t >> 6, lane = t & 63;
  int l15 = lane & 15, quad = lane >> 4;
  int n0 = blockIdx.y * 64 + wave * 16;
  bf16x8 aQ = {};
  if (quad == 0)
    aQ = *(const bf16x8*)&qh[((size_t)bh * NV + n0 + l15) * 8];
  unsigned short* Pw = P[wave];
  f32x4 accO = {0.f, 0.f, 0.f, 0.f};
  const unsigned short* kbase = kg + (size_t)bh * KTOP * 8;
  const unsigned short* vbase = vt + (size_t)bh * 16 * 512;
  for (int kc = 0; kc < 16; ++kc) {          // 32 keys per iteration
#pragma unroll
    for (int half = 0; half < 2; ++half) {   // 16 keys per QK mfma
      int key0 = kc * 32 + half * 16;
      bf16x8 bK = {};
      if (quad == 0)
        bK = *(const bf16x8*)&kbase[(size_t)(key0 + l15) * 8];
      f32x4 s = {0.f, 0.f, 0.f, 0.f};
      s = __builtin_amdgcn_mfma_f32_16x16x32_bf16(aQ, bK, s, 0, 0, 0);
#pragma unroll
      for (int r = 0; r < 4; ++r)
        Pw[(quad * 4 + r) * 40 + half * 16 + l15] = f2bf(exp2f(s[r]));
    }
    bf16x8 aP = *(const bf16x8*)&Pw[l15 * 40 + quad * 8];                     // A: m=q, k=key
    bf16x8 bV = *(const bf16x8*)&vbase[(size_t)l15 * 512 + kc * 32 + quad * 8]; // B: n=vcol, k=key
    accO = __builtin_amdgcn_mfma_f32_16x16x32_bf16(aP, bV, accO, 0, 0, 0);
  }
#pragma unroll
  for (int r = 0; r < 4; ++r) {
    float se = __shfl(accO[r], quad * 16 + 8);
    float o = accO[r] * (1.0f / se);
    if (l15 < 8) {
      int n = n0 + quad * 4 + r;
      aoydw[((size_t)b * NV + n) * 512 + h * 8 + l15] = f2bf(o);
    }
  }
}

// ---------------------------------------------------------------- K7: depthwise conv, v_nc (n,c) bf16 -> aoydw cols 256+
// round-10 fix: grid 2048 blocks (8/CU) for latency hiding; no LDS weight stage
__global__ void __launch_bounds__(256) k_dw(const unsigned short* __restrict__ v_nc,
                                            const float* __restrict__ wdw,
                                            const float* __restrict__ bdw,
                                            unsigned short* __restrict__ aoydw) {
  int c = threadIdx.x;
  int b = blockIdx.y;
  float wr[27];
#pragma unroll
  for (int i = 0; i < 27; ++i) wr[i] = wdw[c * 27 + i];
  float bias = bdw[c];
  const unsigned short* src = v_nc + (size_t)b * NV * 256 + c;
  unsigned short* dst = aoydw + (size_t)b * NV * 512 + 256 + c;
  int n = blockIdx.x * 4;                    // 4 consecutive n (same h-row) share taps
  int d = n >> 8, h = (n >> 4) & 15, w = n & 15;
  float a0 = bias, a1 = bias, a2 = bias, a3 = bias;
#pragma unroll
  for (int kd = 0; kd < 3; ++kd) {
    int zd = d - 1 + kd; bool okd = (unsigned)zd < 16u;
#pragma unroll
    for (int kh = 0; kh < 3; ++kh) {
      int zh = h - 1 + kh; bool okh = okd && ((unsigned)zh < 16u);
      int rowb = zd * 256 + zh * 16;
      float v[6];
#pragma unroll
      for (int i = 0; i < 6; ++i) {
        int zw = w - 1 + i;
        bool ok = okh && ((unsigned)zw < 16u);   // wave-uniform mask
        v[i] = ok ? bf2f(src[(size_t)(rowb + zw) * 256]) : 0.f;
      }
      const float* wp = &wr[kd * 9 + kh * 3];
      a0 = fmaf(v[0], wp[0], fmaf(v[1], wp[1], fmaf(v[2], wp[2], a0)));
      a1 = fmaf(v[1], wp[0], fmaf(v[2], wp[1], fmaf(v[3], wp[2], a1)));
      a2 = fmaf(v[2], wp[0], fmaf(v[3], wp[1], fmaf(v[4], wp[2], a2)));
      a3 = fmaf(v[3], wp[0], fmaf(v[4], wp[1], fmaf(v[5], wp[2], a3)));
    }
  }
  dst[(size_t)(n + 0) * 512] = f2bf(a0);
  dst[(size_t)(n + 1) * 512] = f2bf(a1);
  dst[(size_t)(n + 2) * 512] = f2bf(a2);
  dst[(size_t)(n + 3) * 512] = f2bf(a3);
}

// ---------------------------------------------------------------- K8: final GEMM K=512, MFMA bf16
__global__ void __launch_bounds__(256) k_final(const unsigned short* __restrict__ aoydw,
                                               const unsigned short* __restrict__ wcat,
                                               const float* __restrict__ bproj,
                                               const float* __restrict__ bpw,
                                               float* __restrict__ out) {
  __shared__ unsigned short Als[64 * 40];
  __shared__ unsigned short Bls[128 * 40];
  int n0 = blockIdx.x * 64, j0 = blockIdx.y * 128, b = blockIdx.z;
  int t = threadIdx.x;
  int wave = t >> 6, lane = t & 63;
  int l15 = lane & 15, q = lane >> 4, q8 = q * 8;
  int wn = (wave >> 1) * 32, wjj = (wave & 1) * 64;
  f32x4 acc[2][4] = {};
  const unsigned short* Abase = aoydw + (size_t)b * NV * 512;
  int ar = t >> 2, aq = t & 3;
  int br = t >> 1, bhh = t & 1;
  for (int c0 = 0; c0 < 512; c0 += 32) {
    __syncthreads();
    *(uint4*)&Als[ar * 40 + aq * 8] =
        *(const uint4*)&Abase[(size_t)(n0 + ar) * 512 + c0 + aq * 8];
    const unsigned short* sb = &wcat[(size_t)(j0 + br) * 512 + c0 + bhh * 16];
    *(uint4*)&Bls[br * 40 + bhh * 16]     = *(const uint4*)&sb[0];
    *(uint4*)&Bls[br * 40 + bhh * 16 + 8] = *(const uint4*)&sb[8];
    __syncthreads();
    bf16x8 af[2], bf[4];
#pragma unroll
    for (int mt = 0; mt < 2; ++mt)
      af[mt] = *(const bf16x8*)&Als[(wn + mt * 16 + l15) * 40 + q8];
#pragma unroll
    for (int nt = 0; nt < 4; ++nt)
      bf[nt] = *(const bf16x8*)&Bls[(wjj + nt * 16 + l15) * 40 + q8];
#pragma unroll
    for (int mt = 0; mt < 2; ++mt)
#pragma unroll
      for (int nt = 0; nt < 4; ++nt)
        acc[mt][nt] = __builtin_amdgcn_mfma_f32_16x16x32_bf16(af[mt], bf[nt], acc[mt][nt], 0, 0, 0);
  }
#pragma unroll
  for (int nt = 0; nt < 4; ++nt) {
    int j = j0 + wjj + nt * 16 + l15;
    float bl = bproj[j] + bpw[j];
#pragma unroll
    for (int mt = 0; mt < 2; ++mt) {
      int n = n0 + wn + mt * 16 + q * 4;
      float4 r = make_float4(acc[mt][nt][0] + bl, acc[mt][nt][1] + bl,
                             acc[mt][nt][2] + bl, acc[mt][nt][3] + bl);
      *(float4*)&out[(size_t)(b * 256 + j) * NV + n] = r;
    }
  }
}

// ---------------------------------------------------------------- launch
extern "C" void kernel_launch(void* const* d_in, const int* in_sizes, int n_in,
                              void* d_out, int out_size, void* d_ws, size_t ws_size,
                              hipStream_t stream) {
  const float* x_kv   = (const float*)d_in[0];
  const float* x_q    = (const float*)d_in[1];
  const float* w_spa  = (const float*)d_in[2];
  const float* w_kv   = (const float*)d_in[3];
  const float* b_kv   = (const float*)d_in[4];
  const float* w_q    = (const float*)d_in[5];
  const float* b_q    = (const float*)d_in[6];
  const float* w_proj = (const float*)d_in[7];
  const float* b_proj = (const float*)d_in[8];
  const float* w_dw   = (const float*)d_in[9];
  const float* b_dw   = (const float*)d_in[10];
  const float* w_pw   = (const float*)d_in[11];
  const float* b_pw   = (const float*)d_in[12];
  float* out = (float*)d_out;

  const size_t MB = 1024 * 1024;
  char* ws = (char*)d_ws;
  unsigned short* xkv_t = (unsigned short*)(ws);                 // 4 MB (b,n,c) bf16
  unsigned short* xq_t  = (unsigned short*)(ws + 4 * MB);        // 4 MB
  unsigned short* v_nc  = (unsigned short*)(ws + 8 * MB);        // 4 MB (b,n,c) bf16
  unsigned short* qh    = (unsigned short*)(ws + 12 * MB);       // 4 MB (b,h,n,8) bf16
  unsigned short* aoydw = (unsigned short*)(ws + 16 * MB);       // 8 MB (b,n,512) bf16
  unsigned short* kg    = (unsigned short*)(ws + 24 * MB);       // 512 KB (bh,512,8) bf16 pre-scaled
  unsigned short* vt    = (unsigned short*)(ws + 24 * MB + 512 * 1024);  // 1 MB (bh,16,512) bf16
  unsigned short* wv_t  = (unsigned short*)(ws + 26 * MB);               // 128 KB
  unsigned short* wq_t  = (unsigned short*)(ws + 26 * MB + 131072);      // 128 KB
  unsigned short* wcat  = (unsigned short*)(ws + 26 * MB + 262144);      // 256 KB
  float*          avgmx = (float*)(ws + 27 * MB);                        //  64 KB
  float*          scores= (float*)(ws + 27 * MB + 65536);               //  32 KB
  int*            idx   = (int*)  (ws + 27 * MB + 98304);               //   4 KB

  k_tcast<<<dim3(64, 4, 2), 256, 0, stream>>>(x_kv, (size_t)CN * NV, xkv_t, 256, (size_t)NV * 256);
  k_tcast<<<dim3(64, 4, 2), 256, 0, stream>>>(x_q,  (size_t)CN * NV, xq_t,  256, (size_t)NV * 256);
  k_wprep<<<dim3(4, 4, 4), 256, 0, stream>>>(w_kv, w_q, w_proj, w_pw, wv_t, wq_t, wcat);
  k_reduce<<<256, 256, 0, stream>>>(x_kv, avgmx);
  k_spa<<<64, 256, 0, stream>>>(avgmx, w_spa, scores);
  k_topk<<<2, 1024, 0, stream>>>(scores, idx);
  k_qv<<<dim3(32, 2, 4), 256, 0, stream>>>(xkv_t, xq_t, wv_t, wq_t, b_kv, b_q, v_nc, qh);
  k_projg<<<dim3(16, 4, 2), 256, 0, stream>>>(x_kv, w_kv, 512, b_kv, idx, kg);
  k_vt<<<64, 256, 0, stream>>>(v_nc, idx, vt);
  k_fattn<<<dim3(64, 64), 256, 0, stream>>>(qh, kg, vt, aoydw);
  k_dw<<<dim3(1024, 2), 256, 0, stream>>>(v_nc, w_dw, b_dw, aoydw);
  k_final<<<dim3(64, 2, 2), 256, 0, stream>>>(aoydw, wcat, b_proj, b_pw, out);
}

// Round 12
// 260.845 us; speedup vs baseline: 2.3658x; 1.0180x over previous
//
#include <hip/hip_runtime.h>
#include <hip/hip_bf16.h>

typedef short bf16x8 __attribute__((ext_vector_type(8)));
typedef float f32x4 __attribute__((ext_vector_type(4)));

constexpr int CN = 256, NV = 4096, KTOP = 512;

static __device__ __forceinline__ unsigned short f2bf(float f) {
  __hip_bfloat16 h = __float2bfloat16(f);
  return *(unsigned short*)&h;
}
static __device__ __forceinline__ unsigned pack2(float a, float b) {
  return (unsigned)f2bf(a) | ((unsigned)f2bf(b) << 16);
}
static __device__ __forceinline__ float bf2f(unsigned short u) {
  return __uint_as_float(((unsigned)u) << 16);
}

// ---------------------------------------------------------------- K0: transpose-cast f32 (c,n) -> bf16 (n,c)
// z = 0,1: x_kv batches; z = 2,3: x_q batches (merged launch)
__global__ void __launch_bounds__(256) k_tcast2(const float* __restrict__ srcA,
                                                const float* __restrict__ srcB,
                                                unsigned short* __restrict__ dstA,
                                                unsigned short* __restrict__ dstB) {
  __shared__ float tile[64 * 65];
  int z = blockIdx.z, b = z & 1;
  const float* s = (z < 2 ? srcA : srcB) + (size_t)b * CN * NV;
  unsigned short* d = (z < 2 ? dstA : dstB) + (size_t)b * NV * 256;
  int c0 = blockIdx.y * 64, n0 = blockIdx.x * 64;
  int t = threadIdx.x;
  for (int i = 0; i < 16; ++i) {
    int id = i * 256 + t, c = id >> 6, n = id & 63;
    tile[c * 65 + n] = s[(size_t)(c0 + c) * NV + n0 + n];
  }
  __syncthreads();
  int n = t & 63, part = t >> 6;
  unsigned w[8];
#pragma unroll
  for (int k = 0; k < 8; ++k)
    w[k] = pack2(tile[(part * 16 + 2 * k) * 65 + n], tile[(part * 16 + 2 * k + 1) * 65 + n]);
  uint4* p = (uint4*)&d[(size_t)(n0 + n) * 256 + c0 + part * 16];
  p[0] = make_uint4(w[0], w[1], w[2], w[3]);
  p[1] = make_uint4(w[4], w[5], w[6], w[7]);
}

// ---------------------------------------------------------------- K0b: weight prep -> bf16 (j, c) layouts
__global__ void __launch_bounds__(256) k_wprep(const float* __restrict__ wkv,
                                               const float* __restrict__ wq,
                                               const float* __restrict__ wproj,
                                               const float* __restrict__ wpw,
                                               unsigned short* __restrict__ wv_t,
                                               unsigned short* __restrict__ wq_t,
                                               unsigned short* __restrict__ wcat) {
  __shared__ float tile[64 * 65];
  int role = blockIdx.z;
  int j0 = blockIdx.x * 64, c0 = blockIdx.y * 64;
  int t = threadIdx.x;
  if (role == 3) {  // wpw (j,c) straight cast into wcat cols 256..512
    int j = t >> 2, part = t & 3;
    const float* s = &wpw[(size_t)(j0 + j) * 256 + c0 + part * 16];
    unsigned w[8];
#pragma unroll
    for (int k = 0; k < 8; ++k) w[k] = pack2(s[2 * k], s[2 * k + 1]);
    uint4* p = (uint4*)&wcat[(size_t)(j0 + j) * 512 + 256 + c0 + part * 16];
    p[0] = make_uint4(w[0], w[1], w[2], w[3]);
    p[1] = make_uint4(w[4], w[5], w[6], w[7]);
    return;
  }
  const float* src; int srcLD, srcOff; unsigned short* dst; int dstLD;
  if (role == 0)      { src = wkv;   srcLD = 512; srcOff = 256; dst = wv_t; dstLD = 256; }
  else if (role == 1) { src = wq;    srcLD = 256; srcOff = 0;   dst = wq_t; dstLD = 256; }
  else                { src = wproj; srcLD = 256; srcOff = 0;   dst = wcat; dstLD = 512; }
  for (int i = 0; i < 16; ++i) {
    int id = i * 256 + t, c = id >> 6, j = id & 63;
    tile[c * 65 + j] = src[(size_t)(c0 + c) * srcLD + srcOff + j0 + j];
  }
  __syncthreads();
  int j = t & 63, part = t >> 6;
  unsigned w[8];
#pragma unroll
  for (int k = 0; k < 8; ++k)
    w[k] = pack2(tile[(part * 16 + 2 * k) * 65 + j], tile[(part * 16 + 2 * k + 1) * 65 + j]);
  uint4* p = (uint4*)&dst[(size_t)(j0 + j) * dstLD + c0 + part * 16];
  p[0] = make_uint4(w[0], w[1], w[2], w[3]);
  p[1] = make_uint4(w[4], w[5], w[6], w[7]);
}

// ---------------------------------------------------------------- K1: channel mean/max
__global__ void __launch_bounds__(256) k_reduce(const float* __restrict__ xkv,
                                                float* __restrict__ avgmx) {
  __shared__ float ssum[256], smax[256];
  int blk = blockIdx.x;
  int b = blk >> 7, n0 = (blk & 127) * 32;
  int t = threadIdx.x, cg = t >> 5, nl = t & 31;
  int n = n0 + nl;
  const float* p = xkv + (size_t)b * CN * NV + (size_t)cg * 32 * NV + n;
  float s = 0.f, m = -1e30f;
  for (int i = 0; i < 32; ++i) {
    float v = p[(size_t)i * NV];
    s += v; m = fmaxf(m, v);
  }
  ssum[t] = s; smax[t] = m;
  __syncthreads();
  if (cg == 0) {
    for (int g = 1; g < 8; ++g) { s += ssum[g * 32 + nl]; m = fmaxf(m, smax[g * 32 + nl]); }
    avgmx[(b * 2 + 0) * NV + n] = s * (1.0f / 256.0f);
    avgmx[(b * 2 + 1) * NV + n] = m;
  }
}

// ---------------------------------------------------------------- K2: 7x7x7 conv + sigmoid
__global__ void __launch_bounds__(256) k_spa(const float* __restrict__ avgmx,
                                             const float* __restrict__ wspa,
                                             float* __restrict__ scores) {
  __shared__ float vol[2 * 4096];
  __shared__ float ws[686];
  int b = blockIdx.x >> 5, chunk = blockIdx.x & 31;
  int tid = threadIdx.x;
  for (int t = tid; t < 8192; t += 256) vol[t] = avgmx[b * 8192 + t];
  for (int t = tid; t < 686; t += 256) ws[t] = wspa[t];
  __syncthreads();
  int ci = tid & 1;
  int n = chunk * 128 + (tid >> 1);
  int d = n >> 8, h = (n >> 4) & 15, w = n & 15;
  const float* vb = vol + ci * 4096;
  const float* wb = ws + ci * 343;
  float acc = 0.f;
  for (int kd = 0; kd < 7; ++kd) {
    int zd = d - 3 + kd; if ((unsigned)zd >= 16u) continue;
    for (int kh = 0; kh < 7; ++kh) {
      int zh = h - 3 + kh; if ((unsigned)zh >= 16u) continue;
      const float* row = vb + zd * 256 + zh * 16;
      const float* wr = wb + kd * 49 + kh * 7;
#pragma unroll
      for (int kw = 0; kw < 7; ++kw) {
        int zw = w - 3 + kw;
        if ((unsigned)zw < 16u) acc += row[zw] * wr[kw];
      }
    }
  }
  acc += __shfl_xor(acc, 1);
  if (ci == 0) scores[b * NV + n] = 1.0f / (1.0f + expf(-acc));
}

// ---------------------------------------------------------------- K3: top-512 radix-select (wave-scan, fewer barriers)
__global__ void __launch_bounds__(1024) k_topk(const float* __restrict__ scores,
                                               int* __restrict__ idx) {
  __shared__ unsigned sv[4096];
  __shared__ int sB;
  __shared__ unsigned sSub, scnt;
  __shared__ unsigned hist[256];
  __shared__ int wsum[16];
  int b = blockIdx.x, tid = threadIdx.x;
  for (int t = tid; t < 4096; t += 1024) sv[t] = __float_as_uint(scores[b * NV + t]);
  if (tid == 0) scnt = 0;
  unsigned prefix = 0;
  int r = 512;
  for (int shift = 24; shift >= 0; shift -= 8) {
    if (tid < 256) hist[tid] = 0;
    __syncthreads();
    unsigned maskhi = (shift == 24) ? 0u : (0xFFFFFFFFu << (shift + 8));
    for (int i = 0; i < 4; ++i) {
      unsigned v = sv[tid + i * 1024];
      if ((v & maskhi) == prefix) atomicAdd(&hist[(v >> shift) & 255], 1u);
    }
    __syncthreads();
    if (tid < 64) {  // single wave: 4 bins/lane, shfl suffix scan, no barriers
      int lane = tid;
      unsigned h0 = hist[lane * 4 + 0], h1 = hist[lane * 4 + 1];
      unsigned h2 = hist[lane * 4 + 2], h3 = hist[lane * 4 + 3];
      unsigned s = h0 + h1 + h2 + h3;
      for (int off = 1; off < 64; off <<= 1) {
        unsigned y = __shfl_down(s, off);
        if (lane + off < 64) s += y;
      }
      unsigned tail = __shfl_down(s, 1);
      if (lane == 63) tail = 0;
      unsigned s3 = tail + h3, s2 = s3 + h2, s1 = s2 + h1, s0 = s1 + h0;
      unsigned sx[5] = {s0, s1, s2, s3, tail};
#pragma unroll
      for (int i = 0; i < 4; ++i)
        if (sx[i] >= (unsigned)r && sx[i + 1] < (unsigned)r) { sB = lane * 4 + i; sSub = sx[i + 1]; }
    }
    __syncthreads();
    prefix |= ((unsigned)sB) << shift;
    r -= (int)sSub;
    __syncthreads();
  }
  unsigned vstar = prefix;
  for (int i = 0; i < 4; ++i) {
    int t = tid * 4 + i;
    if (sv[t] > vstar) { unsigned p = atomicAdd(&scnt, 1u); idx[b * KTOP + p] = t; }
  }
  __syncthreads();
  int base = (int)scnt;
  int loc = 0;
  for (int i = 0; i < 4; ++i) loc += (sv[tid * 4 + i] == vstar);
  int lane = tid & 63, w = tid >> 6;
  int x = loc;
  for (int off = 1; off < 64; off <<= 1) {
    int y = __shfl_up(x, off);
    if (lane >= off) x += y;
  }
  if (lane == 63) wsum[w] = x;
  __syncthreads();
  int wbase = 0;
  for (int i = 0; i < w; ++i) wbase += wsum[i];
  int excl = wbase + x - loc;
  for (int i = 0; i < 4; ++i) {
    int t = tid * 4 + i;
    if (sv[t] == vstar) {
      if (excl < r) idx[b * KTOP + base + excl] = t;
      ++excl;
    }
  }
}

// ---------------------------------------------------------------- K4: fused V+Q projection, MFMA bf16 -> bf16 outs
__global__ void __launch_bounds__(256) k_qv(const unsigned short* __restrict__ xkv_t,
                                            const unsigned short* __restrict__ xq_t,
                                            const unsigned short* __restrict__ wv_t,
                                            const unsigned short* __restrict__ wq_t,
                                            const float* __restrict__ bkv,
                                            const float* __restrict__ bq,
                                            unsigned short* __restrict__ v_nc,
                                            unsigned short* __restrict__ qh) {
  __shared__ unsigned short Als[128 * 40];
  __shared__ unsigned short Bls[128 * 40];
  int role = blockIdx.z;
  int b = role & 1;
  bool isQ = role >= 2;
  const unsigned short* A = isQ ? wq_t : wv_t;                              // (j=256, c=256)
  const unsigned short* B = (isQ ? xq_t : xkv_t) + (size_t)b * NV * 256;    // (n, c)
  const float* bias = isQ ? bq : (bkv + 256);
  int n0 = blockIdx.x * 128, j0 = blockIdx.y * 128;
  int t = threadIdx.x;
  int wave = t >> 6, lane = t & 63;
  int l15 = lane & 15, q = lane >> 4, q8 = q * 8;
  int wj = (wave >> 1) * 64, wn = (wave & 1) * 64;
  f32x4 acc[4][4] = {};
  int ar = t >> 1, ah = t & 1;
  for (int c0 = 0; c0 < 256; c0 += 32) {
    __syncthreads();
    {
      const unsigned short* sa = &A[(size_t)(j0 + ar) * 256 + c0 + ah * 16];
      *(uint4*)&Als[ar * 40 + ah * 16]     = *(const uint4*)&sa[0];
      *(uint4*)&Als[ar * 40 + ah * 16 + 8] = *(const uint4*)&sa[8];
      const unsigned short* sb = &B[(size_t)(n0 + ar) * 256 + c0 + ah * 16];
      *(uint4*)&Bls[ar * 40 + ah * 16]     = *(const uint4*)&sb[0];
      *(uint4*)&Bls[ar * 40 + ah * 16 + 8] = *(const uint4*)&sb[8];
    }
    __syncthreads();
    bf16x8 af[4], bf[4];
#pragma unroll
    for (int mt = 0; mt < 4; ++mt)
      af[mt] = *(const bf16x8*)&Als[(wj + mt * 16 + l15) * 40 + q8];
#pragma unroll
    for (int nt = 0; nt < 4; ++nt)
      bf[nt] = *(const bf16x8*)&Bls[(wn + nt * 16 + l15) * 40 + q8];
#pragma unroll
    for (int mt = 0; mt < 4; ++mt)
#pragma unroll
      for (int nt = 0; nt < 4; ++nt)
        acc[mt][nt] = __builtin_amdgcn_mfma_f32_16x16x32_bf16(af[mt], bf[nt], acc[mt][nt], 0, 0, 0);
  }
#pragma unroll
  for (int mt = 0; mt < 4; ++mt) {
    int jb = j0 + wj + mt * 16 + q * 4;          // 4 consecutive j
    float4 b4 = *(const float4*)&bias[jb];
#pragma unroll
    for (int nt = 0; nt < 4; ++nt) {
      int n = n0 + wn + nt * 16 + l15;
      float v0 = acc[mt][nt][0] + b4.x;
      float v1 = acc[mt][nt][1] + b4.y;
      float v2 = acc[mt][nt][2] + b4.z;
      float v3 = acc[mt][nt][3] + b4.w;
      uint2 pk = make_uint2(pack2(v0, v1), pack2(v2, v3));
      if (isQ) {
        int h = jb >> 3, d0 = jb & 7;            // jb%4==0 -> within one head
        *(uint2*)&qh[((size_t)(b * 32 + h) * NV + n) * 8 + d0] = pk;
      } else {
        *(uint2*)&v_nc[((size_t)b * NV + n) * 256 + jb] = pk;
      }
    }
  }
}

// ---------------------------------------------------------------- K5: gathered K projection (f32 compute, bf16 scaled out)
__global__ void k_projg(const float* __restrict__ X, const float* __restrict__ W, int ldw,
                        const float* __restrict__ bias, const int* __restrict__ map,
                        unsigned short* __restrict__ kg) {
  __shared__ float Xs[32 * 33];
  __shared__ float Ws[32 * 64];
  __shared__ int nmap[32];
  const float kscale = 0.35355339059327373f * 1.4426950408889634f;  // 1/sqrt(8)*log2(e)
  int m0 = blockIdx.x * 32, j0 = blockIdx.y * 64, b = blockIdx.z;
  int tid = threadIdx.x;
  if (tid < 32) nmap[tid] = map[b * KTOP + m0 + tid];
  int mm = tid >> 3, tj = (tid & 7) * 8;
  float acc[8] = {};
  const float* Xb = X + (size_t)b * CN * NV;
  for (int c0 = 0; c0 < 256; c0 += 32) {
    __syncthreads();
    for (int t = tid; t < 1024; t += 256) {
      int cc = t >> 5, mmm = t & 31;
      Xs[cc * 33 + mmm] = Xb[(size_t)(c0 + cc) * NV + nmap[mmm]];
    }
    for (int t = tid; t < 2048; t += 256) {
      int cc = t >> 6, jj = t & 63;
      Ws[cc * 64 + jj] = W[(size_t)(c0 + cc) * ldw + j0 + jj];
    }
    __syncthreads();
    for (int cc = 0; cc < 32; ++cc) {
      float xv = Xs[cc * 33 + mm];
      float4 w0 = *(const float4*)&Ws[cc * 64 + tj];
      float4 w1 = *(const float4*)&Ws[cc * 64 + tj + 4];
      acc[0] += xv * w0.x; acc[1] += xv * w0.y; acc[2] += xv * w0.z; acc[3] += xv * w0.w;
      acc[4] += xv * w1.x; acc[5] += xv * w1.y; acc[6] += xv * w1.z; acc[7] += xv * w1.w;
    }
  }
  int m = m0 + mm, j = j0 + tj;
  float s[8];
#pragma unroll
  for (int jj = 0; jj < 8; ++jj) s[jj] = (acc[jj] + bias[j + jj]) * kscale;
  unsigned short* outp = kg + ((size_t)(b * 32 + (j >> 3)) * KTOP + m) * 8;
  *(uint4*)outp = make_uint4(pack2(s[0], s[1]), pack2(s[2], s[3]),
                             pack2(s[4], s[5]), pack2(s[6], s[7]));
}

// ---------------------------------------------------------------- K5b: build V^T (+ones row) per bh
__global__ void __launch_bounds__(256) k_vt(const unsigned short* __restrict__ v_nc,
                                            const int* __restrict__ idx,
                                            unsigned short* __restrict__ vt) {
  int bh = blockIdx.x;
  int b = bh >> 5, h = bh & 31;
  int t = threadIdx.x;
  unsigned short* dst = vt + (size_t)bh * 16 * 512;
  for (int i = t; i < 512; i += 256) dst[8 * 512 + i] = 0x3F80;       // 1.0 bf16
  for (int i = t; i < 512 * 7; i += 256) dst[9 * 512 + i] = 0;
  const int* ib = idx + b * KTOP;
  for (int kk = t; kk < 512; kk += 256) {
    uint4 v = *(const uint4*)&v_nc[((size_t)b * NV + ib[kk]) * 256 + h * 8];
    unsigned short tmp[8];
    *(uint4*)tmp = v;
#pragma unroll
    for (int d = 0; d < 8; ++d) dst[d * 512 + kk] = tmp[d];
  }
}

// ---------------------------------------------------------------- K6: MFMA flash attention
// round-12: raw v_exp_f32 + truncated bf16 P-store (was: libm exp2f + RNE pack, ~5x VALU)
__global__ void __launch_bounds__(256) k_fattn(const unsigned short* __restrict__ qh,
                                               const unsigned short* __restrict__ kg,
                                               const unsigned short* __restrict__ vt,
                                               unsigned short* __restrict__ aoydw) {
  __shared__ unsigned short P[4][16 * 40];
  int bh = blockIdx.x;
  int b = bh >> 5, h = bh & 31;
  int t = threadIdx.x, wave = t >> 6, lane = t & 63;
  int l15 = lane & 15, quad = lane >> 4;
  int n0 = blockIdx.y * 64 + wave * 16;
  bf16x8 aQ = {};
  if (quad == 0)
    aQ = *(const bf16x8*)&qh[((size_t)bh * NV + n0 + l15) * 8];
  unsigned short* Pw = P[wave];
  f32x4 accO = {0.f, 0.f, 0.f, 0.f};
  const unsigned short* kbase = kg + (size_t)bh * KTOP * 8;
  const unsigned short* vbase = vt + (size_t)bh * 16 * 512;
  for (int kc = 0; kc < 16; ++kc) {          // 32 keys per iteration
#pragma unroll
    for (int half = 0; half < 2; ++half) {   // 16 keys per QK mfma
      int key0 = kc * 32 + half * 16;
      bf16x8 bK = {};
      if (quad == 0)
        bK = *(const bf16x8*)&kbase[(size_t)(key0 + l15) * 8];
      f32x4 s = {0.f, 0.f, 0.f, 0.f};
      s = __builtin_amdgcn_mfma_f32_16x16x32_bf16(aQ, bK, s, 0, 0, 0);
#pragma unroll
      for (int r = 0; r < 4; ++r) {
        float e = __builtin_amdgcn_exp2f(s[r]);   // logits O(1): raw v_exp_f32 safe
        Pw[(quad * 4 + r) * 40 + half * 16 + l15] =
            (unsigned short)(__float_as_uint(e) >> 16);  // truncated bf16 (1 instr)
      }
    }
    bf16x8 aP = *(const bf16x8*)&Pw[l15 * 40 + quad * 8];                     // A: m=q, k=key
    bf16x8 bV = *(const bf16x8*)&vbase[(size_t)l15 * 512 + kc * 32 + quad * 8]; // B: n=vcol, k=key
    accO = __builtin_amdgcn_mfma_f32_16x16x32_bf16(aP, bV, accO, 0, 0, 0);
  }
#pragma unroll
  for (int r = 0; r < 4; ++r) {
    float se = __shfl(accO[r], quad * 16 + 8);
    float o = accO[r] * (1.0f / se);
    if (l15 < 8) {
      int n = n0 + quad * 4 + r;
      aoydw[((size_t)b * NV + n) * 512 + h * 8 + l15] = f2bf(o);
    }
  }
}

// ---------------------------------------------------------------- K7: depthwise conv, v_nc (n,c) bf16 -> aoydw cols 256+
__global__ void __launch_bounds__(256) k_dw(const unsigned short* __restrict__ v_nc,
                                            const float* __restrict__ wdw,
                                            const float* __restrict__ bdw,
                                            unsigned short* __restrict__ aoydw) {
  int c = threadIdx.x;
  int b = blockIdx.y;
  float wr[27];
#pragma unroll
  for (int i = 0; i < 27; ++i) wr[i] = wdw[c * 27 + i];
  float bias = bdw[c];
  const unsigned short* src = v_nc + (size_t)b * NV * 256 + c;
  unsigned short* dst = aoydw + (size_t)b * NV * 512 + 256 + c;
  int n = blockIdx.x * 4;                    // 4 consecutive n (same h-row) share taps
  int d = n >> 8, h = (n >> 4) & 15, w = n & 15;
  float a0 = bias, a1 = bias, a2 = bias, a3 = bias;
#pragma unroll
  for (int kd = 0; kd < 3; ++kd) {
    int zd = d - 1 + kd; bool okd = (unsigned)zd < 16u;
#pragma unroll
    for (int kh = 0; kh < 3; ++kh) {
      int zh = h - 1 + kh; bool okh = okd && ((unsigned)zh < 16u);
      int rowb = zd * 256 + zh * 16;
      float v[6];
#pragma unroll
      for (int i = 0; i < 6; ++i) {
        int zw = w - 1 + i;
        bool ok = okh && ((unsigned)zw < 16u);   // wave-uniform mask
        v[i] = ok ? bf2f(src[(size_t)(rowb + zw) * 256]) : 0.f;
      }
      const float* wp = &wr[kd * 9 + kh * 3];
      a0 = fmaf(v[0], wp[0], fmaf(v[1], wp[1], fmaf(v[2], wp[2], a0)));
      a1 = fmaf(v[1], wp[0], fmaf(v[2], wp[1], fmaf(v[3], wp[2], a1)));
      a2 = fmaf(v[2], wp[0], fmaf(v[3], wp[1], fmaf(v[4], wp[2], a2)));
      a3 = fmaf(v[3], wp[0], fmaf(v[4], wp[1], fmaf(v[5], wp[2], a3)));
    }
  }
  dst[(size_t)(n + 0) * 512] = f2bf(a0);
  dst[(size_t)(n + 1) * 512] = f2bf(a1);
  dst[(size_t)(n + 2) * 512] = f2bf(a2);
  dst[(size_t)(n + 3) * 512] = f2bf(a3);
}

// ---------------------------------------------------------------- K8: final GEMM K=512, MFMA bf16
__global__ void __launch_bounds__(256) k_final(const unsigned short* __restrict__ aoydw,
                                               const unsigned short* __restrict__ wcat,
                                               const float* __restrict__ bproj,
                                               const float* __restrict__ bpw,
                                               float* __restrict__ out) {
  __shared__ unsigned short Als[64 * 40];
  __shared__ unsigned short Bls[128 * 40];
  int n0 = blockIdx.x * 64, j0 = blockIdx.y * 128, b = blockIdx.z;
  int t = threadIdx.x;
  int wave = t >> 6, lane = t & 63;
  int l15 = lane & 15, q = lane >> 4, q8 = q * 8;
  int wn = (wave >> 1) * 32, wjj = (wave & 1) * 64;
  f32x4 acc[2][4] = {};
  const unsigned short* Abase = aoydw + (size_t)b * NV * 512;
  int ar = t >> 2, aq = t & 3;
  int br = t >> 1, bhh = t & 1;
  for (int c0 = 0; c0 < 512; c0 += 32) {
    __syncthreads();
    *(uint4*)&Als[ar * 40 + aq * 8] =
        *(const uint4*)&Abase[(size_t)(n0 + ar) * 512 + c0 + aq * 8];
    const unsigned short* sb = &wcat[(size_t)(j0 + br) * 512 + c0 + bhh * 16];
    *(uint4*)&Bls[br * 40 + bhh * 16]     = *(const uint4*)&sb[0];
    *(uint4*)&Bls[br * 40 + bhh * 16 + 8] = *(const uint4*)&sb[8];
    __syncthreads();
    bf16x8 af[2], bf[4];
#pragma unroll
    for (int mt = 0; mt < 2; ++mt)
      af[mt] = *(const bf16x8*)&Als[(wn + mt * 16 + l15) * 40 + q8];
#pragma unroll
    for (int nt = 0; nt < 4; ++nt)
      bf[nt] = *(const bf16x8*)&Bls[(wjj + nt * 16 + l15) * 40 + q8];
#pragma unroll
    for (int mt = 0; mt < 2; ++mt)
#pragma unroll
      for (int nt = 0; nt < 4; ++nt)
        acc[mt][nt] = __builtin_amdgcn_mfma_f32_16x16x32_bf16(af[mt], bf[nt], acc[mt][nt], 0, 0, 0);
  }
#pragma unroll
  for (int nt = 0; nt < 4; ++nt) {
    int j = j0 + wjj + nt * 16 + l15;
    float bl = bproj[j] + bpw[j];
#pragma unroll
    for (int mt = 0; mt < 2; ++mt) {
      int n = n0 + wn + mt * 16 + q * 4;
      float4 r = make_float4(acc[mt][nt][0] + bl, acc[mt][nt][1] + bl,
                             acc[mt][nt][2] + bl, acc[mt][nt][3] + bl);
      *(float4*)&out[(size_t)(b * 256 + j) * NV + n] = r;
    }
  }
}

// ---------------------------------------------------------------- launch
extern "C" void kernel_launch(void* const* d_in, const int* in_sizes, int n_in,
                              void* d_out, int out_size, void* d_ws, size_t ws_size,
                              hipStream_t stream) {
  const float* x_kv   = (const float*)d_in[0];
  const float* x_q    = (const float*)d_in[1];
  const float* w_spa  = (const float*)d_in[2];
  const float* w_kv   = (const float*)d_in[3];
  const float* b_kv   = (const float*)d_in[4];
  const float* w_q    = (const float*)d_in[5];
  const float* b_q    = (const float*)d_in[6];
  const float* w_proj = (const float*)d_in[7];
  const float* b_proj = (const float*)d_in[8];
  const float* w_dw   = (const float*)d_in[9];
  const float* b_dw   = (const float*)d_in[10];
  const float* w_pw   = (const float*)d_in[11];
  const float* b_pw   = (const float*)d_in[12];
  float* out = (float*)d_out;

  const size_t MB = 1024 * 1024;
  char* ws = (char*)d_ws;
  unsigned short* xkv_t = (unsigned short*)(ws);                 // 4 MB (b,n,c) bf16
  unsigned short* xq_t  = (unsigned short*)(ws + 4 * MB);        // 4 MB
  unsigned short* v_nc  = (unsigned short*)(ws + 8 * MB);        // 4 MB (b,n,c) bf16
  unsigned short* qh    = (unsigned short*)(ws + 12 * MB);       // 4 MB (b,h,n,8) bf16
  unsigned short* aoydw = (unsigned short*)(ws + 16 * MB);       // 8 MB (b,n,512) bf16
  unsigned short* kg    = (unsigned short*)(ws + 24 * MB);       // 512 KB (bh,512,8) bf16 pre-scaled
  unsigned short* vt    = (unsigned short*)(ws + 24 * MB + 512 * 1024);  // 1 MB (bh,16,512) bf16
  unsigned short* wv_t  = (unsigned short*)(ws + 26 * MB);               // 128 KB
  unsigned short* wq_t  = (unsigned short*)(ws + 26 * MB + 131072);      // 128 KB
  unsigned short* wcat  = (unsigned short*)(ws + 26 * MB + 262144);      // 256 KB
  float*          avgmx = (float*)(ws + 27 * MB);                        //  64 KB
  float*          scores= (float*)(ws + 27 * MB + 65536);               //  32 KB
  int*            idx   = (int*)  (ws + 27 * MB + 98304);               //   4 KB

  k_tcast2<<<dim3(64, 4, 4), 256, 0, stream>>>(x_kv, x_q, xkv_t, xq_t);
  k_wprep<<<dim3(4, 4, 4), 256, 0, stream>>>(w_kv, w_q, w_proj, w_pw, wv_t, wq_t, wcat);
  k_reduce<<<256, 256, 0, stream>>>(x_kv, avgmx);
  k_spa<<<64, 256, 0, stream>>>(avgmx, w_spa, scores);
  k_topk<<<2, 1024, 0, stream>>>(scores, idx);
  k_qv<<<dim3(32, 2, 4), 256, 0, stream>>>(xkv_t, xq_t, wv_t, wq_t, b_kv, b_q, v_nc, qh);
  k_projg<<<dim3(16, 4, 2), 256, 0, stream>>>(x_kv, w_kv, 512, b_kv, idx, kg);
  k_vt<<<64, 256, 0, stream>>>(v_nc, idx, vt);
  k_fattn<<<dim3(64, 64), 256, 0, stream>>>(qh, kg, vt, aoydw);
  k_dw<<<dim3(1024, 2), 256, 0, stream>>>(v_nc, w_dw, b_dw, aoydw);
  k_final<<<dim3(64, 2, 2), 256, 0, stream>>>(aoydw, wcat, b_proj, b_pw, out);
}